// Round 5
// baseline (1458.789 us; speedup 1.0000x reference)
//
#include <hip/hip_runtime.h>
#include <math.h>

#define DIV_UP(a,b) (((a)+(b)-1)/(b))

typedef _Float16 half_t;
typedef _Float16 half8 __attribute__((ext_vector_type(8)));
typedef float f32x4 __attribute__((ext_vector_type(4)));

#define FLAG_RELU   1
#define FLAG_OUTF32 2
#define FLAG_SPLITK 4
#define FLAG_ATOMIC 8
#define FLAG_BNSUMS 16

#define GLDS16(src, dst) \
  __builtin_amdgcn_global_load_lds((const __attribute__((address_space(1))) void*)(src), \
                                   (__attribute__((address_space(3))) void*)(dst), 16, 0, 0)

__device__ __forceinline__ float fsig_(float x){ return 1.0f/(1.0f+__expf(-x)); }
__device__ __forceinline__ float ftanh_(float x){
  float ax = fabsf(x);
  float e = __expf(-2.0f*ax);
  float t = (1.0f - e)/(1.0f + e);
  return copysignf(t, x);
}

// ------------------------------------------------------------------
// ALL weight transposes (fp32 [K][N] -> fp16 [N][K]) in ONE launch.
// ------------------------------------------------------------------
#define NTP 18
struct TpAll {
  const float* src[NTP];
  half_t* dst[NTP];
  int K[NTP];
  int N[NTP];
  int prefix[NTP+1];
};

__global__ __launch_bounds__(256) void transpose_cvt_all_kernel(TpAll a)
{
  __shared__ float tile[32][33];
  int bid = blockIdx.x;
  int z = 0;
  while (bid >= a.prefix[z+1]) ++z;
  int local = bid - a.prefix[z];
  const float* w = a.src[z];
  half_t* wT = a.dst[z];
  int K = a.K[z], N = a.N[z];
  int tilesX = (N + 31) >> 5;
  int nt = (local % tilesX) * 32;
  int kt = (local / tilesX) * 32;
  int tx = threadIdx.x & 31, ty = threadIdx.x >> 5;
  #pragma unroll
  for (int r = 0; r < 4; ++r) {
    int k = kt + ty + r*8, n = nt + tx;
    tile[ty + r*8][tx] = (k < K && n < N) ? w[(long)k*N + n] : 0.f;
  }
  __syncthreads();
  #pragma unroll
  for (int r = 0; r < 4; ++r) {
    int n = nt + ty + r*8, k = kt + tx;
    if (n < N && k < K) wT[(long)n*K + k] = (half_t)tile[tx][ty + r*8];
  }
}

// ------------------------------------------------------------------
// conv1 special case: x (32,64,256,3) fp32, w (3,3,3,64), out fp16 + ReLU.
// ------------------------------------------------------------------
__global__ __launch_bounds__(256) void conv1_kernel(
    const float* __restrict__ x, const float* __restrict__ w,
    const float* __restrict__ bias, half_t* __restrict__ out)
{
  __shared__ float xs[3][258*3];
  int nb = blockIdx.x;            // n*64 + ho
  int n = nb >> 6, ho = nb & 63;
  int tid = threadIdx.x;
  int co = tid & 63;
  float wreg[27];
  #pragma unroll
  for (int k = 0; k < 27; ++k) wreg[k] = w[k*64 + co];
  float bco = bias[co];
  for (int i = tid; i < 3*258*3; i += 256) {
    int row = i / (258*3); int rem = i % (258*3);
    int col = rem / 3;     int ci  = rem % 3;
    int ih = ho - 1 + row; int iw = col - 1;
    float v = 0.f;
    if (ih >= 0 && ih < 64 && iw >= 0 && iw < 256)
      v = x[(((long)n*64 + ih)*256 + iw)*3 + ci];
    xs[row][col*3 + ci] = v;
  }
  __syncthreads();
  int wave = tid >> 6;
  for (int p = 0; p < 64; ++p) {
    int wo = wave*64 + p;
    float acc = bco;
    #pragma unroll
    for (int kh = 0; kh < 3; ++kh)
      #pragma unroll
      for (int kw = 0; kw < 3; ++kw)
        #pragma unroll
        for (int ci = 0; ci < 3; ++ci)
          acc = fmaf(xs[kh][(wo+kw)*3 + ci], wreg[(kh*3+kw)*3 + ci], acc);
    acc = fmaxf(acc, 0.f);
    out[(((long)n*64 + ho)*256 + wo)*64 + co] = (half_t)acc;
  }
}

// ------------------------------------------------------------------
// MFMA implicit-GEMM conv/GEMM. 128x128 tile, BK=64, 4 waves.
// R3: XCD-aware bijective remap (FETCH 281->27MB on conv6).
// R4: single-barrier double-buffered K-loop (latency hiding).
// ------------------------------------------------------------------
struct GOut { const half_t* wT; const float* bias; void* out; };

__global__ __launch_bounds__(256) void mfma_conv_kernel(
    const half_t* __restrict__ x, GOut g0, GOut g1, GOut g2,
    const half_t* __restrict__ zbuf, float* __restrict__ bns,
    int N,int H,int W,int Ci,int Ho,int Wo,int Co,
    int KH,int KW,int padH,int padW,
    int M,int K,int flags,int splitS)
{
  GOut g;
  int ciBeg = 0, ciEnd = Ci;
  if (flags & FLAG_SPLITK) {
    g = g0;
    int span = Ci / splitS;
    ciBeg = blockIdx.z * span;
    ciEnd = ciBeg + span;
  } else {
    g = (blockIdx.z == 0) ? g0 : (blockIdx.z == 1 ? g1 : g2);
  }
  const half_t* __restrict__ wT = g.wT;
  __shared__ half_t As[2][128*64];
  __shared__ half_t Bs[2][128*64];
  int tid = threadIdx.x;

  // ---- XCD-aware bijective remap: slot -> work (m-major, n fastest) ----
  int nbx = gridDim.x, nby = gridDim.y;
  int total = nbx * nby;
  int flat = blockIdx.y * nbx + blockIdx.x;   // dispatch slot within z-slice
  int q = total >> 3, r = total & 7;
  int xcd = flat & 7;                          // hw XCD (round-robin heuristic)
  int j = flat >> 3;                           // j-th slot on that XCD
  int w = xcd * q + (xcd < r ? xcd : r) + j;   // contiguous work band per XCD
  int m0 = (w / nbx) * 128, n0 = (w % nbx) * 128;

  int wave = tid >> 6, lane = tid & 63;
  int l15 = lane & 15, quad = lane >> 4;
  int x7 = lane & 7;
  int wm = (wave & 1) * 64, wn = (wave >> 1) * 64;

  // staging decode: 4 issues, row_i = i*32 + (tid>>3), source chunk swizzled
  int rSub = tid >> 3;
  int colHalf = (((tid & 7) ^ (rSub & 7))) * 8;

  int ho_[4], wo_[4], ni_[4]; bool av_[4];
  #pragma unroll
  for (int i = 0; i < 4; ++i) {
    int m = m0 + i*32 + rSub;
    av_[i] = m < M;
    int mm = av_[i] ? m : 0;
    wo_[i] = mm % Wo; int t2 = mm / Wo;
    ho_[i] = t2 % Ho; ni_[i] = t2 / Ho;
  }
  const half_t* bBase[4];
  #pragma unroll
  for (int i = 0; i < 4; ++i) {
    int n = n0 + i*32 + rSub;
    bBase[i] = (n < Co) ? (wT + (long)n*K + colHalf) : nullptr;
  }

  // fragment LDS chunk offsets per k-sub (conflict-free via XOR swizzle)
  int pch0 = ((quad)     ^ x7) * 8;
  int pch1 = ((4 + quad) ^ x7) * 8;

  f32x4 acc[4][4];
  #pragma unroll
  for (int i = 0; i < 4; ++i)
    #pragma unroll
    for (int j2 = 0; j2 < 4; ++j2)
      acc[i][j2] = (f32x4){0.f, 0.f, 0.f, 0.f};

  // ---- staging state: running (skh, skw, sci) k-tile coordinates ----
  int NT = ((ciEnd - ciBeg) >> 6) * KH * KW;
  int skh = 0, skw = 0, sci = ciBeg;
  long sAOff[4]; bool sAval[4];
  auto recompA = [&]() {
    #pragma unroll
    for (int i = 0; i < 4; ++i) {
      int ih = ho_[i] - padH + skh, iw = wo_[i] - padW + skw;
      bool ok = av_[i] && ih >= 0 && ih < H && iw >= 0 && iw < W;
      sAval[i] = ok;
      sAOff[i] = ok ? ((((long)ni_[i]*H + ih)*W + iw)*(long)Ci + colHalf) : 0;
    }
  };
  recompA();
  auto stage = [&](int b) {
    int kgS = (skh*KW + skw)*Ci + sci;           // global B k-index
    #pragma unroll
    for (int i = 0; i < 4; ++i) {
      const half_t* sa = sAval[i] ? (x + sAOff[i] + sci) : zbuf;
      GLDS16(sa, &As[b][i*2048 + wave*512]);
      const half_t* sb = bBase[i] ? (bBase[i] + kgS) : zbuf;
      GLDS16(sb, &Bs[b][i*2048 + wave*512]);
    }
  };
  auto advance = [&]() {
    sci += 64;
    if (sci == ciEnd) {
      sci = ciBeg; ++skw;
      if (skw == KW) { skw = 0; ++skh; }
      recompA();
    }
  };

  stage(0); advance();
  __syncthreads();                 // drains vmcnt(0): buf0 ready

  for (int kt = 0; kt < NT; ++kt) {
    int p = kt & 1;
    if (kt + 1 < NT) { stage(p ^ 1); advance(); }   // prefetch under MFMA
    {
      half8 af[4], bf[4];
      #pragma unroll
      for (int i = 0; i < 4; ++i)
        af[i] = *reinterpret_cast<half8*>(&As[p][(wm + i*16 + l15)*64 + pch0]);
      #pragma unroll
      for (int j2 = 0; j2 < 4; ++j2)
        bf[j2] = *reinterpret_cast<half8*>(&Bs[p][(wn + j2*16 + l15)*64 + pch0]);
      #pragma unroll
      for (int i = 0; i < 4; ++i)
        #pragma unroll
        for (int j2 = 0; j2 < 4; ++j2)
          acc[i][j2] = __builtin_amdgcn_mfma_f32_16x16x32_f16(af[i], bf[j2], acc[i][j2], 0, 0, 0);
    }
    {
      half8 af[4], bf[4];
      #pragma unroll
      for (int i = 0; i < 4; ++i)
        af[i] = *reinterpret_cast<half8*>(&As[p][(wm + i*16 + l15)*64 + pch1]);
      #pragma unroll
      for (int j2 = 0; j2 < 4; ++j2)
        bf[j2] = *reinterpret_cast<half8*>(&Bs[p][(wn + j2*16 + l15)*64 + pch1]);
      #pragma unroll
      for (int i = 0; i < 4; ++i)
        #pragma unroll
        for (int j2 = 0; j2 < 4; ++j2)
          acc[i][j2] = __builtin_amdgcn_mfma_f32_16x16x32_f16(af[i], bf[j2], acc[i][j2], 0, 0, 0);
    }
    __syncthreads();               // one barrier per K-step (drains vmcnt too)
  }

  // ---- BN sums from accumulators (f32, pre-relu value incl. bias) ----
  if (flags & FLAG_BNSUMS) {
    float* red = (float*)As;     // [wave][quad][l15][j][2] = 4*4*16*4*2 floats
    #pragma unroll
    for (int j2 = 0; j2 < 4; ++j2) {
      int n = n0 + wn + j2*16 + l15;
      float bv = g.bias[n];
      float s = 0.f, qq = 0.f;
      #pragma unroll
      for (int i = 0; i < 4; ++i)
        #pragma unroll
        for (int rr = 0; rr < 4; ++rr) {
          int m = m0 + wm + i*16 + quad*4 + rr;
          if (m < M) { float v = acc[i][j2][rr] + bv; s += v; qq += v*v; }
        }
      int idx = ((((wave*4 + quad)*16 + l15)*4) + j2)*2;
      red[idx] = s; red[idx+1] = qq;
    }
    __syncthreads();
    if (tid < 128) {
      int hi = tid >> 6;               // which 64-channel half (wn)
      int jj = (tid >> 4) & 3, ll = tid & 15;
      float s = 0.f, qq = 0.f;
      #pragma unroll
      for (int w2 = 0; w2 < 2; ++w2)
        #pragma unroll
        for (int qd = 0; qd < 4; ++qd) {
          int idx = (((((hi*2 + w2)*4 + qd)*16 + ll)*4) + jj)*2;
          s += red[idx]; qq += red[idx+1];
        }
      int n = n0 + tid;                // == n0 + hi*64 + jj*16 + ll
      atomicAdd(&bns[n], s);
      atomicAdd(&bns[Co + n], qq);
    }
  }

  // ---- store ----
  #pragma unroll
  for (int i = 0; i < 4; ++i) {
    #pragma unroll
    for (int rr = 0; rr < 4; ++rr) {
      int m = m0 + wm + i*16 + quad*4 + rr;
      if (m >= M) continue;
      #pragma unroll
      for (int j2 = 0; j2 < 4; ++j2) {
        int n = n0 + wn + j2*16 + l15;
        if (n >= Co) continue;
        if (flags & FLAG_ATOMIC) {
          atomicAdd(&((float*)g.out)[(long)m*Co + n], acc[i][j2][rr]);
        } else {
          float v = acc[i][j2][rr] + g.bias[n];
          if (flags & FLAG_RELU) v = fmaxf(v, 0.f);
          if (flags & FLAG_OUTF32) ((float*)g.out)[(long)m*Co + n] = v;
          else ((half_t*)g.out)[(long)m*Co + n] = (half_t)v;
        }
      }
    }
  }
}

// ------------------------------------------------------------------
// Max pool fp16, NHWC, 8 channels per thread.
// ------------------------------------------------------------------
__global__ __launch_bounds__(256) void maxpool8_kernel(
    const half_t* __restrict__ x, half_t* __restrict__ out,
    int N,int H,int W,int C,int Ho,int Wo,int sH,int sW)
{
  int C8 = C >> 3;
  long idx = (long)blockIdx.x*256 + threadIdx.x;
  long total8 = (long)N*Ho*Wo*C8;
  if (idx >= total8) return;
  int cb = (int)(idx % C8);
  long pix = idx / C8;
  int wo = (int)(pix % Wo); long t2 = pix / Wo;
  int ho = (int)(t2 % Ho); int n = (int)(t2 / Ho);
  int c = cb * 8;
  float m[8];
  #pragma unroll
  for (int e = 0; e < 8; ++e) m[e] = -INFINITY;
  for (int i = 0; i < 2; ++i) {
    int ih = ho*sH + i;
    if (ih >= H) continue;
    for (int j = 0; j < 2; ++j) {
      int iw = wo*sW + j;
      if (iw >= W) continue;
      half8 v = *reinterpret_cast<const half8*>(x + (((long)n*H + ih)*W + iw)*C + c);
      #pragma unroll
      for (int e = 0; e < 8; ++e) m[e] = fmaxf(m[e], (float)v[e]);
    }
  }
  half8 o;
  #pragma unroll
  for (int e = 0; e < 8; ++e) o[e] = (half_t)m[e];
  *reinterpret_cast<half8*>(out + idx*8) = o;
}

// ------------------------------------------------------------------
// BN apply + ReLU (in place), 8 channels/thread.
// ------------------------------------------------------------------
__global__ __launch_bounds__(256) void bn_apply_relu8_kernel(
    half_t* __restrict__ x, const float* __restrict__ sums,
    const float* __restrict__ scale, const float* __restrict__ bias,
    long total8, int C, float invN)
{
  long idx = (long)blockIdx.x*256 + threadIdx.x;
  if (idx >= total8) return;
  int c = (int)((idx*8) % C);
  half8 v = *reinterpret_cast<half8*>(x + idx*8);
  half8 o;
  #pragma unroll
  for (int e = 0; e < 8; ++e) {
    float mean = sums[c+e] * invN;
    float var  = sums[C + c+e] * invN - mean*mean;
    float rstd = rsqrtf(var + 1e-5f);
    float y = ((float)v[e] - mean) * rstd * scale[c+e] + bias[c+e];
    o[e] = (half_t)fmaxf(y, 0.0f);
  }
  *reinterpret_cast<half8*>(x + idx*8) = o;
}

// ------------------------------------------------------------------
// Fused BN+ReLU+maxpool: out (N,Ho,Wo,C) from in (N,H,W,C).
// ------------------------------------------------------------------
__global__ __launch_bounds__(256) void bn_pool8_kernel(
    const half_t* __restrict__ x, half_t* __restrict__ out,
    const float* __restrict__ sums, const float* __restrict__ scale,
    const float* __restrict__ bias,
    int N,int H,int W,int C,int Ho,int Wo,int sH,int sW, float invN)
{
  int C8 = C >> 3;
  long idx = (long)blockIdx.x*256 + threadIdx.x;
  long total8 = (long)N*Ho*Wo*C8;
  if (idx >= total8) return;
  int cb = (int)(idx % C8);
  long pix = idx / C8;
  int wo = (int)(pix % Wo); long t2 = pix / Wo;
  int ho = (int)(t2 % Ho); int n = (int)(t2 / Ho);
  int c = cb * 8;
  float mean[8], rs[8], bb[8];
  #pragma unroll
  for (int e = 0; e < 8; ++e) {
    mean[e] = sums[c+e] * invN;
    float var = sums[C + c+e] * invN - mean[e]*mean[e];
    rs[e] = rsqrtf(var + 1e-5f) * scale[c+e];
    bb[e] = bias[c+e];
  }
  float m[8];
  #pragma unroll
  for (int e = 0; e < 8; ++e) m[e] = -INFINITY;
  for (int i = 0; i < 2; ++i) {
    int ih = ho*sH + i;
    if (ih >= H) continue;
    for (int j = 0; j < 2; ++j) {
      int iw = wo*sW + j;
      if (iw >= W) continue;
      half8 v = *reinterpret_cast<const half8*>(x + (((long)n*H + ih)*W + iw)*C + c);
      #pragma unroll
      for (int e = 0; e < 8; ++e) {
        float y = fmaxf(((float)v[e] - mean[e]) * rs[e] + bb[e], 0.f);
        m[e] = fmaxf(m[e], y);
      }
    }
  }
  half8 o;
  #pragma unroll
  for (int e = 0; e < 8; ++e) o[e] = (half_t)m[e];
  *reinterpret_cast<half8*>(out + idx*8) = o;
}

// ------------------------------------------------------------------
// Bias prefill for the split-K qkv GEMM output (480 x 1536 f32).
// ------------------------------------------------------------------
__global__ __launch_bounds__(256) void bias_fill_kernel(
    float* __restrict__ out, const float* __restrict__ b0,
    const float* __restrict__ b1, const float* __restrict__ b2, int total)
{
  int idx = blockIdx.x*256 + threadIdx.x;
  if (idx >= total) return;
  int n = idx % 1536;
  float v = (n < 512) ? b0[n] : (n < 1024 ? b1[n-512] : b2[n-1024]);
  out[idx] = v;
}

// ------------------------------------------------------------------
// Attention (T=15, D=512), qkv interleaved f32 rows of ld=1536, out fp16.
// ------------------------------------------------------------------
__global__ __launch_bounds__(256) void attention_kernel(
    const float* __restrict__ qkv, half_t* __restrict__ out,
    int T, int D, int ld)
{
  int b = blockIdx.x;
  int tid = threadIdx.x;
  __shared__ float P[15][16];
  if (tid < T*T) {
    int t = tid / T, s = tid % T;
    const float* qp = qkv + ((long)b*T + t)*ld;
    const float* kp = qkv + ((long)b*T + s)*ld + 512;
    float acc = 0.f;
    for (int d = 0; d < D; d += 4) {
      float4 qv = *reinterpret_cast<const float4*>(qp + d);
      float4 kv = *reinterpret_cast<const float4*>(kp + d);
      acc += qv.x*kv.x + qv.y*kv.y + qv.z*kv.z + qv.w*kv.w;
    }
    P[t][s] = acc * (1.0f/32.0f);
  }
  __syncthreads();
  if (tid < T) {
    float mx = -INFINITY;
    for (int s = 0; s < T; ++s) mx = fmaxf(mx, P[tid][s]);
    float sum = 0.f;
    for (int s = 0; s < T; ++s) { float e = expf(P[tid][s] - mx); P[tid][s] = e; sum += e; }
    float inv = 1.0f / sum;
    for (int s = 0; s < T; ++s) P[tid][s] *= inv;
  }
  __syncthreads();
  for (int idx = tid; idx < T*D; idx += 256) {
    int s = idx / D, kk2 = idx % D;
    float acc = 0.f;
    #pragma unroll
    for (int t = 0; t < 15; ++t)
      acc += qkv[((long)b*T + t)*ld + 1024 + kk2] * P[t][s];
    out[((long)b*T + s)*D + kk2] = (half_t)acc;
  }
}

// ------------------------------------------------------------------
// Persistent bidirectional LSTM — R5 restructure:
//  * stage_h + hs LDS + its barrier DELETED. MFMA A-fragments load
//    DIRECTLY from hbuf via agent-scope atomic b64 loads (the same
//    coherent primitive stage_h used), 2x8B per lane per chunk. The
//    compiler interleaves the 64 h-loads + 32 weight loads with the
//    64 MFMAs via counted waitcnt — no LDS round trip, one less
//    barrier, no serial {stage -> barrier -> read} chain.
//  * Poll moved to step TOP with target s (identical semantics,
//    shifted); all 4 waves poll independently -> no barrier after.
//  * Write-safety unchanged: flag>=s+1 still means "done reading h_s"
//    (set after the chunk loop consumed everything), checked before
//    any overwrite of that parity.
//  * 2 barriers/step total: gates-ready, h-store-drain.
// ------------------------------------------------------------------
template<int H>
__global__ __launch_bounds__(256, 1) void lstm_persistent_kernel(
    const float* __restrict__ preF, const float* __restrict__ preR,
    const half_t* __restrict__ whTF, const half_t* __restrict__ whTR,
    half_t* __restrict__ hbuf, half_t* __restrict__ y,
    int* __restrict__ flags, int nblk,
    int ystride, int yoffF, int yoffR)
{
  constexpr int KI = H / 32;       // k-chunks of 32 == number of blocks
  __shared__ float gates[32][133]; // [batch][gate*32 + hcol]
  int tid = threadIdx.x;
  int jb0 = blockIdx.x * 32;       // 32 H-columns per block
  int lane = tid & 63, wave = tid >> 6;   // wave == gate index
  int l15 = lane & 15, quad = lane >> 4;
  int bb = tid >> 3;               // batch row for elementwise
  int jj0 = (tid & 7) * 4;         // 4 H-cols per thread
  constexpr int H4 = 4 * H;

  float cst[4] = {0.f, 0.f, 0.f, 0.f};

  // ull offsets of this lane's A-fragment rows within one h-parity buffer
  int o0 = l15 * (H >> 2) + quad * 2;          // row l15
  int o1 = (16 + l15) * (H >> 2) + quad * 2;   // row 16+l15

  const half_t* wB = whTF;

  auto loadpv = [&](int s, float (&pv)[16]) {
    const float* pr = (s < 15) ? preF : preR;
    int t = (s < 15) ? s : 29 - s;
    const float* pp = pr + (long)(bb*15 + t)*H4 + jb0 + jj0;
    #pragma unroll
    for (int g = 0; g < 4; ++g) {
      f32x4 v = *reinterpret_cast<const f32x4*>(pp + g*H);
      pv[g*4+0] = v[0]; pv[g*4+1] = v[1]; pv[g*4+2] = v[2]; pv[g*4+3] = v[3];
    }
  };

  float pv[16];
  loadpv(0, pv);

  for (int s = 0; s < 30; ++s) {
    if (s == 15) wB = whTR;        // reverse direction: carry (cst) continues
    int t = (s < 15) ? s : 29 - s;
    int yoff = (s < 15) ? yoffF : yoffR;

    // ---- wait for all producers of h_s (flag >= s; initial flags 0) ----
    for (;;) {
      int fv = (lane < nblk)
        ? __hip_atomic_load(&flags[lane], __ATOMIC_RELAXED, __HIP_MEMORY_SCOPE_AGENT)
        : 0x7fffffff;
      if (__all(fv >= s)) break;
    }

    // ---- direct-load MFMA over all k-chunks ----
    const unsigned long long* hb =
        (const unsigned long long*)(hbuf + (long)(s & 1) * 32 * H);
    const half_t* w0 = wB + (long)(wave*H + jb0 + l15)*H + quad*8;
    const half_t* w1 = wB + (long)(wave*H + jb0 + 16 + l15)*H + quad*8;

    f32x4 acc00 = {0.f,0.f,0.f,0.f}, acc10 = {0.f,0.f,0.f,0.f};
    f32x4 acc01 = {0.f,0.f,0.f,0.f}, acc11 = {0.f,0.f,0.f,0.f};
    #pragma unroll
    for (int i = 0; i < KI; ++i) {
      union { unsigned long long u[2]; half8 v; } a0, a1;
      a0.u[0] = __hip_atomic_load(hb + o0 + i*8,     __ATOMIC_RELAXED, __HIP_MEMORY_SCOPE_AGENT);
      a0.u[1] = __hip_atomic_load(hb + o0 + i*8 + 1, __ATOMIC_RELAXED, __HIP_MEMORY_SCOPE_AGENT);
      a1.u[0] = __hip_atomic_load(hb + o1 + i*8,     __ATOMIC_RELAXED, __HIP_MEMORY_SCOPE_AGENT);
      a1.u[1] = __hip_atomic_load(hb + o1 + i*8 + 1, __ATOMIC_RELAXED, __HIP_MEMORY_SCOPE_AGENT);
      half8 bf0 = *reinterpret_cast<const half8*>(w0 + i*32);
      half8 bf1 = *reinterpret_cast<const half8*>(w1 + i*32);
      acc00 = __builtin_amdgcn_mfma_f32_16x16x32_f16(a0.v, bf0, acc00, 0, 0, 0);
      acc10 = __builtin_amdgcn_mfma_f32_16x16x32_f16(a1.v, bf0, acc10, 0, 0, 0);
      acc01 = __builtin_amdgcn_mfma_f32_16x16x32_f16(a0.v, bf1, acc01, 0, 0, 0);
      acc11 = __builtin_amdgcn_mfma_f32_16x16x32_f16(a1.v, bf1, acc11, 0, 0, 0);
    }
    #pragma unroll
    for (int r = 0; r < 4; ++r) {
      gates[quad*4 + r][wave*32 + l15]           = acc00[r];
      gates[16 + quad*4 + r][wave*32 + l15]      = acc10[r];
      gates[quad*4 + r][wave*32 + 16 + l15]      = acc01[r];
      gates[16 + quad*4 + r][wave*32 + 16 + l15] = acc11[r];
    }
    __syncthreads();

    unsigned long long hpack;
    {
      half_t hn[4];
      #pragma unroll
      for (int p = 0; p < 4; ++p) {
        int j = jj0 + p;
        float gi = pv[p]      + gates[bb][j];
        float gf = pv[4 + p]  + gates[bb][32 + j];
        float gg = pv[8 + p]  + gates[bb][64 + j];
        float go = pv[12 + p] + gates[bb][96 + j];
        gi = fsig_(gi); gf = fsig_(gf); gg = ftanh_(gg); go = fsig_(go);
        float cn = gf * cst[p] + gi * gg;
        cst[p] = cn;
        hn[p] = (half_t)(go * ftanh_(cn));
      }
      hpack = *reinterpret_cast<unsigned long long*>(hn);
      half_t* hdst = hbuf + (long)((s + 1) & 1) * 32 * H;
      __hip_atomic_store((unsigned long long*)(hdst + (long)bb*H + jb0 + jj0), hpack,
                         __ATOMIC_RELAXED, __HIP_MEMORY_SCOPE_AGENT);
    }

    if (s < 29) {
      __syncthreads();             // drains vmcnt -> h stores visible
      if (tid == 0)
        __hip_atomic_store(&flags[blockIdx.x], s + 1,
                           __ATOMIC_RELAXED, __HIP_MEMORY_SCOPE_AGENT);
      *reinterpret_cast<unsigned long long*>(
          &y[(long)(bb*15 + t)*ystride + yoff + jb0 + jj0]) = hpack;
      loadpv(s + 1, pv);           // prefetch next pv under next step's poll
    } else {
      *reinterpret_cast<unsigned long long*>(
          &y[(long)(bb*15 + t)*ystride + yoff + jb0 + jj0]) = hpack;
    }
  }
}

// ------------------------------------------------------------------
// Host orchestration
// ------------------------------------------------------------------
extern "C" void kernel_launch(void* const* d_in, const int* in_sizes, int n_in,
                              void* d_out, int out_size, void* d_ws, size_t ws_size,
                              hipStream_t stream)
{
  const float* x       = (const float*)d_in[0];
  const float* c1w     = (const float*)d_in[1];  const float* c1b = (const float*)d_in[2];
  const float* c2w     = (const float*)d_in[3];  const float* c2b = (const float*)d_in[4];
  const float* c3w     = (const float*)d_in[5];  const float* c3b = (const float*)d_in[6];
  const float* bn1s    = (const float*)d_in[7];  const float* bn1b = (const float*)d_in[8];
  const float* c4w     = (const float*)d_in[9];  const float* c4b = (const float*)d_in[10];
  const float* bn2s    = (const float*)d_in[11]; const float* bn2b = (const float*)d_in[12];
  const float* c5w     = (const float*)d_in[13]; const float* c5b = (const float*)d_in[14];
  const float* bn3s    = (const float*)d_in[15]; const float* bn3b = (const float*)d_in[16];
  const float* c6w     = (const float*)d_in[17]; const float* c6b = (const float*)d_in[18];
  const float* bn4s    = (const float*)d_in[19]; const float* bn4b = (const float*)d_in[20];
  const float* c7w     = (const float*)d_in[21]; const float* c7b = (const float*)d_in[22];
  const float* bn5s    = (const float*)d_in[23]; const float* bn5b = (const float*)d_in[24];
  const float* wq      = (const float*)d_in[25]; const float* bq = (const float*)d_in[26];
  const float* wk      = (const float*)d_in[27]; const float* bk = (const float*)d_in[28];
  const float* wv      = (const float*)d_in[29]; const float* bv = (const float*)d_in[30];
  const float* l1f_wx  = (const float*)d_in[31]; const float* l1f_wh = (const float*)d_in[32]; const float* l1f_b = (const float*)d_in[33];
  const float* l1r_wx  = (const float*)d_in[34]; const float* l1r_wh = (const float*)d_in[35]; const float* l1r_b = (const float*)d_in[36];
  const float* l2f_wx  = (const float*)d_in[37]; const float* l2f_wh = (const float*)d_in[38]; const float* l2f_b = (const float*)d_in[39];
  const float* l2r_wx  = (const float*)d_in[40]; const float* l2r_wh = (const float*)d_in[41]; const float* l2r_b = (const float*)d_in[42];
  const float* wo      = (const float*)d_in[43]; const float* bo = (const float*)d_in[44];
  float* outp = (float*)d_out;

  char* base = (char*)d_ws;
  half_t* actA = (half_t*)base;
  half_t* actB = (half_t*)(base + 67108864);
  half_t* wtA  = (half_t*)(base + 100663296);
  float*  f32a = (float*)(base + 143687680);
  half_t* h16a = (half_t*)(base + 158736384);

  half_t* wt2  = wtA;
  half_t* wt3  = wtA + 73728;
  half_t* wt4  = wtA + 368640;
  half_t* wt5  = wtA + 958464;
  half_t* wt6  = wtA + 2138112;
  half_t* wt7  = wtA + 4497408;
  half_t* wtq  = wtA + 5545984;        // wtq|wtk|wtv contiguous -> [1536][7680]
  half_t* wtk  = wtA + 9478144;
  half_t* wtv  = wtA + 13410304;
  half_t* wt1f = wtA + 17342464;
  half_t* wt1r = wtA + 17866752;
  half_t* wt2f = wtA + 18391040;
  half_t* wt2r = wtA + 19439616;
  half_t* wto  = wtA + 20488192;

  float* qkvbuf = f32a;                // 480 x 1536 f32
  float* pre1f = f32a + 737280;
  float* pre1r = f32a + 1228800;
  float* pre2f = f32a + 1720320;
  float* pre2r = f32a + 2703360;

  half_t* ao  = h16a;
  half_t* x1  = h16a + 245760;
  half_t* x2  = h16a + 491520;
  half_t* hb1 = h16a + 983040;              // 2 x 32 x 256 fp16
  half_t* hb2 = hb1 + 16384;                // 2 x 32 x 512 fp16
  int*    flags1 = (int*)(hb2 + 32768);     // 512 ints
  int*    flags2 = flags1 + 512;
  half_t* zbuf   = (half_t*)(flags2 + 512); // 32 halves
  float*  bnz    = (float*)(zbuf + 32);     // 5 x 2048 floats

  // transposed fp16 LSTM recurrent weights [4H][H] (appended past bnz)
  half_t* whT1f = (half_t*)(base + 160849920);   // 1024x256 = 512KB
  half_t* whT1r = (half_t*)(base + 161374208);
  half_t* whT2f = (half_t*)(base + 161898496);   // 2048x512 = 2MB
  half_t* whT2r = (half_t*)(base + 163995648);   // end 166,092,800

  auto convm = [&](const half_t* in, const half_t* wt, const float* b, void* out,
                   int N,int H,int W,int Ci,int Ho,int Wo,int Co,
                   int KH,int KW,int pH,int pW,int flags, float* bns){
    int M = N*Ho*Wo, K = KH*KW*Ci;
    dim3 grid(DIV_UP(Co,128), DIV_UP(M,128), 1);
    GOut g{wt, b, out};
    mfma_conv_kernel<<<grid,256,0,stream>>>(in,g,g,g,zbuf,bns,N,H,W,Ci,Ho,Wo,Co,
                                            KH,KW,pH,pW,M,K,flags,1);
  };
  auto gemm3 = [&](const half_t* A, GOut g0, GOut g1, GOut g2, int nz,
                   int M, int Nn, int K, int flags, int splitS){
    dim3 grid(DIV_UP(Nn,128), DIV_UP(M,128), nz);
    mfma_conv_kernel<<<grid,256,0,stream>>>(A,g0,g1,g2,zbuf,bnz,M,1,1,K,1,1,Nn,
                                            1,1,0,0,M,K,flags,splitS);
  };
  auto pool = [&](const half_t* in, half_t* out, int N,int H,int W,int C,
                  int Ho,int Wo,int sH,int sW){
    long total8 = (long)N*Ho*Wo*(C/8);
    maxpool8_kernel<<<(int)DIV_UP(total8,256),256,0,stream>>>(in,out,N,H,W,C,Ho,Wo,sH,sW);
  };
  auto bnApply = [&](half_t* buf, long nPix, int C, const float* s, const float* b,
                     float* sums){
    long total8 = nPix * C / 8;
    bn_apply_relu8_kernel<<<(int)DIV_UP(total8,256),256,0,stream>>>(buf, sums, s, b, total8, C, 1.0f/(float)nPix);
  };
  auto bnPool = [&](const half_t* in, half_t* out, int N,int H,int W,int C,
                    int Ho,int Wo,int sH,int sW, long nPix,
                    const float* s, const float* b, float* sums){
    long total8 = (long)N*Ho*Wo*(C/8);
    bn_pool8_kernel<<<(int)DIV_UP(total8,256),256,0,stream>>>(
        in,out,sums,s,b,N,H,W,C,Ho,Wo,sH,sW,1.0f/(float)nPix);
  };

  // one zero-fill: hb1/hb2, flags, zbuf, 5 bn-sum buffers
  hipMemsetAsync(hb1, 0, 143424, stream);

  // ---- ALL weight transposes in one launch (incl. LSTM Wh -> fp16 [4H][H]) ----
  {
    TpAll tp;
    const float* srcs[NTP] = {c2w,c3w,c4w,c5w,c6w,c7w,wq,wk,wv,l1f_wx,l1r_wx,l2f_wx,l2r_wx,wo,
                              l1f_wh,l1r_wh,l2f_wh,l2r_wh};
    half_t* dsts[NTP] = {wt2,wt3,wt4,wt5,wt6,wt7,wtq,wtk,wtv,wt1f,wt1r,wt2f,wt2r,wto,
                         whT1f,whT1r,whT2f,whT2r};
    int Ks[NTP] = {576,1152,2304,2304,4608,2048,7680,7680,7680,512,512,512,512,1024,
                   256,256,512,512};
    int Ns[NTP] = {128,256,256,512,512,512,512,512,512,1024,1024,2048,2048,1000,
                   1024,1024,2048,2048};
    int acc = 0;
    for (int i = 0; i < NTP; ++i) {
      tp.src[i] = srcs[i]; tp.dst[i] = dsts[i]; tp.K[i] = Ks[i]; tp.N[i] = Ns[i];
      tp.prefix[i] = acc;
      acc += DIV_UP(Ks[i],32) * DIV_UP(Ns[i],32);
    }
    tp.prefix[NTP] = acc;
    transpose_cvt_all_kernel<<<acc,256,0,stream>>>(tp);
  }

  // ---- conv stack (activations fp16) ----
  conv1_kernel<<<2048,256,0,stream>>>(x, c1w, c1b, actA);
  pool(actA, actB, 32,64,256,64,  32,128, 2,2);
  convm(actB, wt2, c2b, actA, 32,32,128,64,  32,128,128, 3,3,1,1, FLAG_RELU, bnz);
  pool(actA, actB, 32,32,128,128, 16,64, 2,2);
  convm(actB, wt3, c3b, actA, 32,16,64,128,  16,64,256,  3,3,1,1, FLAG_BNSUMS, bnz);
  bnApply(actA, 32768, 256, bn1s, bn1b, bnz);
  convm(actA, wt4, c4b, actB, 32,16,64,256,  16,64,256,  3,3,1,1, FLAG_BNSUMS, bnz + 2048);
  bnPool(actB, actA, 32,16,64,256, 16,32, 1,2, 32768, bn2s, bn2b, bnz + 2048);
  convm(actA, wt5, c5b, actB, 32,16,32,256,  16,32,512,  3,3,1,1, FLAG_BNSUMS, bnz + 4096);
  bnApply(actB, 16384, 512, bn3s, bn3b, bnz + 4096);
  convm(actB, wt6, c6b, actA, 32,16,32,512,  16,32,512,  3,3,1,1, FLAG_BNSUMS, bnz + 6144);
  bnPool(actA, actB, 32,16,32,512, 16,16, 1,2, 16384, bn4s, bn4b, bnz + 6144);
  convm(actB, wt7, c7b, actA, 32,16,16,512,  15,15,512,  2,2,0,0, FLAG_BNSUMS, bnz + 8192);
  bnApply(actA, 7200, 512, bn5s, bn5b, bnz + 8192);

  // ---- attention: single qkv GEMM (N=1536), split-K x4, atomic epilogue ----
  bias_fill_kernel<<<DIV_UP(480*1536,256),256,0,stream>>>(qkvbuf, bq, bk, bv, 480*1536);
  gemm3(actA, GOut{wtq, nullptr, qkvbuf}, GOut{wtq, nullptr, qkvbuf},
        GOut{wtq, nullptr, qkvbuf}, 4, 480, 1536, 7680, FLAG_SPLITK|FLAG_ATOMIC, 4);
  attention_kernel<<<32,256,0,stream>>>(qkvbuf, ao, 15, 512, 1536);

  // ---- LSTM stack 1 (H=256): 8 blocks x 32 H-cols ----
  gemm3(ao, GOut{wt1f, l1f_b, pre1f}, GOut{wt1r, l1r_b, pre1r},
        GOut{wt1r, l1r_b, pre1r}, 2, 480, 1024, 512, FLAG_OUTF32, 1);
  lstm_persistent_kernel<256><<<8,256,0,stream>>>(
      pre1f, pre1r, whT1f, whT1r, hb1, x1, flags1, 8, 512, 0, 256);

  // ---- LSTM stack 2 (H=512): 16 blocks x 32 H-cols ----
  gemm3(x1, GOut{wt2f, l2f_b, pre2f}, GOut{wt2r, l2r_b, pre2r},
        GOut{wt2r, l2r_b, pre2r}, 2, 480, 2048, 512, FLAG_OUTF32, 1);
  lstm_persistent_kernel<512><<<16,256,0,stream>>>(
      pre2f, pre2r, whT2f, whT2r, hb2, x2, flags2, 16, 1024, 512, 0);

  // ---- classifier ----
  gemm3(x2, GOut{wto, bo, outp}, GOut{wto, bo, outp}, GOut{wto, bo, outp}, 1,
        480, 1000, 1024, FLAG_OUTF32, 1);
}

// Round 6
// 1164.687 us; speedup vs baseline: 1.2525x; 1.2525x over previous
//
#include <hip/hip_runtime.h>
#include <math.h>

#define DIV_UP(a,b) (((a)+(b)-1)/(b))

typedef _Float16 half_t;
typedef _Float16 half8 __attribute__((ext_vector_type(8)));
typedef float f32x4 __attribute__((ext_vector_type(4)));

#define FLAG_RELU   1
#define FLAG_OUTF32 2
#define FLAG_SPLITK 4
#define FLAG_ATOMIC 8
#define FLAG_BNSUMS 16

#define GLDS16(src, dst) \
  __builtin_amdgcn_global_load_lds((const __attribute__((address_space(1))) void*)(src), \
                                   (__attribute__((address_space(3))) void*)(dst), 16, 0, 0)

__device__ __forceinline__ float fsig_(float x){ return 1.0f/(1.0f+__expf(-x)); }
__device__ __forceinline__ float ftanh_(float x){
  float ax = fabsf(x);
  float e = __expf(-2.0f*ax);
  float t = (1.0f - e)/(1.0f + e);
  return copysignf(t, x);
}

// ------------------------------------------------------------------
// ALL weight transposes (fp32 [K][N] -> fp16 [N][K]) in ONE launch.
// ------------------------------------------------------------------
#define NTP 18
struct TpAll {
  const float* src[NTP];
  half_t* dst[NTP];
  int K[NTP];
  int N[NTP];
  int prefix[NTP+1];
};

__global__ __launch_bounds__(256) void transpose_cvt_all_kernel(TpAll a)
{
  __shared__ float tile[32][33];
  int bid = blockIdx.x;
  int z = 0;
  while (bid >= a.prefix[z+1]) ++z;
  int local = bid - a.prefix[z];
  const float* w = a.src[z];
  half_t* wT = a.dst[z];
  int K = a.K[z], N = a.N[z];
  int tilesX = (N + 31) >> 5;
  int nt = (local % tilesX) * 32;
  int kt = (local / tilesX) * 32;
  int tx = threadIdx.x & 31, ty = threadIdx.x >> 5;
  #pragma unroll
  for (int r = 0; r < 4; ++r) {
    int k = kt + ty + r*8, n = nt + tx;
    tile[ty + r*8][tx] = (k < K && n < N) ? w[(long)k*N + n] : 0.f;
  }
  __syncthreads();
  #pragma unroll
  for (int r = 0; r < 4; ++r) {
    int n = nt + ty + r*8, k = kt + tx;
    if (n < N && k < K) wT[(long)n*K + k] = (half_t)tile[tx][ty + r*8];
  }
}

// ------------------------------------------------------------------
// conv1 special case: x (32,64,256,3) fp32, w (3,3,3,64), out fp16 + ReLU.
// ------------------------------------------------------------------
__global__ __launch_bounds__(256) void conv1_kernel(
    const float* __restrict__ x, const float* __restrict__ w,
    const float* __restrict__ bias, half_t* __restrict__ out)
{
  __shared__ float xs[3][258*3];
  int nb = blockIdx.x;            // n*64 + ho
  int n = nb >> 6, ho = nb & 63;
  int tid = threadIdx.x;
  int co = tid & 63;
  float wreg[27];
  #pragma unroll
  for (int k = 0; k < 27; ++k) wreg[k] = w[k*64 + co];
  float bco = bias[co];
  for (int i = tid; i < 3*258*3; i += 256) {
    int row = i / (258*3); int rem = i % (258*3);
    int col = rem / 3;     int ci  = rem % 3;
    int ih = ho - 1 + row; int iw = col - 1;
    float v = 0.f;
    if (ih >= 0 && ih < 64 && iw >= 0 && iw < 256)
      v = x[(((long)n*64 + ih)*256 + iw)*3 + ci];
    xs[row][col*3 + ci] = v;
  }
  __syncthreads();
  int wave = tid >> 6;
  for (int p = 0; p < 64; ++p) {
    int wo = wave*64 + p;
    float acc = bco;
    #pragma unroll
    for (int kh = 0; kh < 3; ++kh)
      #pragma unroll
      for (int kw = 0; kw < 3; ++kw)
        #pragma unroll
        for (int ci = 0; ci < 3; ++ci)
          acc = fmaf(xs[kh][(wo+kw)*3 + ci], wreg[(kh*3+kw)*3 + ci], acc);
    acc = fmaxf(acc, 0.f);
    out[(((long)n*64 + ho)*256 + wo)*64 + co] = (half_t)acc;
  }
}

// ------------------------------------------------------------------
// MFMA implicit-GEMM conv/GEMM. 128x128 tile, BK=64, 4 waves.
// R3: XCD-aware bijective remap (FETCH 281->27MB on conv6).
// R4: single-barrier double-buffered K-loop (latency hiding).
// ------------------------------------------------------------------
struct GOut { const half_t* wT; const float* bias; void* out; };

__global__ __launch_bounds__(256) void mfma_conv_kernel(
    const half_t* __restrict__ x, GOut g0, GOut g1, GOut g2,
    const half_t* __restrict__ zbuf, float* __restrict__ bns,
    int N,int H,int W,int Ci,int Ho,int Wo,int Co,
    int KH,int KW,int padH,int padW,
    int M,int K,int flags,int splitS)
{
  GOut g;
  int ciBeg = 0, ciEnd = Ci;
  if (flags & FLAG_SPLITK) {
    g = g0;
    int span = Ci / splitS;
    ciBeg = blockIdx.z * span;
    ciEnd = ciBeg + span;
  } else {
    g = (blockIdx.z == 0) ? g0 : (blockIdx.z == 1 ? g1 : g2);
  }
  const half_t* __restrict__ wT = g.wT;
  __shared__ half_t As[2][128*64];
  __shared__ half_t Bs[2][128*64];
  int tid = threadIdx.x;

  // ---- XCD-aware bijective remap: slot -> work (m-major, n fastest) ----
  int nbx = gridDim.x, nby = gridDim.y;
  int total = nbx * nby;
  int flat = blockIdx.y * nbx + blockIdx.x;   // dispatch slot within z-slice
  int q = total >> 3, r = total & 7;
  int xcd = flat & 7;                          // hw XCD (round-robin heuristic)
  int j = flat >> 3;                           // j-th slot on that XCD
  int w = xcd * q + (xcd < r ? xcd : r) + j;   // contiguous work band per XCD
  int m0 = (w / nbx) * 128, n0 = (w % nbx) * 128;

  int wave = tid >> 6, lane = tid & 63;
  int l15 = lane & 15, quad = lane >> 4;
  int x7 = lane & 7;
  int wm = (wave & 1) * 64, wn = (wave >> 1) * 64;

  // staging decode: 4 issues, row_i = i*32 + (tid>>3), source chunk swizzled
  int rSub = tid >> 3;
  int colHalf = (((tid & 7) ^ (rSub & 7))) * 8;

  int ho_[4], wo_[4], ni_[4]; bool av_[4];
  #pragma unroll
  for (int i = 0; i < 4; ++i) {
    int m = m0 + i*32 + rSub;
    av_[i] = m < M;
    int mm = av_[i] ? m : 0;
    wo_[i] = mm % Wo; int t2 = mm / Wo;
    ho_[i] = t2 % Ho; ni_[i] = t2 / Ho;
  }
  const half_t* bBase[4];
  #pragma unroll
  for (int i = 0; i < 4; ++i) {
    int n = n0 + i*32 + rSub;
    bBase[i] = (n < Co) ? (wT + (long)n*K + colHalf) : nullptr;
  }

  // fragment LDS chunk offsets per k-sub (conflict-free via XOR swizzle)
  int pch0 = ((quad)     ^ x7) * 8;
  int pch1 = ((4 + quad) ^ x7) * 8;

  f32x4 acc[4][4];
  #pragma unroll
  for (int i = 0; i < 4; ++i)
    #pragma unroll
    for (int j2 = 0; j2 < 4; ++j2)
      acc[i][j2] = (f32x4){0.f, 0.f, 0.f, 0.f};

  // ---- staging state: running (skh, skw, sci) k-tile coordinates ----
  int NT = ((ciEnd - ciBeg) >> 6) * KH * KW;
  int skh = 0, skw = 0, sci = ciBeg;
  long sAOff[4]; bool sAval[4];
  auto recompA = [&]() {
    #pragma unroll
    for (int i = 0; i < 4; ++i) {
      int ih = ho_[i] - padH + skh, iw = wo_[i] - padW + skw;
      bool ok = av_[i] && ih >= 0 && ih < H && iw >= 0 && iw < W;
      sAval[i] = ok;
      sAOff[i] = ok ? ((((long)ni_[i]*H + ih)*W + iw)*(long)Ci + colHalf) : 0;
    }
  };
  recompA();
  auto stage = [&](int b) {
    int kgS = (skh*KW + skw)*Ci + sci;           // global B k-index
    #pragma unroll
    for (int i = 0; i < 4; ++i) {
      const half_t* sa = sAval[i] ? (x + sAOff[i] + sci) : zbuf;
      GLDS16(sa, &As[b][i*2048 + wave*512]);
      const half_t* sb = bBase[i] ? (bBase[i] + kgS) : zbuf;
      GLDS16(sb, &Bs[b][i*2048 + wave*512]);
    }
  };
  auto advance = [&]() {
    sci += 64;
    if (sci == ciEnd) {
      sci = ciBeg; ++skw;
      if (skw == KW) { skw = 0; ++skh; }
      recompA();
    }
  };

  stage(0); advance();
  __syncthreads();                 // drains vmcnt(0): buf0 ready

  for (int kt = 0; kt < NT; ++kt) {
    int p = kt & 1;
    if (kt + 1 < NT) { stage(p ^ 1); advance(); }   // prefetch under MFMA
    {
      half8 af[4], bf[4];
      #pragma unroll
      for (int i = 0; i < 4; ++i)
        af[i] = *reinterpret_cast<half8*>(&As[p][(wm + i*16 + l15)*64 + pch0]);
      #pragma unroll
      for (int j2 = 0; j2 < 4; ++j2)
        bf[j2] = *reinterpret_cast<half8*>(&Bs[p][(wn + j2*16 + l15)*64 + pch0]);
      #pragma unroll
      for (int i = 0; i < 4; ++i)
        #pragma unroll
        for (int j2 = 0; j2 < 4; ++j2)
          acc[i][j2] = __builtin_amdgcn_mfma_f32_16x16x32_f16(af[i], bf[j2], acc[i][j2], 0, 0, 0);
    }
    {
      half8 af[4], bf[4];
      #pragma unroll
      for (int i = 0; i < 4; ++i)
        af[i] = *reinterpret_cast<half8*>(&As[p][(wm + i*16 + l15)*64 + pch1]);
      #pragma unroll
      for (int j2 = 0; j2 < 4; ++j2)
        bf[j2] = *reinterpret_cast<half8*>(&Bs[p][(wn + j2*16 + l15)*64 + pch1]);
      #pragma unroll
      for (int i = 0; i < 4; ++i)
        #pragma unroll
        for (int j2 = 0; j2 < 4; ++j2)
          acc[i][j2] = __builtin_amdgcn_mfma_f32_16x16x32_f16(af[i], bf[j2], acc[i][j2], 0, 0, 0);
    }
    __syncthreads();               // one barrier per K-step (drains vmcnt too)
  }

  // ---- BN sums from accumulators (f32, pre-relu value incl. bias) ----
  if (flags & FLAG_BNSUMS) {
    float* red = (float*)As;     // [wave][quad][l15][j][2] = 4*4*16*4*2 floats
    #pragma unroll
    for (int j2 = 0; j2 < 4; ++j2) {
      int n = n0 + wn + j2*16 + l15;
      float bv = g.bias[n];
      float s = 0.f, qq = 0.f;
      #pragma unroll
      for (int i = 0; i < 4; ++i)
        #pragma unroll
        for (int rr = 0; rr < 4; ++rr) {
          int m = m0 + wm + i*16 + quad*4 + rr;
          if (m < M) { float v = acc[i][j2][rr] + bv; s += v; qq += v*v; }
        }
      int idx = ((((wave*4 + quad)*16 + l15)*4) + j2)*2;
      red[idx] = s; red[idx+1] = qq;
    }
    __syncthreads();
    if (tid < 128) {
      int hi = tid >> 6;               // which 64-channel half (wn)
      int jj = (tid >> 4) & 3, ll = tid & 15;
      float s = 0.f, qq = 0.f;
      #pragma unroll
      for (int w2 = 0; w2 < 2; ++w2)
        #pragma unroll
        for (int qd = 0; qd < 4; ++qd) {
          int idx = (((((hi*2 + w2)*4 + qd)*16 + ll)*4) + jj)*2;
          s += red[idx]; qq += red[idx+1];
        }
      int n = n0 + tid;                // == n0 + hi*64 + jj*16 + ll
      atomicAdd(&bns[n], s);
      atomicAdd(&bns[Co + n], qq);
    }
  }

  // ---- store ----
  #pragma unroll
  for (int i = 0; i < 4; ++i) {
    #pragma unroll
    for (int rr = 0; rr < 4; ++rr) {
      int m = m0 + wm + i*16 + quad*4 + rr;
      if (m >= M) continue;
      #pragma unroll
      for (int j2 = 0; j2 < 4; ++j2) {
        int n = n0 + wn + j2*16 + l15;
        if (n >= Co) continue;
        if (flags & FLAG_ATOMIC) {
          atomicAdd(&((float*)g.out)[(long)m*Co + n], acc[i][j2][rr]);
        } else {
          float v = acc[i][j2][rr] + g.bias[n];
          if (flags & FLAG_RELU) v = fmaxf(v, 0.f);
          if (flags & FLAG_OUTF32) ((float*)g.out)[(long)m*Co + n] = v;
          else ((half_t*)g.out)[(long)m*Co + n] = (half_t)v;
        }
      }
    }
  }
}

// ------------------------------------------------------------------
// Max pool fp16, NHWC, 8 channels per thread.
// ------------------------------------------------------------------
__global__ __launch_bounds__(256) void maxpool8_kernel(
    const half_t* __restrict__ x, half_t* __restrict__ out,
    int N,int H,int W,int C,int Ho,int Wo,int sH,int sW)
{
  int C8 = C >> 3;
  long idx = (long)blockIdx.x*256 + threadIdx.x;
  long total8 = (long)N*Ho*Wo*C8;
  if (idx >= total8) return;
  int cb = (int)(idx % C8);
  long pix = idx / C8;
  int wo = (int)(pix % Wo); long t2 = pix / Wo;
  int ho = (int)(t2 % Ho); int n = (int)(t2 / Ho);
  int c = cb * 8;
  float m[8];
  #pragma unroll
  for (int e = 0; e < 8; ++e) m[e] = -INFINITY;
  for (int i = 0; i < 2; ++i) {
    int ih = ho*sH + i;
    if (ih >= H) continue;
    for (int j = 0; j < 2; ++j) {
      int iw = wo*sW + j;
      if (iw >= W) continue;
      half8 v = *reinterpret_cast<const half8*>(x + (((long)n*H + ih)*W + iw)*C + c);
      #pragma unroll
      for (int e = 0; e < 8; ++e) m[e] = fmaxf(m[e], (float)v[e]);
    }
  }
  half8 o;
  #pragma unroll
  for (int e = 0; e < 8; ++e) o[e] = (half_t)m[e];
  *reinterpret_cast<half8*>(out + idx*8) = o;
}

// ------------------------------------------------------------------
// BN apply + ReLU (in place), 8 channels/thread.
// ------------------------------------------------------------------
__global__ __launch_bounds__(256) void bn_apply_relu8_kernel(
    half_t* __restrict__ x, const float* __restrict__ sums,
    const float* __restrict__ scale, const float* __restrict__ bias,
    long total8, int C, float invN)
{
  long idx = (long)blockIdx.x*256 + threadIdx.x;
  if (idx >= total8) return;
  int c = (int)((idx*8) % C);
  half8 v = *reinterpret_cast<half8*>(x + idx*8);
  half8 o;
  #pragma unroll
  for (int e = 0; e < 8; ++e) {
    float mean = sums[c+e] * invN;
    float var  = sums[C + c+e] * invN - mean*mean;
    float rstd = rsqrtf(var + 1e-5f);
    float y = ((float)v[e] - mean) * rstd * scale[c+e] + bias[c+e];
    o[e] = (half_t)fmaxf(y, 0.0f);
  }
  *reinterpret_cast<half8*>(x + idx*8) = o;
}

// ------------------------------------------------------------------
// Fused BN+ReLU+maxpool: out (N,Ho,Wo,C) from in (N,H,W,C).
// ------------------------------------------------------------------
__global__ __launch_bounds__(256) void bn_pool8_kernel(
    const half_t* __restrict__ x, half_t* __restrict__ out,
    const float* __restrict__ sums, const float* __restrict__ scale,
    const float* __restrict__ bias,
    int N,int H,int W,int C,int Ho,int Wo,int sH,int sW, float invN)
{
  int C8 = C >> 3;
  long idx = (long)blockIdx.x*256 + threadIdx.x;
  long total8 = (long)N*Ho*Wo*C8;
  if (idx >= total8) return;
  int cb = (int)(idx % C8);
  long pix = idx / C8;
  int wo = (int)(pix % Wo); long t2 = pix / Wo;
  int ho = (int)(t2 % Ho); int n = (int)(t2 / Ho);
  int c = cb * 8;
  float mean[8], rs[8], bb[8];
  #pragma unroll
  for (int e = 0; e < 8; ++e) {
    mean[e] = sums[c+e] * invN;
    float var = sums[C + c+e] * invN - mean[e]*mean[e];
    rs[e] = rsqrtf(var + 1e-5f) * scale[c+e];
    bb[e] = bias[c+e];
  }
  float m[8];
  #pragma unroll
  for (int e = 0; e < 8; ++e) m[e] = -INFINITY;
  for (int i = 0; i < 2; ++i) {
    int ih = ho*sH + i;
    if (ih >= H) continue;
    for (int j = 0; j < 2; ++j) {
      int iw = wo*sW + j;
      if (iw >= W) continue;
      half8 v = *reinterpret_cast<const half8*>(x + (((long)n*H + ih)*W + iw)*C + c);
      #pragma unroll
      for (int e = 0; e < 8; ++e) {
        float y = fmaxf(((float)v[e] - mean[e]) * rs[e] + bb[e], 0.f);
        m[e] = fmaxf(m[e], y);
      }
    }
  }
  half8 o;
  #pragma unroll
  for (int e = 0; e < 8; ++e) o[e] = (half_t)m[e];
  *reinterpret_cast<half8*>(out + idx*8) = o;
}

// ------------------------------------------------------------------
// Bias prefill for the split-K qkv GEMM output (480 x 1536 f32).
// ------------------------------------------------------------------
__global__ __launch_bounds__(256) void bias_fill_kernel(
    float* __restrict__ out, const float* __restrict__ b0,
    const float* __restrict__ b1, const float* __restrict__ b2, int total)
{
  int idx = blockIdx.x*256 + threadIdx.x;
  if (idx >= total) return;
  int n = idx % 1536;
  float v = (n < 512) ? b0[n] : (n < 1024 ? b1[n-512] : b2[n-1024]);
  out[idx] = v;
}

// ------------------------------------------------------------------
// Attention (T=15, D=512), qkv interleaved f32 rows of ld=1536, out fp16.
// ------------------------------------------------------------------
__global__ __launch_bounds__(256) void attention_kernel(
    const float* __restrict__ qkv, half_t* __restrict__ out,
    int T, int D, int ld)
{
  int b = blockIdx.x;
  int tid = threadIdx.x;
  __shared__ float P[15][16];
  if (tid < T*T) {
    int t = tid / T, s = tid % T;
    const float* qp = qkv + ((long)b*T + t)*ld;
    const float* kp = qkv + ((long)b*T + s)*ld + 512;
    float acc = 0.f;
    for (int d = 0; d < D; d += 4) {
      float4 qv = *reinterpret_cast<const float4*>(qp + d);
      float4 kv = *reinterpret_cast<const float4*>(kp + d);
      acc += qv.x*kv.x + qv.y*kv.y + qv.z*kv.z + qv.w*kv.w;
    }
    P[t][s] = acc * (1.0f/32.0f);
  }
  __syncthreads();
  if (tid < T) {
    float mx = -INFINITY;
    for (int s = 0; s < T; ++s) mx = fmaxf(mx, P[tid][s]);
    float sum = 0.f;
    for (int s = 0; s < T; ++s) { float e = expf(P[tid][s] - mx); P[tid][s] = e; sum += e; }
    float inv = 1.0f / sum;
    for (int s = 0; s < T; ++s) P[tid][s] *= inv;
  }
  __syncthreads();
  for (int idx = tid; idx < T*D; idx += 256) {
    int s = idx / D, kk2 = idx % D;
    float acc = 0.f;
    #pragma unroll
    for (int t = 0; t < 15; ++t)
      acc += qkv[((long)b*T + t)*ld + 1024 + kk2] * P[t][s];
    out[((long)b*T + s)*D + kk2] = (half_t)acc;
  }
}

// ------------------------------------------------------------------
// Persistent bidirectional LSTM — R6: revert to the proven R4
// structure (stage_h -> LDS hs -> MFMA; R5's per-lane atomic loads
// serialized — LLVM keeps atomic loads in program order, ~12us/step).
// One tweak kept from R5: the producer-poll moved to the TOP of the
// step (target flag >= s), polled by ALL waves independently ->
// deletes the post-poll barrier (3 barriers/step instead of 4) and
// every wave starts stage_h the instant the last flag lands.
// ------------------------------------------------------------------
#define MAXK 512
#define HSROW (MAXK + 8)

template<int N64, int HLOG>
__device__ __forceinline__ void stage_h(
    const unsigned long long* __restrict__ src, half_t (*hs)[HSROW], int tid)
{
  unsigned long long tmp[N64];
  #pragma unroll
  for (int u = 0; u < N64; ++u)
    tmp[u] = __hip_atomic_load(src + tid + u*256, __ATOMIC_RELAXED, __HIP_MEMORY_SCOPE_AGENT);
  #pragma unroll
  for (int u = 0; u < N64; ++u) {
    int idx = tid + u*256;
    int row = idx >> (HLOG - 2);
    int col = (idx & ((1 << (HLOG - 2)) - 1)) * 4;
    *reinterpret_cast<unsigned long long*>(&hs[row][col]) = tmp[u];
  }
}

template<int H>
__global__ __launch_bounds__(256, 1) void lstm_persistent_kernel(
    const float* __restrict__ preF, const float* __restrict__ preR,
    const half_t* __restrict__ whTF, const half_t* __restrict__ whTR,
    half_t* __restrict__ hbuf, half_t* __restrict__ y,
    int* __restrict__ flags, int nblk,
    int ystride, int yoffF, int yoffR)
{
  constexpr int KI = H / 32;      // k-chunks of 32
  __shared__ half_t hs[32][HSROW];
  __shared__ float gates[32][133]; // [batch][gate*32 + hcol]
  int tid = threadIdx.x;
  int jb0 = blockIdx.x * 32;       // 32 H-columns per block
  int lane = tid & 63, wave = tid >> 6;   // wave == gate index
  int l15 = lane & 15, quad = lane >> 4;
  int bb = tid >> 3;               // batch row for elementwise
  int jj0 = (tid & 7) * 4;         // 4 H-cols per thread
  constexpr int H4 = 4 * H;

  float cst[4] = {0.f, 0.f, 0.f, 0.f};

  const half_t* wB = whTF;

  auto loadpv = [&](int s, float (&pv)[16]) {
    const float* pr = (s < 15) ? preF : preR;
    int t = (s < 15) ? s : 29 - s;
    const float* pp = pr + (long)(bb*15 + t)*H4 + jb0 + jj0;
    #pragma unroll
    for (int g = 0; g < 4; ++g) {
      f32x4 v = *reinterpret_cast<const f32x4*>(pp + g*H);
      pv[g*4+0] = v[0]; pv[g*4+1] = v[1]; pv[g*4+2] = v[2]; pv[g*4+3] = v[3];
    }
  };

  float pv[16];
  loadpv(0, pv);

  for (int s = 0; s < 30; ++s) {
    if (s == 15) wB = whTR;        // reverse direction: carry (cst) continues
    int t = (s < 15) ? s : 29 - s;
    int yoff = (s < 15) ? yoffF : yoffR;

    // ---- top-poll: wait for all producers of h_s (flag >= s) ----
    if (s > 0) {
      for (;;) {
        int fv = (lane < nblk)
          ? __hip_atomic_load(&flags[lane], __ATOMIC_RELAXED, __HIP_MEMORY_SCOPE_AGENT)
          : 0x7fffffff;
        if (__all(fv >= s)) break;
      }
    }

    // ---- stage h_s into LDS (batched coalesced atomic loads) ----
    const unsigned long long* hsrc =
        (const unsigned long long*)(hbuf + (long)(s & 1) * 32 * H);
    if constexpr (H == 512) stage_h<16, 9>(hsrc, hs, tid);
    else                    stage_h<8, 8>(hsrc, hs, tid);
    __syncthreads();

    const half_t* w0 = wB + (long)(wave*H + jb0 + l15)*H + quad*8;
    const half_t* w1 = wB + (long)(wave*H + jb0 + 16 + l15)*H + quad*8;

    f32x4 acc00 = {0.f,0.f,0.f,0.f}, acc10 = {0.f,0.f,0.f,0.f};
    f32x4 acc01 = {0.f,0.f,0.f,0.f}, acc11 = {0.f,0.f,0.f,0.f};
    #pragma unroll
    for (int i = 0; i < KI; ++i) {
      half8 a0 = *reinterpret_cast<half8*>(&hs[l15][i*32 + quad*8]);
      half8 a1 = *reinterpret_cast<half8*>(&hs[16 + l15][i*32 + quad*8]);
      half8 bf0 = *reinterpret_cast<const half8*>(w0 + i*32);
      half8 bf1 = *reinterpret_cast<const half8*>(w1 + i*32);
      acc00 = __builtin_amdgcn_mfma_f32_16x16x32_f16(a0, bf0, acc00, 0, 0, 0);
      acc10 = __builtin_amdgcn_mfma_f32_16x16x32_f16(a1, bf0, acc10, 0, 0, 0);
      acc01 = __builtin_amdgcn_mfma_f32_16x16x32_f16(a0, bf1, acc01, 0, 0, 0);
      acc11 = __builtin_amdgcn_mfma_f32_16x16x32_f16(a1, bf1, acc11, 0, 0, 0);
    }
    #pragma unroll
    for (int r = 0; r < 4; ++r) {
      gates[quad*4 + r][wave*32 + l15]           = acc00[r];
      gates[16 + quad*4 + r][wave*32 + l15]      = acc10[r];
      gates[quad*4 + r][wave*32 + 16 + l15]      = acc01[r];
      gates[16 + quad*4 + r][wave*32 + 16 + l15] = acc11[r];
    }
    __syncthreads();

    unsigned long long hpack;
    {
      half_t hn[4];
      #pragma unroll
      for (int p = 0; p < 4; ++p) {
        int j = jj0 + p;
        float gi = pv[p]      + gates[bb][j];
        float gf = pv[4 + p]  + gates[bb][32 + j];
        float gg = pv[8 + p]  + gates[bb][64 + j];
        float go = pv[12 + p] + gates[bb][96 + j];
        gi = fsig_(gi); gf = fsig_(gf); gg = ftanh_(gg); go = fsig_(go);
        float cn = gf * cst[p] + gi * gg;
        cst[p] = cn;
        hn[p] = (half_t)(go * ftanh_(cn));
      }
      hpack = *reinterpret_cast<unsigned long long*>(hn);
      half_t* hdst = hbuf + (long)((s + 1) & 1) * 32 * H;
      __hip_atomic_store((unsigned long long*)(hdst + (long)bb*H + jb0 + jj0), hpack,
                         __ATOMIC_RELAXED, __HIP_MEMORY_SCOPE_AGENT);
    }

    if (s < 29) {
      __syncthreads();             // drains vmcnt -> h stores visible at LLC
      if (tid == 0)
        __hip_atomic_store(&flags[blockIdx.x], s + 1,
                           __ATOMIC_RELAXED, __HIP_MEMORY_SCOPE_AGENT);
      *reinterpret_cast<unsigned long long*>(
          &y[(long)(bb*15 + t)*ystride + yoff + jb0 + jj0]) = hpack;
      loadpv(s + 1, pv);           // prefetch next pv under next step's poll
    } else {
      *reinterpret_cast<unsigned long long*>(
          &y[(long)(bb*15 + t)*ystride + yoff + jb0 + jj0]) = hpack;
    }
  }
}

// ------------------------------------------------------------------
// Host orchestration
// ------------------------------------------------------------------
extern "C" void kernel_launch(void* const* d_in, const int* in_sizes, int n_in,
                              void* d_out, int out_size, void* d_ws, size_t ws_size,
                              hipStream_t stream)
{
  const float* x       = (const float*)d_in[0];
  const float* c1w     = (const float*)d_in[1];  const float* c1b = (const float*)d_in[2];
  const float* c2w     = (const float*)d_in[3];  const float* c2b = (const float*)d_in[4];
  const float* c3w     = (const float*)d_in[5];  const float* c3b = (const float*)d_in[6];
  const float* bn1s    = (const float*)d_in[7];  const float* bn1b = (const float*)d_in[8];
  const float* c4w     = (const float*)d_in[9];  const float* c4b = (const float*)d_in[10];
  const float* bn2s    = (const float*)d_in[11]; const float* bn2b = (const float*)d_in[12];
  const float* c5w     = (const float*)d_in[13]; const float* c5b = (const float*)d_in[14];
  const float* bn3s    = (const float*)d_in[15]; const float* bn3b = (const float*)d_in[16];
  const float* c6w     = (const float*)d_in[17]; const float* c6b = (const float*)d_in[18];
  const float* bn4s    = (const float*)d_in[19]; const float* bn4b = (const float*)d_in[20];
  const float* c7w     = (const float*)d_in[21]; const float* c7b = (const float*)d_in[22];
  const float* bn5s    = (const float*)d_in[23]; const float* bn5b = (const float*)d_in[24];
  const float* wq      = (const float*)d_in[25]; const float* bq = (const float*)d_in[26];
  const float* wk      = (const float*)d_in[27]; const float* bk = (const float*)d_in[28];
  const float* wv      = (const float*)d_in[29]; const float* bv = (const float*)d_in[30];
  const float* l1f_wx  = (const float*)d_in[31]; const float* l1f_wh = (const float*)d_in[32]; const float* l1f_b = (const float*)d_in[33];
  const float* l1r_wx  = (const float*)d_in[34]; const float* l1r_wh = (const float*)d_in[35]; const float* l1r_b = (const float*)d_in[36];
  const float* l2f_wx  = (const float*)d_in[37]; const float* l2f_wh = (const float*)d_in[38]; const float* l2f_b = (const float*)d_in[39];
  const float* l2r_wx  = (const float*)d_in[40]; const float* l2r_wh = (const float*)d_in[41]; const float* l2r_b = (const float*)d_in[42];
  const float* wo      = (const float*)d_in[43]; const float* bo = (const float*)d_in[44];
  float* outp = (float*)d_out;

  char* base = (char*)d_ws;
  half_t* actA = (half_t*)base;
  half_t* actB = (half_t*)(base + 67108864);
  half_t* wtA  = (half_t*)(base + 100663296);
  float*  f32a = (float*)(base + 143687680);
  half_t* h16a = (half_t*)(base + 158736384);

  half_t* wt2  = wtA;
  half_t* wt3  = wtA + 73728;
  half_t* wt4  = wtA + 368640;
  half_t* wt5  = wtA + 958464;
  half_t* wt6  = wtA + 2138112;
  half_t* wt7  = wtA + 4497408;
  half_t* wtq  = wtA + 5545984;        // wtq|wtk|wtv contiguous -> [1536][7680]
  half_t* wtk  = wtA + 9478144;
  half_t* wtv  = wtA + 13410304;
  half_t* wt1f = wtA + 17342464;
  half_t* wt1r = wtA + 17866752;
  half_t* wt2f = wtA + 18391040;
  half_t* wt2r = wtA + 19439616;
  half_t* wto  = wtA + 20488192;

  float* qkvbuf = f32a;                // 480 x 1536 f32
  float* pre1f = f32a + 737280;
  float* pre1r = f32a + 1228800;
  float* pre2f = f32a + 1720320;
  float* pre2r = f32a + 2703360;

  half_t* ao  = h16a;
  half_t* x1  = h16a + 245760;
  half_t* x2  = h16a + 491520;
  half_t* hb1 = h16a + 983040;              // 2 x 32 x 256 fp16
  half_t* hb2 = hb1 + 16384;                // 2 x 32 x 512 fp16
  int*    flags1 = (int*)(hb2 + 32768);     // 512 ints
  int*    flags2 = flags1 + 512;
  half_t* zbuf   = (half_t*)(flags2 + 512); // 32 halves
  float*  bnz    = (float*)(zbuf + 32);     // 5 x 2048 floats

  // transposed fp16 LSTM recurrent weights [4H][H] (appended past bnz)
  half_t* whT1f = (half_t*)(base + 160849920);   // 1024x256 = 512KB
  half_t* whT1r = (half_t*)(base + 161374208);
  half_t* whT2f = (half_t*)(base + 161898496);   // 2048x512 = 2MB
  half_t* whT2r = (half_t*)(base + 163995648);   // end 166,092,800

  auto convm = [&](const half_t* in, const half_t* wt, const float* b, void* out,
                   int N,int H,int W,int Ci,int Ho,int Wo,int Co,
                   int KH,int KW,int pH,int pW,int flags, float* bns){
    int M = N*Ho*Wo, K = KH*KW*Ci;
    dim3 grid(DIV_UP(Co,128), DIV_UP(M,128), 1);
    GOut g{wt, b, out};
    mfma_conv_kernel<<<grid,256,0,stream>>>(in,g,g,g,zbuf,bns,N,H,W,Ci,Ho,Wo,Co,
                                            KH,KW,pH,pW,M,K,flags,1);
  };
  auto gemm3 = [&](const half_t* A, GOut g0, GOut g1, GOut g2, int nz,
                   int M, int Nn, int K, int flags, int splitS){
    dim3 grid(DIV_UP(Nn,128), DIV_UP(M,128), nz);
    mfma_conv_kernel<<<grid,256,0,stream>>>(A,g0,g1,g2,zbuf,bnz,M,1,1,K,1,1,Nn,
                                            1,1,0,0,M,K,flags,splitS);
  };
  auto pool = [&](const half_t* in, half_t* out, int N,int H,int W,int C,
                  int Ho,int Wo,int sH,int sW){
    long total8 = (long)N*Ho*Wo*(C/8);
    maxpool8_kernel<<<(int)DIV_UP(total8,256),256,0,stream>>>(in,out,N,H,W,C,Ho,Wo,sH,sW);
  };
  auto bnApply = [&](half_t* buf, long nPix, int C, const float* s, const float* b,
                     float* sums){
    long total8 = nPix * C / 8;
    bn_apply_relu8_kernel<<<(int)DIV_UP(total8,256),256,0,stream>>>(buf, sums, s, b, total8, C, 1.0f/(float)nPix);
  };
  auto bnPool = [&](const half_t* in, half_t* out, int N,int H,int W,int C,
                    int Ho,int Wo,int sH,int sW, long nPix,
                    const float* s, const float* b, float* sums){
    long total8 = (long)N*Ho*Wo*(C/8);
    bn_pool8_kernel<<<(int)DIV_UP(total8,256),256,0,stream>>>(
        in,out,sums,s,b,N,H,W,C,Ho,Wo,sH,sW,1.0f/(float)nPix);
  };

  // one zero-fill: hb1/hb2, flags, zbuf, 5 bn-sum buffers
  hipMemsetAsync(hb1, 0, 143424, stream);

  // ---- ALL weight transposes in one launch (incl. LSTM Wh -> fp16 [4H][H]) ----
  {
    TpAll tp;
    const float* srcs[NTP] = {c2w,c3w,c4w,c5w,c6w,c7w,wq,wk,wv,l1f_wx,l1r_wx,l2f_wx,l2r_wx,wo,
                              l1f_wh,l1r_wh,l2f_wh,l2r_wh};
    half_t* dsts[NTP] = {wt2,wt3,wt4,wt5,wt6,wt7,wtq,wtk,wtv,wt1f,wt1r,wt2f,wt2r,wto,
                         whT1f,whT1r,whT2f,whT2r};
    int Ks[NTP] = {576,1152,2304,2304,4608,2048,7680,7680,7680,512,512,512,512,1024,
                   256,256,512,512};
    int Ns[NTP] = {128,256,256,512,512,512,512,512,512,1024,1024,2048,2048,1000,
                   1024,1024,2048,2048};
    int acc = 0;
    for (int i = 0; i < NTP; ++i) {
      tp.src[i] = srcs[i]; tp.dst[i] = dsts[i]; tp.K[i] = Ks[i]; tp.N[i] = Ns[i];
      tp.prefix[i] = acc;
      acc += DIV_UP(Ks[i],32) * DIV_UP(Ns[i],32);
    }
    tp.prefix[NTP] = acc;
    transpose_cvt_all_kernel<<<acc,256,0,stream>>>(tp);
  }

  // ---- conv stack (activations fp16) ----
  conv1_kernel<<<2048,256,0,stream>>>(x, c1w, c1b, actA);
  pool(actA, actB, 32,64,256,64,  32,128, 2,2);
  convm(actB, wt2, c2b, actA, 32,32,128,64,  32,128,128, 3,3,1,1, FLAG_RELU, bnz);
  pool(actA, actB, 32,32,128,128, 16,64, 2,2);
  convm(actB, wt3, c3b, actA, 32,16,64,128,  16,64,256,  3,3,1,1, FLAG_BNSUMS, bnz);
  bnApply(actA, 32768, 256, bn1s, bn1b, bnz);
  convm(actA, wt4, c4b, actB, 32,16,64,256,  16,64,256,  3,3,1,1, FLAG_BNSUMS, bnz + 2048);
  bnPool(actB, actA, 32,16,64,256, 16,32, 1,2, 32768, bn2s, bn2b, bnz + 2048);
  convm(actA, wt5, c5b, actB, 32,16,32,256,  16,32,512,  3,3,1,1, FLAG_BNSUMS, bnz + 4096);
  bnApply(actB, 16384, 512, bn3s, bn3b, bnz + 4096);
  convm(actB, wt6, c6b, actA, 32,16,32,512,  16,32,512,  3,3,1,1, FLAG_BNSUMS, bnz + 6144);
  bnPool(actA, actB, 32,16,32,512, 16,16, 1,2, 16384, bn4s, bn4b, bnz + 6144);
  convm(actB, wt7, c7b, actA, 32,16,16,512,  15,15,512,  2,2,0,0, FLAG_BNSUMS, bnz + 8192);
  bnApply(actA, 7200, 512, bn5s, bn5b, bnz + 8192);

  // ---- attention: single qkv GEMM (N=1536), split-K x4, atomic epilogue ----
  bias_fill_kernel<<<DIV_UP(480*1536,256),256,0,stream>>>(qkvbuf, bq, bk, bv, 480*1536);
  gemm3(actA, GOut{wtq, nullptr, qkvbuf}, GOut{wtq, nullptr, qkvbuf},
        GOut{wtq, nullptr, qkvbuf}, 4, 480, 1536, 7680, FLAG_SPLITK|FLAG_ATOMIC, 4);
  attention_kernel<<<32,256,0,stream>>>(qkvbuf, ao, 15, 512, 1536);

  // ---- LSTM stack 1 (H=256): 8 blocks x 32 H-cols ----
  gemm3(ao, GOut{wt1f, l1f_b, pre1f}, GOut{wt1r, l1r_b, pre1r},
        GOut{wt1r, l1r_b, pre1r}, 2, 480, 1024, 512, FLAG_OUTF32, 1);
  lstm_persistent_kernel<256><<<8,256,0,stream>>>(
      pre1f, pre1r, whT1f, whT1r, hb1, x1, flags1, 8, 512, 0, 256);

  // ---- LSTM stack 2 (H=512): 16 blocks x 32 H-cols ----
  gemm3(x1, GOut{wt2f, l2f_b, pre2f}, GOut{wt2r, l2r_b, pre2r},
        GOut{wt2r, l2r_b, pre2r}, 2, 480, 2048, 512, FLAG_OUTF32, 1);
  lstm_persistent_kernel<512><<<16,256,0,stream>>>(
      pre2f, pre2r, whT2f, whT2r, hb2, x2, flags2, 16, 1024, 512, 0);

  // ---- classifier ----
  gemm3(x2, GOut{wto, bo, outp}, GOut{wto, bo, outp}, GOut{wto, bo, outp}, 1,
        480, 1000, 1024, FLAG_OUTF32, 1);
}

// Round 7
// 1033.638 us; speedup vs baseline: 1.4113x; 1.1268x over previous
//
#include <hip/hip_runtime.h>
#include <math.h>

#define DIV_UP(a,b) (((a)+(b)-1)/(b))

typedef _Float16 half_t;
typedef _Float16 half8 __attribute__((ext_vector_type(8)));
typedef float f32x4 __attribute__((ext_vector_type(4)));

#define FLAG_RELU   1
#define FLAG_OUTF32 2
#define FLAG_SPLITK 4
#define FLAG_ATOMIC 8
#define FLAG_BNSUMS 16

#define GLDS16(src, dst) \
  __builtin_amdgcn_global_load_lds((const __attribute__((address_space(1))) void*)(src), \
                                   (__attribute__((address_space(3))) void*)(dst), 16, 0, 0)

__device__ __forceinline__ float fsig_(float x){ return 1.0f/(1.0f+__expf(-x)); }
__device__ __forceinline__ float ftanh_(float x){
  float ax = fabsf(x);
  float e = __expf(-2.0f*ax);
  float t = (1.0f - e)/(1.0f + e);
  return copysignf(t, x);
}

// ------------------------------------------------------------------
// ALL weight transposes (fp32 [K][N] -> fp16 [N][K]) in ONE launch.
// ------------------------------------------------------------------
#define NTP 18
struct TpAll {
  const float* src[NTP];
  half_t* dst[NTP];
  int K[NTP];
  int N[NTP];
  int prefix[NTP+1];
};

__global__ __launch_bounds__(256) void transpose_cvt_all_kernel(TpAll a)
{
  __shared__ float tile[32][33];
  int bid = blockIdx.x;
  int z = 0;
  while (bid >= a.prefix[z+1]) ++z;
  int local = bid - a.prefix[z];
  const float* w = a.src[z];
  half_t* wT = a.dst[z];
  int K = a.K[z], N = a.N[z];
  int tilesX = (N + 31) >> 5;
  int nt = (local % tilesX) * 32;
  int kt = (local / tilesX) * 32;
  int tx = threadIdx.x & 31, ty = threadIdx.x >> 5;
  #pragma unroll
  for (int r = 0; r < 4; ++r) {
    int k = kt + ty + r*8, n = nt + tx;
    tile[ty + r*8][tx] = (k < K && n < N) ? w[(long)k*N + n] : 0.f;
  }
  __syncthreads();
  #pragma unroll
  for (int r = 0; r < 4; ++r) {
    int n = nt + ty + r*8, k = kt + tx;
    if (n < N && k < K) wT[(long)n*K + k] = (half_t)tile[tx][ty + r*8];
  }
}

// ------------------------------------------------------------------
// conv1 special case: x (32,64,256,3) fp32, w (3,3,3,64), out fp16 + ReLU.
// ------------------------------------------------------------------
__global__ __launch_bounds__(256) void conv1_kernel(
    const float* __restrict__ x, const float* __restrict__ w,
    const float* __restrict__ bias, half_t* __restrict__ out)
{
  __shared__ float xs[3][258*3];
  int nb = blockIdx.x;            // n*64 + ho
  int n = nb >> 6, ho = nb & 63;
  int tid = threadIdx.x;
  int co = tid & 63;
  float wreg[27];
  #pragma unroll
  for (int k = 0; k < 27; ++k) wreg[k] = w[k*64 + co];
  float bco = bias[co];
  for (int i = tid; i < 3*258*3; i += 256) {
    int row = i / (258*3); int rem = i % (258*3);
    int col = rem / 3;     int ci  = rem % 3;
    int ih = ho - 1 + row; int iw = col - 1;
    float v = 0.f;
    if (ih >= 0 && ih < 64 && iw >= 0 && iw < 256)
      v = x[(((long)n*64 + ih)*256 + iw)*3 + ci];
    xs[row][col*3 + ci] = v;
  }
  __syncthreads();
  int wave = tid >> 6;
  for (int p = 0; p < 64; ++p) {
    int wo = wave*64 + p;
    float acc = bco;
    #pragma unroll
    for (int kh = 0; kh < 3; ++kh)
      #pragma unroll
      for (int kw = 0; kw < 3; ++kw)
        #pragma unroll
        for (int ci = 0; ci < 3; ++ci)
          acc = fmaf(xs[kh][(wo+kw)*3 + ci], wreg[(kh*3+kw)*3 + ci], acc);
    acc = fmaxf(acc, 0.f);
    out[(((long)n*64 + ho)*256 + wo)*64 + co] = (half_t)acc;
  }
}

// ------------------------------------------------------------------
// MFMA implicit-GEMM conv/GEMM. 128x128 tile, BK=64, 4 waves.
// R3: XCD-aware bijective remap (FETCH 281->27MB on conv6).
// R4: single-barrier double-buffered K-loop (latency hiding).
// ------------------------------------------------------------------
struct GOut { const half_t* wT; const float* bias; void* out; };

__global__ __launch_bounds__(256) void mfma_conv_kernel(
    const half_t* __restrict__ x, GOut g0, GOut g1, GOut g2,
    const half_t* __restrict__ zbuf, float* __restrict__ bns,
    int N,int H,int W,int Ci,int Ho,int Wo,int Co,
    int KH,int KW,int padH,int padW,
    int M,int K,int flags,int splitS)
{
  GOut g;
  int ciBeg = 0, ciEnd = Ci;
  if (flags & FLAG_SPLITK) {
    g = g0;
    int span = Ci / splitS;
    ciBeg = blockIdx.z * span;
    ciEnd = ciBeg + span;
  } else {
    g = (blockIdx.z == 0) ? g0 : (blockIdx.z == 1 ? g1 : g2);
  }
  const half_t* __restrict__ wT = g.wT;
  __shared__ half_t As[2][128*64];
  __shared__ half_t Bs[2][128*64];
  int tid = threadIdx.x;

  // ---- XCD-aware bijective remap: slot -> work (m-major, n fastest) ----
  int nbx = gridDim.x, nby = gridDim.y;
  int total = nbx * nby;
  int flat = blockIdx.y * nbx + blockIdx.x;   // dispatch slot within z-slice
  int q = total >> 3, r = total & 7;
  int xcd = flat & 7;                          // hw XCD (round-robin heuristic)
  int j = flat >> 3;                           // j-th slot on that XCD
  int w = xcd * q + (xcd < r ? xcd : r) + j;   // contiguous work band per XCD
  int m0 = (w / nbx) * 128, n0 = (w % nbx) * 128;

  int wave = tid >> 6, lane = tid & 63;
  int l15 = lane & 15, quad = lane >> 4;
  int x7 = lane & 7;
  int wm = (wave & 1) * 64, wn = (wave >> 1) * 64;

  // staging decode: 4 issues, row_i = i*32 + (tid>>3), source chunk swizzled
  int rSub = tid >> 3;
  int colHalf = (((tid & 7) ^ (rSub & 7))) * 8;

  int ho_[4], wo_[4], ni_[4]; bool av_[4];
  #pragma unroll
  for (int i = 0; i < 4; ++i) {
    int m = m0 + i*32 + rSub;
    av_[i] = m < M;
    int mm = av_[i] ? m : 0;
    wo_[i] = mm % Wo; int t2 = mm / Wo;
    ho_[i] = t2 % Ho; ni_[i] = t2 / Ho;
  }
  const half_t* bBase[4];
  #pragma unroll
  for (int i = 0; i < 4; ++i) {
    int n = n0 + i*32 + rSub;
    bBase[i] = (n < Co) ? (wT + (long)n*K + colHalf) : nullptr;
  }

  // fragment LDS chunk offsets per k-sub (conflict-free via XOR swizzle)
  int pch0 = ((quad)     ^ x7) * 8;
  int pch1 = ((4 + quad) ^ x7) * 8;

  f32x4 acc[4][4];
  #pragma unroll
  for (int i = 0; i < 4; ++i)
    #pragma unroll
    for (int j2 = 0; j2 < 4; ++j2)
      acc[i][j2] = (f32x4){0.f, 0.f, 0.f, 0.f};

  // ---- staging state: running (skh, skw, sci) k-tile coordinates ----
  int NT = ((ciEnd - ciBeg) >> 6) * KH * KW;
  int skh = 0, skw = 0, sci = ciBeg;
  long sAOff[4]; bool sAval[4];
  auto recompA = [&]() {
    #pragma unroll
    for (int i = 0; i < 4; ++i) {
      int ih = ho_[i] - padH + skh, iw = wo_[i] - padW + skw;
      bool ok = av_[i] && ih >= 0 && ih < H && iw >= 0 && iw < W;
      sAval[i] = ok;
      sAOff[i] = ok ? ((((long)ni_[i]*H + ih)*W + iw)*(long)Ci + colHalf) : 0;
    }
  };
  recompA();
  auto stage = [&](int b) {
    int kgS = (skh*KW + skw)*Ci + sci;           // global B k-index
    #pragma unroll
    for (int i = 0; i < 4; ++i) {
      const half_t* sa = sAval[i] ? (x + sAOff[i] + sci) : zbuf;
      GLDS16(sa, &As[b][i*2048 + wave*512]);
      const half_t* sb = bBase[i] ? (bBase[i] + kgS) : zbuf;
      GLDS16(sb, &Bs[b][i*2048 + wave*512]);
    }
  };
  auto advance = [&]() {
    sci += 64;
    if (sci == ciEnd) {
      sci = ciBeg; ++skw;
      if (skw == KW) { skw = 0; ++skh; }
      recompA();
    }
  };

  stage(0); advance();
  __syncthreads();                 // drains vmcnt(0): buf0 ready

  for (int kt = 0; kt < NT; ++kt) {
    int p = kt & 1;
    if (kt + 1 < NT) { stage(p ^ 1); advance(); }   // prefetch under MFMA
    {
      half8 af[4], bf[4];
      #pragma unroll
      for (int i = 0; i < 4; ++i)
        af[i] = *reinterpret_cast<half8*>(&As[p][(wm + i*16 + l15)*64 + pch0]);
      #pragma unroll
      for (int j2 = 0; j2 < 4; ++j2)
        bf[j2] = *reinterpret_cast<half8*>(&Bs[p][(wn + j2*16 + l15)*64 + pch0]);
      #pragma unroll
      for (int i = 0; i < 4; ++i)
        #pragma unroll
        for (int j2 = 0; j2 < 4; ++j2)
          acc[i][j2] = __builtin_amdgcn_mfma_f32_16x16x32_f16(af[i], bf[j2], acc[i][j2], 0, 0, 0);
    }
    {
      half8 af[4], bf[4];
      #pragma unroll
      for (int i = 0; i < 4; ++i)
        af[i] = *reinterpret_cast<half8*>(&As[p][(wm + i*16 + l15)*64 + pch1]);
      #pragma unroll
      for (int j2 = 0; j2 < 4; ++j2)
        bf[j2] = *reinterpret_cast<half8*>(&Bs[p][(wn + j2*16 + l15)*64 + pch1]);
      #pragma unroll
      for (int i = 0; i < 4; ++i)
        #pragma unroll
        for (int j2 = 0; j2 < 4; ++j2)
          acc[i][j2] = __builtin_amdgcn_mfma_f32_16x16x32_f16(af[i], bf[j2], acc[i][j2], 0, 0, 0);
    }
    __syncthreads();               // one barrier per K-step (drains vmcnt too)
  }

  // ---- BN sums from accumulators (f32, pre-relu value incl. bias) ----
  if (flags & FLAG_BNSUMS) {
    float* red = (float*)As;     // [wave][quad][l15][j][2] = 4*4*16*4*2 floats
    #pragma unroll
    for (int j2 = 0; j2 < 4; ++j2) {
      int n = n0 + wn + j2*16 + l15;
      float bv = g.bias[n];
      float s = 0.f, qq = 0.f;
      #pragma unroll
      for (int i = 0; i < 4; ++i)
        #pragma unroll
        for (int rr = 0; rr < 4; ++rr) {
          int m = m0 + wm + i*16 + quad*4 + rr;
          if (m < M) { float v = acc[i][j2][rr] + bv; s += v; qq += v*v; }
        }
      int idx = ((((wave*4 + quad)*16 + l15)*4) + j2)*2;
      red[idx] = s; red[idx+1] = qq;
    }
    __syncthreads();
    if (tid < 128) {
      int hi = tid >> 6;               // which 64-channel half (wn)
      int jj = (tid >> 4) & 3, ll = tid & 15;
      float s = 0.f, qq = 0.f;
      #pragma unroll
      for (int w2 = 0; w2 < 2; ++w2)
        #pragma unroll
        for (int qd = 0; qd < 4; ++qd) {
          int idx = (((((hi*2 + w2)*4 + qd)*16 + ll)*4) + jj)*2;
          s += red[idx]; qq += red[idx+1];
        }
      int n = n0 + tid;                // == n0 + hi*64 + jj*16 + ll
      atomicAdd(&bns[n], s);
      atomicAdd(&bns[Co + n], qq);
    }
  }

  // ---- store ----
  #pragma unroll
  for (int i = 0; i < 4; ++i) {
    #pragma unroll
    for (int rr = 0; rr < 4; ++rr) {
      int m = m0 + wm + i*16 + quad*4 + rr;
      if (m >= M) continue;
      #pragma unroll
      for (int j2 = 0; j2 < 4; ++j2) {
        int n = n0 + wn + j2*16 + l15;
        if (n >= Co) continue;
        if (flags & FLAG_ATOMIC) {
          atomicAdd(&((float*)g.out)[(long)m*Co + n], acc[i][j2][rr]);
        } else {
          float v = acc[i][j2][rr] + g.bias[n];
          if (flags & FLAG_RELU) v = fmaxf(v, 0.f);
          if (flags & FLAG_OUTF32) ((float*)g.out)[(long)m*Co + n] = v;
          else ((half_t*)g.out)[(long)m*Co + n] = (half_t)v;
        }
      }
    }
  }
}

// ------------------------------------------------------------------
// Max pool fp16, NHWC, 8 channels per thread.
// ------------------------------------------------------------------
__global__ __launch_bounds__(256) void maxpool8_kernel(
    const half_t* __restrict__ x, half_t* __restrict__ out,
    int N,int H,int W,int C,int Ho,int Wo,int sH,int sW)
{
  int C8 = C >> 3;
  long idx = (long)blockIdx.x*256 + threadIdx.x;
  long total8 = (long)N*Ho*Wo*C8;
  if (idx >= total8) return;
  int cb = (int)(idx % C8);
  long pix = idx / C8;
  int wo = (int)(pix % Wo); long t2 = pix / Wo;
  int ho = (int)(t2 % Ho); int n = (int)(t2 / Ho);
  int c = cb * 8;
  float m[8];
  #pragma unroll
  for (int e = 0; e < 8; ++e) m[e] = -INFINITY;
  for (int i = 0; i < 2; ++i) {
    int ih = ho*sH + i;
    if (ih >= H) continue;
    for (int j = 0; j < 2; ++j) {
      int iw = wo*sW + j;
      if (iw >= W) continue;
      half8 v = *reinterpret_cast<const half8*>(x + (((long)n*H + ih)*W + iw)*C + c);
      #pragma unroll
      for (int e = 0; e < 8; ++e) m[e] = fmaxf(m[e], (float)v[e]);
    }
  }
  half8 o;
  #pragma unroll
  for (int e = 0; e < 8; ++e) o[e] = (half_t)m[e];
  *reinterpret_cast<half8*>(out + idx*8) = o;
}

// ------------------------------------------------------------------
// BN apply + ReLU (in place), 8 channels/thread.
// ------------------------------------------------------------------
__global__ __launch_bounds__(256) void bn_apply_relu8_kernel(
    half_t* __restrict__ x, const float* __restrict__ sums,
    const float* __restrict__ scale, const float* __restrict__ bias,
    long total8, int C, float invN)
{
  long idx = (long)blockIdx.x*256 + threadIdx.x;
  if (idx >= total8) return;
  int c = (int)((idx*8) % C);
  half8 v = *reinterpret_cast<half8*>(x + idx*8);
  half8 o;
  #pragma unroll
  for (int e = 0; e < 8; ++e) {
    float mean = sums[c+e] * invN;
    float var  = sums[C + c+e] * invN - mean*mean;
    float rstd = rsqrtf(var + 1e-5f);
    float y = ((float)v[e] - mean) * rstd * scale[c+e] + bias[c+e];
    o[e] = (half_t)fmaxf(y, 0.0f);
  }
  *reinterpret_cast<half8*>(x + idx*8) = o;
}

// ------------------------------------------------------------------
// Fused BN+ReLU+maxpool: out (N,Ho,Wo,C) from in (N,H,W,C).
// ------------------------------------------------------------------
__global__ __launch_bounds__(256) void bn_pool8_kernel(
    const half_t* __restrict__ x, half_t* __restrict__ out,
    const float* __restrict__ sums, const float* __restrict__ scale,
    const float* __restrict__ bias,
    int N,int H,int W,int C,int Ho,int Wo,int sH,int sW, float invN)
{
  int C8 = C >> 3;
  long idx = (long)blockIdx.x*256 + threadIdx.x;
  long total8 = (long)N*Ho*Wo*C8;
  if (idx >= total8) return;
  int cb = (int)(idx % C8);
  long pix = idx / C8;
  int wo = (int)(pix % Wo); long t2 = pix / Wo;
  int ho = (int)(t2 % Ho); int n = (int)(t2 / Ho);
  int c = cb * 8;
  float mean[8], rs[8], bb[8];
  #pragma unroll
  for (int e = 0; e < 8; ++e) {
    mean[e] = sums[c+e] * invN;
    float var = sums[C + c+e] * invN - mean[e]*mean[e];
    rs[e] = rsqrtf(var + 1e-5f) * scale[c+e];
    bb[e] = bias[c+e];
  }
  float m[8];
  #pragma unroll
  for (int e = 0; e < 8; ++e) m[e] = -INFINITY;
  for (int i = 0; i < 2; ++i) {
    int ih = ho*sH + i;
    if (ih >= H) continue;
    for (int j = 0; j < 2; ++j) {
      int iw = wo*sW + j;
      if (iw >= W) continue;
      half8 v = *reinterpret_cast<const half8*>(x + (((long)n*H + ih)*W + iw)*C + c);
      #pragma unroll
      for (int e = 0; e < 8; ++e) {
        float y = fmaxf(((float)v[e] - mean[e]) * rs[e] + bb[e], 0.f);
        m[e] = fmaxf(m[e], y);
      }
    }
  }
  half8 o;
  #pragma unroll
  for (int e = 0; e < 8; ++e) o[e] = (half_t)m[e];
  *reinterpret_cast<half8*>(out + idx*8) = o;
}

// ------------------------------------------------------------------
// Bias prefill for the split-K qkv GEMM output (480 x 1536 f32).
// ------------------------------------------------------------------
__global__ __launch_bounds__(256) void bias_fill_kernel(
    float* __restrict__ out, const float* __restrict__ b0,
    const float* __restrict__ b1, const float* __restrict__ b2, int total)
{
  int idx = blockIdx.x*256 + threadIdx.x;
  if (idx >= total) return;
  int n = idx % 1536;
  float v = (n < 512) ? b0[n] : (n < 1024 ? b1[n-512] : b2[n-1024]);
  out[idx] = v;
}

// ------------------------------------------------------------------
// Attention (T=15, D=512), qkv interleaved f32 rows of ld=1536, out fp16.
// ------------------------------------------------------------------
__global__ __launch_bounds__(256) void attention_kernel(
    const float* __restrict__ qkv, half_t* __restrict__ out,
    int T, int D, int ld)
{
  int b = blockIdx.x;
  int tid = threadIdx.x;
  __shared__ float P[15][16];
  if (tid < T*T) {
    int t = tid / T, s = tid % T;
    const float* qp = qkv + ((long)b*T + t)*ld;
    const float* kp = qkv + ((long)b*T + s)*ld + 512;
    float acc = 0.f;
    for (int d = 0; d < D; d += 4) {
      float4 qv = *reinterpret_cast<const float4*>(qp + d);
      float4 kv = *reinterpret_cast<const float4*>(kp + d);
      acc += qv.x*kv.x + qv.y*kv.y + qv.z*kv.z + qv.w*kv.w;
    }
    P[t][s] = acc * (1.0f/32.0f);
  }
  __syncthreads();
  if (tid < T) {
    float mx = -INFINITY;
    for (int s = 0; s < T; ++s) mx = fmaxf(mx, P[tid][s]);
    float sum = 0.f;
    for (int s = 0; s < T; ++s) { float e = expf(P[tid][s] - mx); P[tid][s] = e; sum += e; }
    float inv = 1.0f / sum;
    for (int s = 0; s < T; ++s) P[tid][s] *= inv;
  }
  __syncthreads();
  for (int idx = tid; idx < T*D; idx += 256) {
    int s = idx / D, kk2 = idx % D;
    float acc = 0.f;
    #pragma unroll
    for (int t = 0; t < 15; ++t)
      acc += qkv[((long)b*T + t)*ld + 1024 + kk2] * P[t][s];
    out[((long)b*T + s)*D + kk2] = (half_t)acc;
  }
}

// ------------------------------------------------------------------
// Persistent bidirectional LSTM — R7: EXACT R4 structure (loadw/wreg,
// bottom poll by wave 0; measured 104.9us for H=512) + ONE variable:
// XCD-pinning. Launch 8x blocks; only blockIdx%8==0 work (dispatch
// slot%8 = XCD heuristic, validated by R3's remap on this machine).
// All workers then share ONE XCD's L2 (internally coherent), so the
// h-broadcast + flag round trips are L2-latency instead of die-level
// LLC. Correctness is placement-independent (agent-scope atomics);
// worst case = spread workers = R4 behavior.
// ------------------------------------------------------------------
#define MAXK 512
#define HSROW (MAXK + 8)

template<int N64, int HLOG>
__device__ __forceinline__ void stage_h(
    const unsigned long long* __restrict__ src, half_t (*hs)[HSROW], int tid)
{
  unsigned long long tmp[N64];
  #pragma unroll
  for (int u = 0; u < N64; ++u)
    tmp[u] = __hip_atomic_load(src + tid + u*256, __ATOMIC_RELAXED, __HIP_MEMORY_SCOPE_AGENT);
  #pragma unroll
  for (int u = 0; u < N64; ++u) {
    int idx = tid + u*256;
    int row = idx >> (HLOG - 2);
    int col = (idx & ((1 << (HLOG - 2)) - 1)) * 4;
    *reinterpret_cast<unsigned long long*>(&hs[row][col]) = tmp[u];
  }
}

template<int H>
__global__ __launch_bounds__(256, 1) void lstm_persistent_kernel(
    const float* __restrict__ preF, const float* __restrict__ preR,
    const half_t* __restrict__ whTF, const half_t* __restrict__ whTR,
    half_t* __restrict__ hbuf, half_t* __restrict__ y,
    int* __restrict__ flags, int nblk,
    int ystride, int yoffF, int yoffR)
{
  if (blockIdx.x & 7) return;      // XCD-pin: keep slot%8==0 -> one XCD
  int wid = blockIdx.x >> 3;       // worker id 0..nblk-1

  constexpr int KI = H / 32;      // k-chunks of 32
  __shared__ half_t hs[32][HSROW];
  __shared__ float gates[32][133]; // [batch][gate*32 + hcol]
  int tid = threadIdx.x;
  int jb0 = wid * 32;              // 32 H-columns per worker
  int lane = tid & 63, wave = tid >> 6;   // wave == gate index
  int l15 = lane & 15, quad = lane >> 4;
  int bb = tid >> 3;               // batch row for elementwise
  int jj0 = (tid & 7) * 4;         // 4 H-cols per thread
  constexpr int H4 = 4 * H;

  float cst[4] = {0.f, 0.f, 0.f, 0.f};
  half8 wreg[2][KI];               // B fragments: [col frag][k chunk]

  auto loadw = [&](const half_t* __restrict__ whT) {
    #pragma unroll
    for (int f = 0; f < 2; ++f) {
      const half_t* wp = whT + (long)(wave*H + jb0 + f*16 + l15)*H + quad*8;
      #pragma unroll
      for (int i = 0; i < KI; ++i)
        wreg[f][i] = *reinterpret_cast<const half8*>(wp + i*32);
    }
  };

  auto loadpv = [&](int s, float (&pv)[16]) {
    const float* pr = (s < 15) ? preF : preR;
    int t = (s < 15) ? s : 29 - s;
    const float* pp = pr + (long)(bb*15 + t)*H4 + jb0 + jj0;
    #pragma unroll
    for (int g = 0; g < 4; ++g) {
      f32x4 v = *reinterpret_cast<const f32x4*>(pp + g*H);
      pv[g*4+0] = v[0]; pv[g*4+1] = v[1]; pv[g*4+2] = v[2]; pv[g*4+3] = v[3];
    }
  };

  loadw(whTF);
  float pv[16];
  loadpv(0, pv);

  for (int s = 0; s < 30; ++s) {
    if (s == 15) loadw(whTR);      // reverse direction: carry (cst) continues
    int t = (s < 15) ? s : 29 - s;
    int yoff = (s < 15) ? yoffF : yoffR;

    const unsigned long long* hsrc =
        (const unsigned long long*)(hbuf + (long)(s & 1) * 32 * H);
    if constexpr (H == 512) stage_h<16, 9>(hsrc, hs, tid);
    else                    stage_h<8, 8>(hsrc, hs, tid);
    __syncthreads();

    f32x4 acc00 = {0.f,0.f,0.f,0.f}, acc10 = {0.f,0.f,0.f,0.f};
    f32x4 acc01 = {0.f,0.f,0.f,0.f}, acc11 = {0.f,0.f,0.f,0.f};
    #pragma unroll
    for (int i = 0; i < KI; ++i) {
      half8 a0 = *reinterpret_cast<half8*>(&hs[l15][i*32 + quad*8]);
      half8 a1 = *reinterpret_cast<half8*>(&hs[16 + l15][i*32 + quad*8]);
      acc00 = __builtin_amdgcn_mfma_f32_16x16x32_f16(a0, wreg[0][i], acc00, 0, 0, 0);
      acc10 = __builtin_amdgcn_mfma_f32_16x16x32_f16(a1, wreg[0][i], acc10, 0, 0, 0);
      acc01 = __builtin_amdgcn_mfma_f32_16x16x32_f16(a0, wreg[1][i], acc01, 0, 0, 0);
      acc11 = __builtin_amdgcn_mfma_f32_16x16x32_f16(a1, wreg[1][i], acc11, 0, 0, 0);
    }
    #pragma unroll
    for (int r = 0; r < 4; ++r) {
      gates[quad*4 + r][wave*32 + l15]           = acc00[r];
      gates[16 + quad*4 + r][wave*32 + l15]      = acc10[r];
      gates[quad*4 + r][wave*32 + 16 + l15]      = acc01[r];
      gates[16 + quad*4 + r][wave*32 + 16 + l15] = acc11[r];
    }
    __syncthreads();

    unsigned long long hpack;
    {
      half_t hn[4];
      #pragma unroll
      for (int p = 0; p < 4; ++p) {
        int j = jj0 + p;
        float gi = pv[p]      + gates[bb][j];
        float gf = pv[4 + p]  + gates[bb][32 + j];
        float gg = pv[8 + p]  + gates[bb][64 + j];
        float go = pv[12 + p] + gates[bb][96 + j];
        gi = fsig_(gi); gf = fsig_(gf); gg = ftanh_(gg); go = fsig_(go);
        float cn = gf * cst[p] + gi * gg;
        cst[p] = cn;
        hn[p] = (half_t)(go * ftanh_(cn));
      }
      hpack = *reinterpret_cast<unsigned long long*>(hn);
      half_t* hdst = hbuf + (long)((s + 1) & 1) * 32 * H;
      __hip_atomic_store((unsigned long long*)(hdst + (long)bb*H + jb0 + jj0), hpack,
                         __ATOMIC_RELAXED, __HIP_MEMORY_SCOPE_AGENT);
    }

    if (s < 29) {
      __syncthreads();             // drains vmcnt -> h stores visible
      if (tid == 0)
        __hip_atomic_store(&flags[wid], s + 1,
                           __ATOMIC_RELAXED, __HIP_MEMORY_SCOPE_AGENT);
      *reinterpret_cast<unsigned long long*>(
          &y[(long)(bb*15 + t)*ystride + yoff + jb0 + jj0]) = hpack;
      loadpv(s + 1, pv);           // prefetch next pv under the spin-wait
      if (tid < 64) {
        int target = s + 1;
        for (;;) {
          int vv = (tid < nblk)
            ? __hip_atomic_load(&flags[tid], __ATOMIC_RELAXED, __HIP_MEMORY_SCOPE_AGENT)
            : target;
          if (__all(vv >= target)) break;
        }
      }
      __syncthreads();
    } else {
      *reinterpret_cast<unsigned long long*>(
          &y[(long)(bb*15 + t)*ystride + yoff + jb0 + jj0]) = hpack;
    }
  }
}

// ------------------------------------------------------------------
// Host orchestration
// ------------------------------------------------------------------
extern "C" void kernel_launch(void* const* d_in, const int* in_sizes, int n_in,
                              void* d_out, int out_size, void* d_ws, size_t ws_size,
                              hipStream_t stream)
{
  const float* x       = (const float*)d_in[0];
  const float* c1w     = (const float*)d_in[1];  const float* c1b = (const float*)d_in[2];
  const float* c2w     = (const float*)d_in[3];  const float* c2b = (const float*)d_in[4];
  const float* c3w     = (const float*)d_in[5];  const float* c3b = (const float*)d_in[6];
  const float* bn1s    = (const float*)d_in[7];  const float* bn1b = (const float*)d_in[8];
  const float* c4w     = (const float*)d_in[9];  const float* c4b = (const float*)d_in[10];
  const float* bn2s    = (const float*)d_in[11]; const float* bn2b = (const float*)d_in[12];
  const float* c5w     = (const float*)d_in[13]; const float* c5b = (const float*)d_in[14];
  const float* bn3s    = (const float*)d_in[15]; const float* bn3b = (const float*)d_in[16];
  const float* c6w     = (const float*)d_in[17]; const float* c6b = (const float*)d_in[18];
  const float* bn4s    = (const float*)d_in[19]; const float* bn4b = (const float*)d_in[20];
  const float* c7w     = (const float*)d_in[21]; const float* c7b = (const float*)d_in[22];
  const float* bn5s    = (const float*)d_in[23]; const float* bn5b = (const float*)d_in[24];
  const float* wq      = (const float*)d_in[25]; const float* bq = (const float*)d_in[26];
  const float* wk      = (const float*)d_in[27]; const float* bk = (const float*)d_in[28];
  const float* wv      = (const float*)d_in[29]; const float* bv = (const float*)d_in[30];
  const float* l1f_wx  = (const float*)d_in[31]; const float* l1f_wh = (const float*)d_in[32]; const float* l1f_b = (const float*)d_in[33];
  const float* l1r_wx  = (const float*)d_in[34]; const float* l1r_wh = (const float*)d_in[35]; const float* l1r_b = (const float*)d_in[36];
  const float* l2f_wx  = (const float*)d_in[37]; const float* l2f_wh = (const float*)d_in[38]; const float* l2f_b = (const float*)d_in[39];
  const float* l2r_wx  = (const float*)d_in[40]; const float* l2r_wh = (const float*)d_in[41]; const float* l2r_b = (const float*)d_in[42];
  const float* wo      = (const float*)d_in[43]; const float* bo = (const float*)d_in[44];
  float* outp = (float*)d_out;

  char* base = (char*)d_ws;
  half_t* actA = (half_t*)base;
  half_t* actB = (half_t*)(base + 67108864);
  half_t* wtA  = (half_t*)(base + 100663296);
  float*  f32a = (float*)(base + 143687680);
  half_t* h16a = (half_t*)(base + 158736384);

  half_t* wt2  = wtA;
  half_t* wt3  = wtA + 73728;
  half_t* wt4  = wtA + 368640;
  half_t* wt5  = wtA + 958464;
  half_t* wt6  = wtA + 2138112;
  half_t* wt7  = wtA + 4497408;
  half_t* wtq  = wtA + 5545984;        // wtq|wtk|wtv contiguous -> [1536][7680]
  half_t* wtk  = wtA + 9478144;
  half_t* wtv  = wtA + 13410304;
  half_t* wt1f = wtA + 17342464;
  half_t* wt1r = wtA + 17866752;
  half_t* wt2f = wtA + 18391040;
  half_t* wt2r = wtA + 19439616;
  half_t* wto  = wtA + 20488192;

  float* qkvbuf = f32a;                // 480 x 1536 f32
  float* pre1f = f32a + 737280;
  float* pre1r = f32a + 1228800;
  float* pre2f = f32a + 1720320;
  float* pre2r = f32a + 2703360;

  half_t* ao  = h16a;
  half_t* x1  = h16a + 245760;
  half_t* x2  = h16a + 491520;
  half_t* hb1 = h16a + 983040;              // 2 x 32 x 256 fp16
  half_t* hb2 = hb1 + 16384;                // 2 x 32 x 512 fp16
  int*    flags1 = (int*)(hb2 + 32768);     // 512 ints
  int*    flags2 = flags1 + 512;
  half_t* zbuf   = (half_t*)(flags2 + 512); // 32 halves
  float*  bnz    = (float*)(zbuf + 32);     // 5 x 2048 floats

  // transposed fp16 LSTM recurrent weights [4H][H] (appended past bnz)
  half_t* whT1f = (half_t*)(base + 160849920);   // 1024x256 = 512KB
  half_t* whT1r = (half_t*)(base + 161374208);
  half_t* whT2f = (half_t*)(base + 161898496);   // 2048x512 = 2MB
  half_t* whT2r = (half_t*)(base + 163995648);   // end 166,092,800

  auto convm = [&](const half_t* in, const half_t* wt, const float* b, void* out,
                   int N,int H,int W,int Ci,int Ho,int Wo,int Co,
                   int KH,int KW,int pH,int pW,int flags, float* bns){
    int M = N*Ho*Wo, K = KH*KW*Ci;
    dim3 grid(DIV_UP(Co,128), DIV_UP(M,128), 1);
    GOut g{wt, b, out};
    mfma_conv_kernel<<<grid,256,0,stream>>>(in,g,g,g,zbuf,bns,N,H,W,Ci,Ho,Wo,Co,
                                            KH,KW,pH,pW,M,K,flags,1);
  };
  auto gemm3 = [&](const half_t* A, GOut g0, GOut g1, GOut g2, int nz,
                   int M, int Nn, int K, int flags, int splitS){
    dim3 grid(DIV_UP(Nn,128), DIV_UP(M,128), nz);
    mfma_conv_kernel<<<grid,256,0,stream>>>(A,g0,g1,g2,zbuf,bnz,M,1,1,K,1,1,Nn,
                                            1,1,0,0,M,K,flags,splitS);
  };
  auto pool = [&](const half_t* in, half_t* out, int N,int H,int W,int C,
                  int Ho,int Wo,int sH,int sW){
    long total8 = (long)N*Ho*Wo*(C/8);
    maxpool8_kernel<<<(int)DIV_UP(total8,256),256,0,stream>>>(in,out,N,H,W,C,Ho,Wo,sH,sW);
  };
  auto bnApply = [&](half_t* buf, long nPix, int C, const float* s, const float* b,
                     float* sums){
    long total8 = nPix * C / 8;
    bn_apply_relu8_kernel<<<(int)DIV_UP(total8,256),256,0,stream>>>(buf, sums, s, b, total8, C, 1.0f/(float)nPix);
  };
  auto bnPool = [&](const half_t* in, half_t* out, int N,int H,int W,int C,
                    int Ho,int Wo,int sH,int sW, long nPix,
                    const float* s, const float* b, float* sums){
    long total8 = (long)N*Ho*Wo*(C/8);
    bn_pool8_kernel<<<(int)DIV_UP(total8,256),256,0,stream>>>(
        in,out,sums,s,b,N,H,W,C,Ho,Wo,sH,sW,1.0f/(float)nPix);
  };

  // one zero-fill: hb1/hb2, flags, zbuf, 5 bn-sum buffers
  hipMemsetAsync(hb1, 0, 143424, stream);

  // ---- ALL weight transposes in one launch (incl. LSTM Wh -> fp16 [4H][H]) ----
  {
    TpAll tp;
    const float* srcs[NTP] = {c2w,c3w,c4w,c5w,c6w,c7w,wq,wk,wv,l1f_wx,l1r_wx,l2f_wx,l2r_wx,wo,
                              l1f_wh,l1r_wh,l2f_wh,l2r_wh};
    half_t* dsts[NTP] = {wt2,wt3,wt4,wt5,wt6,wt7,wtq,wtk,wtv,wt1f,wt1r,wt2f,wt2r,wto,
                         whT1f,whT1r,whT2f,whT2r};
    int Ks[NTP] = {576,1152,2304,2304,4608,2048,7680,7680,7680,512,512,512,512,1024,
                   256,256,512,512};
    int Ns[NTP] = {128,256,256,512,512,512,512,512,512,1024,1024,2048,2048,1000,
                   1024,1024,2048,2048};
    int acc = 0;
    for (int i = 0; i < NTP; ++i) {
      tp.src[i] = srcs[i]; tp.dst[i] = dsts[i]; tp.K[i] = Ks[i]; tp.N[i] = Ns[i];
      tp.prefix[i] = acc;
      acc += DIV_UP(Ks[i],32) * DIV_UP(Ns[i],32);
    }
    tp.prefix[NTP] = acc;
    transpose_cvt_all_kernel<<<acc,256,0,stream>>>(tp);
  }

  // ---- conv stack (activations fp16) ----
  conv1_kernel<<<2048,256,0,stream>>>(x, c1w, c1b, actA);
  pool(actA, actB, 32,64,256,64,  32,128, 2,2);
  convm(actB, wt2, c2b, actA, 32,32,128,64,  32,128,128, 3,3,1,1, FLAG_RELU, bnz);
  pool(actA, actB, 32,32,128,128, 16,64, 2,2);
  convm(actB, wt3, c3b, actA, 32,16,64,128,  16,64,256,  3,3,1,1, FLAG_BNSUMS, bnz);
  bnApply(actA, 32768, 256, bn1s, bn1b, bnz);
  convm(actA, wt4, c4b, actB, 32,16,64,256,  16,64,256,  3,3,1,1, FLAG_BNSUMS, bnz + 2048);
  bnPool(actB, actA, 32,16,64,256, 16,32, 1,2, 32768, bn2s, bn2b, bnz + 2048);
  convm(actA, wt5, c5b, actB, 32,16,32,256,  16,32,512,  3,3,1,1, FLAG_BNSUMS, bnz + 4096);
  bnApply(actB, 16384, 512, bn3s, bn3b, bnz + 4096);
  convm(actB, wt6, c6b, actA, 32,16,32,512,  16,32,512,  3,3,1,1, FLAG_BNSUMS, bnz + 6144);
  bnPool(actA, actB, 32,16,32,512, 16,16, 1,2, 16384, bn4s, bn4b, bnz + 6144);
  convm(actB, wt7, c7b, actA, 32,16,16,512,  15,15,512,  2,2,0,0, FLAG_BNSUMS, bnz + 8192);
  bnApply(actA, 7200, 512, bn5s, bn5b, bnz + 8192);

  // ---- attention: single qkv GEMM (N=1536), split-K x4, atomic epilogue ----
  bias_fill_kernel<<<DIV_UP(480*1536,256),256,0,stream>>>(qkvbuf, bq, bk, bv, 480*1536);
  gemm3(actA, GOut{wtq, nullptr, qkvbuf}, GOut{wtq, nullptr, qkvbuf},
        GOut{wtq, nullptr, qkvbuf}, 4, 480, 1536, 7680, FLAG_SPLITK|FLAG_ATOMIC, 4);
  attention_kernel<<<32,256,0,stream>>>(qkvbuf, ao, 15, 512, 1536);

  // ---- LSTM stack 1 (H=256): 8 workers (XCD-pinned, grid 64) ----
  gemm3(ao, GOut{wt1f, l1f_b, pre1f}, GOut{wt1r, l1r_b, pre1r},
        GOut{wt1r, l1r_b, pre1r}, 2, 480, 1024, 512, FLAG_OUTF32, 1);
  lstm_persistent_kernel<256><<<64,256,0,stream>>>(
      pre1f, pre1r, whT1f, whT1r, hb1, x1, flags1, 8, 512, 0, 256);

  // ---- LSTM stack 2 (H=512): 16 workers (XCD-pinned, grid 128) ----
  gemm3(x1, GOut{wt2f, l2f_b, pre2f}, GOut{wt2r, l2r_b, pre2r},
        GOut{wt2r, l2r_b, pre2r}, 2, 480, 2048, 512, FLAG_OUTF32, 1);
  lstm_persistent_kernel<512><<<128,256,0,stream>>>(
      pre2f, pre2r, whT2f, whT2r, hb2, x2, flags2, 16, 1024, 512, 0);

  // ---- classifier ----
  gemm3(x2, GOut{wto, bo, outp}, GOut{wto, bo, outp}, GOut{wto, bo, outp}, 1,
        480, 1000, 1024, FLAG_OUTF32, 1);
}

// Round 8
// 1027.015 us; speedup vs baseline: 1.4204x; 1.0064x over previous
//
#include <hip/hip_runtime.h>
#include <math.h>

#define DIV_UP(a,b) (((a)+(b)-1)/(b))

typedef _Float16 half_t;
typedef _Float16 half8 __attribute__((ext_vector_type(8)));
typedef float f32x4 __attribute__((ext_vector_type(4)));

#define FLAG_RELU   1
#define FLAG_OUTF32 2
#define FLAG_SPLITK 4
#define FLAG_ATOMIC 8
#define FLAG_BNSUMS 16

#define GLDS16(src, dst) \
  __builtin_amdgcn_global_load_lds((const __attribute__((address_space(1))) void*)(src), \
                                   (__attribute__((address_space(3))) void*)(dst), 16, 0, 0)

__device__ __forceinline__ float fsig_(float x){ return 1.0f/(1.0f+__expf(-x)); }
__device__ __forceinline__ float ftanh_(float x){
  float ax = fabsf(x);
  float e = __expf(-2.0f*ax);
  float t = (1.0f - e)/(1.0f + e);
  return copysignf(t, x);
}

// ------------------------------------------------------------------
// ALL weight transposes (fp32 [K][N] -> fp16 [N][K]) in ONE launch.
// ------------------------------------------------------------------
#define NTP 18
struct TpAll {
  const float* src[NTP];
  half_t* dst[NTP];
  int K[NTP];
  int N[NTP];
  int prefix[NTP+1];
};

__global__ __launch_bounds__(256) void transpose_cvt_all_kernel(TpAll a)
{
  __shared__ float tile[32][33];
  int bid = blockIdx.x;
  int z = 0;
  while (bid >= a.prefix[z+1]) ++z;
  int local = bid - a.prefix[z];
  const float* w = a.src[z];
  half_t* wT = a.dst[z];
  int K = a.K[z], N = a.N[z];
  int tilesX = (N + 31) >> 5;
  int nt = (local % tilesX) * 32;
  int kt = (local / tilesX) * 32;
  int tx = threadIdx.x & 31, ty = threadIdx.x >> 5;
  #pragma unroll
  for (int r = 0; r < 4; ++r) {
    int k = kt + ty + r*8, n = nt + tx;
    tile[ty + r*8][tx] = (k < K && n < N) ? w[(long)k*N + n] : 0.f;
  }
  __syncthreads();
  #pragma unroll
  for (int r = 0; r < 4; ++r) {
    int n = nt + ty + r*8, k = kt + tx;
    if (n < N && k < K) wT[(long)n*K + k] = (half_t)tile[tx][ty + r*8];
  }
}

// ------------------------------------------------------------------
// conv1 special case: x (32,64,256,3) fp32, w (3,3,3,64), out fp16 + ReLU.
// ------------------------------------------------------------------
__global__ __launch_bounds__(256) void conv1_kernel(
    const float* __restrict__ x, const float* __restrict__ w,
    const float* __restrict__ bias, half_t* __restrict__ out)
{
  __shared__ float xs[3][258*3];
  int nb = blockIdx.x;            // n*64 + ho
  int n = nb >> 6, ho = nb & 63;
  int tid = threadIdx.x;
  int co = tid & 63;
  float wreg[27];
  #pragma unroll
  for (int k = 0; k < 27; ++k) wreg[k] = w[k*64 + co];
  float bco = bias[co];
  for (int i = tid; i < 3*258*3; i += 256) {
    int row = i / (258*3); int rem = i % (258*3);
    int col = rem / 3;     int ci  = rem % 3;
    int ih = ho - 1 + row; int iw = col - 1;
    float v = 0.f;
    if (ih >= 0 && ih < 64 && iw >= 0 && iw < 256)
      v = x[(((long)n*64 + ih)*256 + iw)*3 + ci];
    xs[row][col*3 + ci] = v;
  }
  __syncthreads();
  int wave = tid >> 6;
  for (int p = 0; p < 64; ++p) {
    int wo = wave*64 + p;
    float acc = bco;
    #pragma unroll
    for (int kh = 0; kh < 3; ++kh)
      #pragma unroll
      for (int kw = 0; kw < 3; ++kw)
        #pragma unroll
        for (int ci = 0; ci < 3; ++ci)
          acc = fmaf(xs[kh][(wo+kw)*3 + ci], wreg[(kh*3+kw)*3 + ci], acc);
    acc = fmaxf(acc, 0.f);
    out[(((long)n*64 + ho)*256 + wo)*64 + co] = (half_t)acc;
  }
}

// ------------------------------------------------------------------
// MFMA implicit-GEMM conv/GEMM. 128x128 tile, BK=64, 4 waves.
// R3: XCD-aware bijective remap (FETCH 281->27MB on conv6).
// R4: double-buffered K-loop.
// R8: COUNTED vmcnt (T4). R4's __syncthreads drained vmcnt(0) ->
//   waited for the SAME iteration's prefetch (zero hiding window,
//   ~300-600cy exposed per K-step, MfmaUtil ~30%). Now:
//     stage(p^1) -> s_waitcnt vmcnt(8) -> s_barrier -> MFMA(p) -> s_barrier
//   vmcnt(8) waits only for the PREVIOUS iteration's 8 loads (FIFO
//   oldest) which had a full iteration to land; the 8 just-issued
//   stay in flight across both barriers. Raw s_barrier (no drain);
//   "memory" fences pin ds_reads inside the [barrier, barrier] window
//   (rule #18). Reads of p complete before end barrier (lgkmcnt
//   precedes MFMA use) -> stage(p) next iteration is race-free.
// ------------------------------------------------------------------
struct GOut { const half_t* wT; const float* bias; void* out; };

__global__ __launch_bounds__(256) void mfma_conv_kernel(
    const half_t* __restrict__ x, GOut g0, GOut g1, GOut g2,
    const half_t* __restrict__ zbuf, float* __restrict__ bns,
    int N,int H,int W,int Ci,int Ho,int Wo,int Co,
    int KH,int KW,int padH,int padW,
    int M,int K,int flags,int splitS)
{
  GOut g;
  int ciBeg = 0, ciEnd = Ci;
  if (flags & FLAG_SPLITK) {
    g = g0;
    int span = Ci / splitS;
    ciBeg = blockIdx.z * span;
    ciEnd = ciBeg + span;
  } else {
    g = (blockIdx.z == 0) ? g0 : (blockIdx.z == 1 ? g1 : g2);
  }
  const half_t* __restrict__ wT = g.wT;
  __shared__ half_t As[2][128*64];
  __shared__ half_t Bs[2][128*64];
  int tid = threadIdx.x;

  // ---- XCD-aware bijective remap: slot -> work (m-major, n fastest) ----
  int nbx = gridDim.x, nby = gridDim.y;
  int total = nbx * nby;
  int flat = blockIdx.y * nbx + blockIdx.x;   // dispatch slot within z-slice
  int q = total >> 3, r = total & 7;
  int xcd = flat & 7;                          // hw XCD (round-robin heuristic)
  int j = flat >> 3;                           // j-th slot on that XCD
  int w = xcd * q + (xcd < r ? xcd : r) + j;   // contiguous work band per XCD
  int m0 = (w / nbx) * 128, n0 = (w % nbx) * 128;

  int wave = tid >> 6, lane = tid & 63;
  int l15 = lane & 15, quad = lane >> 4;
  int x7 = lane & 7;
  int wm = (wave & 1) * 64, wn = (wave >> 1) * 64;

  // staging decode: 4 issues, row_i = i*32 + (tid>>3), source chunk swizzled
  int rSub = tid >> 3;
  int colHalf = (((tid & 7) ^ (rSub & 7))) * 8;

  int ho_[4], wo_[4], ni_[4]; bool av_[4];
  #pragma unroll
  for (int i = 0; i < 4; ++i) {
    int m = m0 + i*32 + rSub;
    av_[i] = m < M;
    int mm = av_[i] ? m : 0;
    wo_[i] = mm % Wo; int t2 = mm / Wo;
    ho_[i] = t2 % Ho; ni_[i] = t2 / Ho;
  }
  const half_t* bBase[4];
  #pragma unroll
  for (int i = 0; i < 4; ++i) {
    int n = n0 + i*32 + rSub;
    bBase[i] = (n < Co) ? (wT + (long)n*K + colHalf) : nullptr;
  }

  // fragment LDS chunk offsets per k-sub (conflict-free via XOR swizzle)
  int pch0 = ((quad)     ^ x7) * 8;
  int pch1 = ((4 + quad) ^ x7) * 8;

  f32x4 acc[4][4];
  #pragma unroll
  for (int i = 0; i < 4; ++i)
    #pragma unroll
    for (int j2 = 0; j2 < 4; ++j2)
      acc[i][j2] = (f32x4){0.f, 0.f, 0.f, 0.f};

  // ---- staging state: running (skh, skw, sci) k-tile coordinates ----
  int NT = ((ciEnd - ciBeg) >> 6) * KH * KW;
  int skh = 0, skw = 0, sci = ciBeg;
  long sAOff[4]; bool sAval[4];
  auto recompA = [&]() {
    #pragma unroll
    for (int i = 0; i < 4; ++i) {
      int ih = ho_[i] - padH + skh, iw = wo_[i] - padW + skw;
      bool ok = av_[i] && ih >= 0 && ih < H && iw >= 0 && iw < W;
      sAval[i] = ok;
      sAOff[i] = ok ? ((((long)ni_[i]*H + ih)*W + iw)*(long)Ci + colHalf) : 0;
    }
  };
  recompA();
  auto stage = [&](int b) {
    int kgS = (skh*KW + skw)*Ci + sci;           // global B k-index
    #pragma unroll
    for (int i = 0; i < 4; ++i) {
      const half_t* sa = sAval[i] ? (x + sAOff[i] + sci) : zbuf;
      GLDS16(sa, &As[b][i*2048 + wave*512]);
      const half_t* sb = bBase[i] ? (bBase[i] + kgS) : zbuf;
      GLDS16(sb, &Bs[b][i*2048 + wave*512]);
    }
  };
  auto advance = [&]() {
    sci += 64;
    if (sci == ciEnd) {
      sci = ciBeg; ++skw;
      if (skw == KW) { skw = 0; ++skh; }
      recompA();
    }
  };

  stage(0); advance();             // prologue: buf0 in flight

  for (int kt = 0; kt < NT; ++kt) {
    int p = kt & 1;
    if (kt + 1 < NT) {
      stage(p ^ 1); advance();     // 8 new loads in flight (buf p^1)
      asm volatile("s_waitcnt vmcnt(8)" ::: "memory");  // wait buf p's 8 (oldest)
    } else {
      asm volatile("s_waitcnt vmcnt(0)" ::: "memory");  // last: drain
    }
    __builtin_amdgcn_s_barrier();  // all waves: buf p fully written
    asm volatile("" ::: "memory");
    {
      half8 af[4], bf[4];
      #pragma unroll
      for (int i = 0; i < 4; ++i)
        af[i] = *reinterpret_cast<half8*>(&As[p][(wm + i*16 + l15)*64 + pch0]);
      #pragma unroll
      for (int j2 = 0; j2 < 4; ++j2)
        bf[j2] = *reinterpret_cast<half8*>(&Bs[p][(wn + j2*16 + l15)*64 + pch0]);
      #pragma unroll
      for (int i = 0; i < 4; ++i)
        #pragma unroll
        for (int j2 = 0; j2 < 4; ++j2)
          acc[i][j2] = __builtin_amdgcn_mfma_f32_16x16x32_f16(af[i], bf[j2], acc[i][j2], 0, 0, 0);
    }
    {
      half8 af[4], bf[4];
      #pragma unroll
      for (int i = 0; i < 4; ++i)
        af[i] = *reinterpret_cast<half8*>(&As[p][(wm + i*16 + l15)*64 + pch1]);
      #pragma unroll
      for (int j2 = 0; j2 < 4; ++j2)
        bf[j2] = *reinterpret_cast<half8*>(&Bs[p][(wn + j2*16 + l15)*64 + pch1]);
      #pragma unroll
      for (int i = 0; i < 4; ++i)
        #pragma unroll
        for (int j2 = 0; j2 < 4; ++j2)
          acc[i][j2] = __builtin_amdgcn_mfma_f32_16x16x32_f16(af[i], bf[j2], acc[i][j2], 0, 0, 0);
    }
    asm volatile("" ::: "memory");
    __builtin_amdgcn_s_barrier();  // all waves done reading buf p
  }

  // ---- BN sums from accumulators (f32, pre-relu value incl. bias) ----
  if (flags & FLAG_BNSUMS) {
    float* red = (float*)As;     // [wave][quad][l15][j][2] = 4*4*16*4*2 floats
    #pragma unroll
    for (int j2 = 0; j2 < 4; ++j2) {
      int n = n0 + wn + j2*16 + l15;
      float bv = g.bias[n];
      float s = 0.f, qq = 0.f;
      #pragma unroll
      for (int i = 0; i < 4; ++i)
        #pragma unroll
        for (int rr = 0; rr < 4; ++rr) {
          int m = m0 + wm + i*16 + quad*4 + rr;
          if (m < M) { float v = acc[i][j2][rr] + bv; s += v; qq += v*v; }
        }
      int idx = ((((wave*4 + quad)*16 + l15)*4) + j2)*2;
      red[idx] = s; red[idx+1] = qq;
    }
    __syncthreads();
    if (tid < 128) {
      int hi = tid >> 6;               // which 64-channel half (wn)
      int jj = (tid >> 4) & 3, ll = tid & 15;
      float s = 0.f, qq = 0.f;
      #pragma unroll
      for (int w2 = 0; w2 < 2; ++w2)
        #pragma unroll
        for (int qd = 0; qd < 4; ++qd) {
          int idx = (((((hi*2 + w2)*4 + qd)*16 + ll)*4) + jj)*2;
          s += red[idx]; qq += red[idx+1];
        }
      int n = n0 + tid;                // == n0 + hi*64 + jj*16 + ll
      atomicAdd(&bns[n], s);
      atomicAdd(&bns[Co + n], qq);
    }
  }

  // ---- store ----
  #pragma unroll
  for (int i = 0; i < 4; ++i) {
    #pragma unroll
    for (int rr = 0; rr < 4; ++rr) {
      int m = m0 + wm + i*16 + quad*4 + rr;
      if (m >= M) continue;
      #pragma unroll
      for (int j2 = 0; j2 < 4; ++j2) {
        int n = n0 + wn + j2*16 + l15;
        if (n >= Co) continue;
        if (flags & FLAG_ATOMIC) {
          atomicAdd(&((float*)g.out)[(long)m*Co + n], acc[i][j2][rr]);
        } else {
          float v = acc[i][j2][rr] + g.bias[n];
          if (flags & FLAG_RELU) v = fmaxf(v, 0.f);
          if (flags & FLAG_OUTF32) ((float*)g.out)[(long)m*Co + n] = v;
          else ((half_t*)g.out)[(long)m*Co + n] = (half_t)v;
        }
      }
    }
  }
}

// ------------------------------------------------------------------
// Max pool fp16, NHWC, 8 channels per thread.
// ------------------------------------------------------------------
__global__ __launch_bounds__(256) void maxpool8_kernel(
    const half_t* __restrict__ x, half_t* __restrict__ out,
    int N,int H,int W,int C,int Ho,int Wo,int sH,int sW)
{
  int C8 = C >> 3;
  long idx = (long)blockIdx.x*256 + threadIdx.x;
  long total8 = (long)N*Ho*Wo*C8;
  if (idx >= total8) return;
  int cb = (int)(idx % C8);
  long pix = idx / C8;
  int wo = (int)(pix % Wo); long t2 = pix / Wo;
  int ho = (int)(t2 % Ho); int n = (int)(t2 / Ho);
  int c = cb * 8;
  float m[8];
  #pragma unroll
  for (int e = 0; e < 8; ++e) m[e] = -INFINITY;
  for (int i = 0; i < 2; ++i) {
    int ih = ho*sH + i;
    if (ih >= H) continue;
    for (int j = 0; j < 2; ++j) {
      int iw = wo*sW + j;
      if (iw >= W) continue;
      half8 v = *reinterpret_cast<const half8*>(x + (((long)n*H + ih)*W + iw)*C + c);
      #pragma unroll
      for (int e = 0; e < 8; ++e) m[e] = fmaxf(m[e], (float)v[e]);
    }
  }
  half8 o;
  #pragma unroll
  for (int e = 0; e < 8; ++e) o[e] = (half_t)m[e];
  *reinterpret_cast<half8*>(out + idx*8) = o;
}

// ------------------------------------------------------------------
// BN apply + ReLU (in place), 8 channels/thread.
// ------------------------------------------------------------------
__global__ __launch_bounds__(256) void bn_apply_relu8_kernel(
    half_t* __restrict__ x, const float* __restrict__ sums,
    const float* __restrict__ scale, const float* __restrict__ bias,
    long total8, int C, float invN)
{
  long idx = (long)blockIdx.x*256 + threadIdx.x;
  if (idx >= total8) return;
  int c = (int)((idx*8) % C);
  half8 v = *reinterpret_cast<half8*>(x + idx*8);
  half8 o;
  #pragma unroll
  for (int e = 0; e < 8; ++e) {
    float mean = sums[c+e] * invN;
    float var  = sums[C + c+e] * invN - mean*mean;
    float rstd = rsqrtf(var + 1e-5f);
    float y = ((float)v[e] - mean) * rstd * scale[c+e] + bias[c+e];
    o[e] = (half_t)fmaxf(y, 0.0f);
  }
  *reinterpret_cast<half8*>(x + idx*8) = o;
}

// ------------------------------------------------------------------
// Fused BN+ReLU+maxpool: out (N,Ho,Wo,C) from in (N,H,W,C).
// ------------------------------------------------------------------
__global__ __launch_bounds__(256) void bn_pool8_kernel(
    const half_t* __restrict__ x, half_t* __restrict__ out,
    const float* __restrict__ sums, const float* __restrict__ scale,
    const float* __restrict__ bias,
    int N,int H,int W,int C,int Ho,int Wo,int sH,int sW, float invN)
{
  int C8 = C >> 3;
  long idx = (long)blockIdx.x*256 + threadIdx.x;
  long total8 = (long)N*Ho*Wo*C8;
  if (idx >= total8) return;
  int cb = (int)(idx % C8);
  long pix = idx / C8;
  int wo = (int)(pix % Wo); long t2 = pix / Wo;
  int ho = (int)(t2 % Ho); int n = (int)(t2 / Ho);
  int c = cb * 8;
  float mean[8], rs[8], bb[8];
  #pragma unroll
  for (int e = 0; e < 8; ++e) {
    mean[e] = sums[c+e] * invN;
    float var = sums[C + c+e] * invN - mean[e]*mean[e];
    rs[e] = rsqrtf(var + 1e-5f) * scale[c+e];
    bb[e] = bias[c+e];
  }
  float m[8];
  #pragma unroll
  for (int e = 0; e < 8; ++e) m[e] = -INFINITY;
  for (int i = 0; i < 2; ++i) {
    int ih = ho*sH + i;
    if (ih >= H) continue;
    for (int j = 0; j < 2; ++j) {
      int iw = wo*sW + j;
      if (iw >= W) continue;
      half8 v = *reinterpret_cast<const half8*>(x + (((long)n*H + ih)*W + iw)*C + c);
      #pragma unroll
      for (int e = 0; e < 8; ++e) {
        float y = fmaxf(((float)v[e] - mean[e]) * rs[e] + bb[e], 0.f);
        m[e] = fmaxf(m[e], y);
      }
    }
  }
  half8 o;
  #pragma unroll
  for (int e = 0; e < 8; ++e) o[e] = (half_t)m[e];
  *reinterpret_cast<half8*>(out + idx*8) = o;
}

// ------------------------------------------------------------------
// Bias prefill for the split-K qkv GEMM output (480 x 1536 f32).
// ------------------------------------------------------------------
__global__ __launch_bounds__(256) void bias_fill_kernel(
    float* __restrict__ out, const float* __restrict__ b0,
    const float* __restrict__ b1, const float* __restrict__ b2, int total)
{
  int idx = blockIdx.x*256 + threadIdx.x;
  if (idx >= total) return;
  int n = idx % 1536;
  float v = (n < 512) ? b0[n] : (n < 1024 ? b1[n-512] : b2[n-1024]);
  out[idx] = v;
}

// ------------------------------------------------------------------
// Attention (T=15, D=512), qkv interleaved f32 rows of ld=1536, out fp16.
// ------------------------------------------------------------------
__global__ __launch_bounds__(256) void attention_kernel(
    const float* __restrict__ qkv, half_t* __restrict__ out,
    int T, int D, int ld)
{
  int b = blockIdx.x;
  int tid = threadIdx.x;
  __shared__ float P[15][16];
  if (tid < T*T) {
    int t = tid / T, s = tid % T;
    const float* qp = qkv + ((long)b*T + t)*ld;
    const float* kp = qkv + ((long)b*T + s)*ld + 512;
    float acc = 0.f;
    for (int d = 0; d < D; d += 4) {
      float4 qv = *reinterpret_cast<const float4*>(qp + d);
      float4 kv = *reinterpret_cast<const float4*>(kp + d);
      acc += qv.x*kv.x + qv.y*kv.y + qv.z*kv.z + qv.w*kv.w;
    }
    P[t][s] = acc * (1.0f/32.0f);
  }
  __syncthreads();
  if (tid < T) {
    float mx = -INFINITY;
    for (int s = 0; s < T; ++s) mx = fmaxf(mx, P[tid][s]);
    float sum = 0.f;
    for (int s = 0; s < T; ++s) { float e = expf(P[tid][s] - mx); P[tid][s] = e; sum += e; }
    float inv = 1.0f / sum;
    for (int s = 0; s < T; ++s) P[tid][s] *= inv;
  }
  __syncthreads();
  for (int idx = tid; idx < T*D; idx += 256) {
    int s = idx / D, kk2 = idx % D;
    float acc = 0.f;
    #pragma unroll
    for (int t = 0; t < 15; ++t)
      acc += qkv[((long)b*T + t)*ld + 1024 + kk2] * P[t][s];
    out[((long)b*T + s)*D + kk2] = (half_t)acc;
  }
}

// ------------------------------------------------------------------
// Persistent bidirectional LSTM — R7 version (R4 structure + XCD pin).
// Closed: ~3.5us/step is the agent-scope sync floor (R7 null).
// ------------------------------------------------------------------
#define MAXK 512
#define HSROW (MAXK + 8)

template<int N64, int HLOG>
__device__ __forceinline__ void stage_h(
    const unsigned long long* __restrict__ src, half_t (*hs)[HSROW], int tid)
{
  unsigned long long tmp[N64];
  #pragma unroll
  for (int u = 0; u < N64; ++u)
    tmp[u] = __hip_atomic_load(src + tid + u*256, __ATOMIC_RELAXED, __HIP_MEMORY_SCOPE_AGENT);
  #pragma unroll
  for (int u = 0; u < N64; ++u) {
    int idx = tid + u*256;
    int row = idx >> (HLOG - 2);
    int col = (idx & ((1 << (HLOG - 2)) - 1)) * 4;
    *reinterpret_cast<unsigned long long*>(&hs[row][col]) = tmp[u];
  }
}

template<int H>
__global__ __launch_bounds__(256, 1) void lstm_persistent_kernel(
    const float* __restrict__ preF, const float* __restrict__ preR,
    const half_t* __restrict__ whTF, const half_t* __restrict__ whTR,
    half_t* __restrict__ hbuf, half_t* __restrict__ y,
    int* __restrict__ flags, int nblk,
    int ystride, int yoffF, int yoffR)
{
  if (blockIdx.x & 7) return;      // XCD-pin: keep slot%8==0 -> one XCD
  int wid = blockIdx.x >> 3;       // worker id 0..nblk-1

  constexpr int KI = H / 32;      // k-chunks of 32
  __shared__ half_t hs[32][HSROW];
  __shared__ float gates[32][133]; // [batch][gate*32 + hcol]
  int tid = threadIdx.x;
  int jb0 = wid * 32;              // 32 H-columns per worker
  int lane = tid & 63, wave = tid >> 6;   // wave == gate index
  int l15 = lane & 15, quad = lane >> 4;
  int bb = tid >> 3;               // batch row for elementwise
  int jj0 = (tid & 7) * 4;         // 4 H-cols per thread
  constexpr int H4 = 4 * H;

  float cst[4] = {0.f, 0.f, 0.f, 0.f};
  half8 wreg[2][KI];               // B fragments: [col frag][k chunk]

  auto loadw = [&](const half_t* __restrict__ whT) {
    #pragma unroll
    for (int f = 0; f < 2; ++f) {
      const half_t* wp = whT + (long)(wave*H + jb0 + f*16 + l15)*H + quad*8;
      #pragma unroll
      for (int i = 0; i < KI; ++i)
        wreg[f][i] = *reinterpret_cast<const half8*>(wp + i*32);
    }
  };

  auto loadpv = [&](int s, float (&pv)[16]) {
    const float* pr = (s < 15) ? preF : preR;
    int t = (s < 15) ? s : 29 - s;
    const float* pp = pr + (long)(bb*15 + t)*H4 + jb0 + jj0;
    #pragma unroll
    for (int g = 0; g < 4; ++g) {
      f32x4 v = *reinterpret_cast<const f32x4*>(pp + g*H);
      pv[g*4+0] = v[0]; pv[g*4+1] = v[1]; pv[g*4+2] = v[2]; pv[g*4+3] = v[3];
    }
  };

  loadw(whTF);
  float pv[16];
  loadpv(0, pv);

  for (int s = 0; s < 30; ++s) {
    if (s == 15) loadw(whTR);      // reverse direction: carry (cst) continues
    int t = (s < 15) ? s : 29 - s;
    int yoff = (s < 15) ? yoffF : yoffR;

    const unsigned long long* hsrc =
        (const unsigned long long*)(hbuf + (long)(s & 1) * 32 * H);
    if constexpr (H == 512) stage_h<16, 9>(hsrc, hs, tid);
    else                    stage_h<8, 8>(hsrc, hs, tid);
    __syncthreads();

    f32x4 acc00 = {0.f,0.f,0.f,0.f}, acc10 = {0.f,0.f,0.f,0.f};
    f32x4 acc01 = {0.f,0.f,0.f,0.f}, acc11 = {0.f,0.f,0.f,0.f};
    #pragma unroll
    for (int i = 0; i < KI; ++i) {
      half8 a0 = *reinterpret_cast<half8*>(&hs[l15][i*32 + quad*8]);
      half8 a1 = *reinterpret_cast<half8*>(&hs[16 + l15][i*32 + quad*8]);
      acc00 = __builtin_amdgcn_mfma_f32_16x16x32_f16(a0, wreg[0][i], acc00, 0, 0, 0);
      acc10 = __builtin_amdgcn_mfma_f32_16x16x32_f16(a1, wreg[0][i], acc10, 0, 0, 0);
      acc01 = __builtin_amdgcn_mfma_f32_16x16x32_f16(a0, wreg[1][i], acc01, 0, 0, 0);
      acc11 = __builtin_amdgcn_mfma_f32_16x16x32_f16(a1, wreg[1][i], acc11, 0, 0, 0);
    }
    #pragma unroll
    for (int r = 0; r < 4; ++r) {
      gates[quad*4 + r][wave*32 + l15]           = acc00[r];
      gates[16 + quad*4 + r][wave*32 + l15]      = acc10[r];
      gates[quad*4 + r][wave*32 + 16 + l15]      = acc01[r];
      gates[16 + quad*4 + r][wave*32 + 16 + l15] = acc11[r];
    }
    __syncthreads();

    unsigned long long hpack;
    {
      half_t hn[4];
      #pragma unroll
      for (int p = 0; p < 4; ++p) {
        int j = jj0 + p;
        float gi = pv[p]      + gates[bb][j];
        float gf = pv[4 + p]  + gates[bb][32 + j];
        float gg = pv[8 + p]  + gates[bb][64 + j];
        float go = pv[12 + p] + gates[bb][96 + j];
        gi = fsig_(gi); gf = fsig_(gf); gg = ftanh_(gg); go = fsig_(go);
        float cn = gf * cst[p] + gi * gg;
        cst[p] = cn;
        hn[p] = (half_t)(go * ftanh_(cn));
      }
      hpack = *reinterpret_cast<unsigned long long*>(hn);
      half_t* hdst = hbuf + (long)((s + 1) & 1) * 32 * H;
      __hip_atomic_store((unsigned long long*)(hdst + (long)bb*H + jb0 + jj0), hpack,
                         __ATOMIC_RELAXED, __HIP_MEMORY_SCOPE_AGENT);
    }

    if (s < 29) {
      __syncthreads();             // drains vmcnt -> h stores visible
      if (tid == 0)
        __hip_atomic_store(&flags[wid], s + 1,
                           __ATOMIC_RELAXED, __HIP_MEMORY_SCOPE_AGENT);
      *reinterpret_cast<unsigned long long*>(
          &y[(long)(bb*15 + t)*ystride + yoff + jb0 + jj0]) = hpack;
      loadpv(s + 1, pv);           // prefetch next pv under the spin-wait
      if (tid < 64) {
        int target = s + 1;
        for (;;) {
          int vv = (tid < nblk)
            ? __hip_atomic_load(&flags[tid], __ATOMIC_RELAXED, __HIP_MEMORY_SCOPE_AGENT)
            : target;
          if (__all(vv >= target)) break;
        }
      }
      __syncthreads();
    } else {
      *reinterpret_cast<unsigned long long*>(
          &y[(long)(bb*15 + t)*ystride + yoff + jb0 + jj0]) = hpack;
    }
  }
}

// ------------------------------------------------------------------
// Host orchestration
// ------------------------------------------------------------------
extern "C" void kernel_launch(void* const* d_in, const int* in_sizes, int n_in,
                              void* d_out, int out_size, void* d_ws, size_t ws_size,
                              hipStream_t stream)
{
  const float* x       = (const float*)d_in[0];
  const float* c1w     = (const float*)d_in[1];  const float* c1b = (const float*)d_in[2];
  const float* c2w     = (const float*)d_in[3];  const float* c2b = (const float*)d_in[4];
  const float* c3w     = (const float*)d_in[5];  const float* c3b = (const float*)d_in[6];
  const float* bn1s    = (const float*)d_in[7];  const float* bn1b = (const float*)d_in[8];
  const float* c4w     = (const float*)d_in[9];  const float* c4b = (const float*)d_in[10];
  const float* bn2s    = (const float*)d_in[11]; const float* bn2b = (const float*)d_in[12];
  const float* c5w     = (const float*)d_in[13]; const float* c5b = (const float*)d_in[14];
  const float* bn3s    = (const float*)d_in[15]; const float* bn3b = (const float*)d_in[16];
  const float* c6w     = (const float*)d_in[17]; const float* c6b = (const float*)d_in[18];
  const float* bn4s    = (const float*)d_in[19]; const float* bn4b = (const float*)d_in[20];
  const float* c7w     = (const float*)d_in[21]; const float* c7b = (const float*)d_in[22];
  const float* bn5s    = (const float*)d_in[23]; const float* bn5b = (const float*)d_in[24];
  const float* wq      = (const float*)d_in[25]; const float* bq = (const float*)d_in[26];
  const float* wk      = (const float*)d_in[27]; const float* bk = (const float*)d_in[28];
  const float* wv      = (const float*)d_in[29]; const float* bv = (const float*)d_in[30];
  const float* l1f_wx  = (const float*)d_in[31]; const float* l1f_wh = (const float*)d_in[32]; const float* l1f_b = (const float*)d_in[33];
  const float* l1r_wx  = (const float*)d_in[34]; const float* l1r_wh = (const float*)d_in[35]; const float* l1r_b = (const float*)d_in[36];
  const float* l2f_wx  = (const float*)d_in[37]; const float* l2f_wh = (const float*)d_in[38]; const float* l2f_b = (const float*)d_in[39];
  const float* l2r_wx  = (const float*)d_in[40]; const float* l2r_wh = (const float*)d_in[41]; const float* l2r_b = (const float*)d_in[42];
  const float* wo      = (const float*)d_in[43]; const float* bo = (const float*)d_in[44];
  float* outp = (float*)d_out;

  char* base = (char*)d_ws;
  half_t* actA = (half_t*)base;
  half_t* actB = (half_t*)(base + 67108864);
  half_t* wtA  = (half_t*)(base + 100663296);
  float*  f32a = (float*)(base + 143687680);
  half_t* h16a = (half_t*)(base + 158736384);

  half_t* wt2  = wtA;
  half_t* wt3  = wtA + 73728;
  half_t* wt4  = wtA + 368640;
  half_t* wt5  = wtA + 958464;
  half_t* wt6  = wtA + 2138112;
  half_t* wt7  = wtA + 4497408;
  half_t* wtq  = wtA + 5545984;        // wtq|wtk|wtv contiguous -> [1536][7680]
  half_t* wtk  = wtA + 9478144;
  half_t* wtv  = wtA + 13410304;
  half_t* wt1f = wtA + 17342464;
  half_t* wt1r = wtA + 17866752;
  half_t* wt2f = wtA + 18391040;
  half_t* wt2r = wtA + 19439616;
  half_t* wto  = wtA + 20488192;

  float* qkvbuf = f32a;                // 480 x 1536 f32
  float* pre1f = f32a + 737280;
  float* pre1r = f32a + 1228800;
  float* pre2f = f32a + 1720320;
  float* pre2r = f32a + 2703360;

  half_t* ao  = h16a;
  half_t* x1  = h16a + 245760;
  half_t* x2  = h16a + 491520;
  half_t* hb1 = h16a + 983040;              // 2 x 32 x 256 fp16
  half_t* hb2 = hb1 + 16384;                // 2 x 32 x 512 fp16
  int*    flags1 = (int*)(hb2 + 32768);     // 512 ints
  int*    flags2 = flags1 + 512;
  half_t* zbuf   = (half_t*)(flags2 + 512); // 32 halves
  float*  bnz    = (float*)(zbuf + 32);     // 5 x 2048 floats

  // transposed fp16 LSTM recurrent weights [4H][H] (appended past bnz)
  half_t* whT1f = (half_t*)(base + 160849920);   // 1024x256 = 512KB
  half_t* whT1r = (half_t*)(base + 161374208);
  half_t* whT2f = (half_t*)(base + 161898496);   // 2048x512 = 2MB
  half_t* whT2r = (half_t*)(base + 163995648);   // end 166,092,800

  auto convm = [&](const half_t* in, const half_t* wt, const float* b, void* out,
                   int N,int H,int W,int Ci,int Ho,int Wo,int Co,
                   int KH,int KW,int pH,int pW,int flags, float* bns){
    int M = N*Ho*Wo, K = KH*KW*Ci;
    dim3 grid(DIV_UP(Co,128), DIV_UP(M,128), 1);
    GOut g{wt, b, out};
    mfma_conv_kernel<<<grid,256,0,stream>>>(in,g,g,g,zbuf,bns,N,H,W,Ci,Ho,Wo,Co,
                                            KH,KW,pH,pW,M,K,flags,1);
  };
  auto gemm3 = [&](const half_t* A, GOut g0, GOut g1, GOut g2, int nz,
                   int M, int Nn, int K, int flags, int splitS){
    dim3 grid(DIV_UP(Nn,128), DIV_UP(M,128), nz);
    mfma_conv_kernel<<<grid,256,0,stream>>>(A,g0,g1,g2,zbuf,bnz,M,1,1,K,1,1,Nn,
                                            1,1,0,0,M,K,flags,splitS);
  };
  auto pool = [&](const half_t* in, half_t* out, int N,int H,int W,int C,
                  int Ho,int Wo,int sH,int sW){
    long total8 = (long)N*Ho*Wo*(C/8);
    maxpool8_kernel<<<(int)DIV_UP(total8,256),256,0,stream>>>(in,out,N,H,W,C,Ho,Wo,sH,sW);
  };
  auto bnApply = [&](half_t* buf, long nPix, int C, const float* s, const float* b,
                     float* sums){
    long total8 = nPix * C / 8;
    bn_apply_relu8_kernel<<<(int)DIV_UP(total8,256),256,0,stream>>>(buf, sums, s, b, total8, C, 1.0f/(float)nPix);
  };
  auto bnPool = [&](const half_t* in, half_t* out, int N,int H,int W,int C,
                    int Ho,int Wo,int sH,int sW, long nPix,
                    const float* s, const float* b, float* sums){
    long total8 = (long)N*Ho*Wo*(C/8);
    bn_pool8_kernel<<<(int)DIV_UP(total8,256),256,0,stream>>>(
        in,out,sums,s,b,N,H,W,C,Ho,Wo,sH,sW,1.0f/(float)nPix);
  };

  // one zero-fill: hb1/hb2, flags, zbuf, 5 bn-sum buffers
  hipMemsetAsync(hb1, 0, 143424, stream);

  // ---- ALL weight transposes in one launch (incl. LSTM Wh -> fp16 [4H][H]) ----
  {
    TpAll tp;
    const float* srcs[NTP] = {c2w,c3w,c4w,c5w,c6w,c7w,wq,wk,wv,l1f_wx,l1r_wx,l2f_wx,l2r_wx,wo,
                              l1f_wh,l1r_wh,l2f_wh,l2r_wh};
    half_t* dsts[NTP] = {wt2,wt3,wt4,wt5,wt6,wt7,wtq,wtk,wtv,wt1f,wt1r,wt2f,wt2r,wto,
                         whT1f,whT1r,whT2f,whT2r};
    int Ks[NTP] = {576,1152,2304,2304,4608,2048,7680,7680,7680,512,512,512,512,1024,
                   256,256,512,512};
    int Ns[NTP] = {128,256,256,512,512,512,512,512,512,1024,1024,2048,2048,1000,
                   1024,1024,2048,2048};
    int acc = 0;
    for (int i = 0; i < NTP; ++i) {
      tp.src[i] = srcs[i]; tp.dst[i] = dsts[i]; tp.K[i] = Ks[i]; tp.N[i] = Ns[i];
      tp.prefix[i] = acc;
      acc += DIV_UP(Ks[i],32) * DIV_UP(Ns[i],32);
    }
    tp.prefix[NTP] = acc;
    transpose_cvt_all_kernel<<<acc,256,0,stream>>>(tp);
  }

  // ---- conv stack (activations fp16) ----
  conv1_kernel<<<2048,256,0,stream>>>(x, c1w, c1b, actA);
  pool(actA, actB, 32,64,256,64,  32,128, 2,2);
  convm(actB, wt2, c2b, actA, 32,32,128,64,  32,128,128, 3,3,1,1, FLAG_RELU, bnz);
  pool(actA, actB, 32,32,128,128, 16,64, 2,2);
  convm(actB, wt3, c3b, actA, 32,16,64,128,  16,64,256,  3,3,1,1, FLAG_BNSUMS, bnz);
  bnApply(actA, 32768, 256, bn1s, bn1b, bnz);
  convm(actA, wt4, c4b, actB, 32,16,64,256,  16,64,256,  3,3,1,1, FLAG_BNSUMS, bnz + 2048);
  bnPool(actB, actA, 32,16,64,256, 16,32, 1,2, 32768, bn2s, bn2b, bnz + 2048);
  convm(actA, wt5, c5b, actB, 32,16,32,256,  16,32,512,  3,3,1,1, FLAG_BNSUMS, bnz + 4096);
  bnApply(actB, 16384, 512, bn3s, bn3b, bnz + 4096);
  convm(actB, wt6, c6b, actA, 32,16,32,512,  16,32,512,  3,3,1,1, FLAG_BNSUMS, bnz + 6144);
  bnPool(actA, actB, 32,16,32,512, 16,16, 1,2, 16384, bn4s, bn4b, bnz + 6144);
  convm(actB, wt7, c7b, actA, 32,16,16,512,  15,15,512,  2,2,0,0, FLAG_BNSUMS, bnz + 8192);
  bnApply(actA, 7200, 512, bn5s, bn5b, bnz + 8192);

  // ---- attention: single qkv GEMM (N=1536), split-K x4, atomic epilogue ----
  bias_fill_kernel<<<DIV_UP(480*1536,256),256,0,stream>>>(qkvbuf, bq, bk, bv, 480*1536);
  gemm3(actA, GOut{wtq, nullptr, qkvbuf}, GOut{wtq, nullptr, qkvbuf},
        GOut{wtq, nullptr, qkvbuf}, 4, 480, 1536, 7680, FLAG_SPLITK|FLAG_ATOMIC, 4);
  attention_kernel<<<32,256,0,stream>>>(qkvbuf, ao, 15, 512, 1536);

  // ---- LSTM stack 1 (H=256): 8 workers (XCD-pinned, grid 64) ----
  gemm3(ao, GOut{wt1f, l1f_b, pre1f}, GOut{wt1r, l1r_b, pre1r},
        GOut{wt1r, l1r_b, pre1r}, 2, 480, 1024, 512, FLAG_OUTF32, 1);
  lstm_persistent_kernel<256><<<64,256,0,stream>>>(
      pre1f, pre1r, whT1f, whT1r, hb1, x1, flags1, 8, 512, 0, 256);

  // ---- LSTM stack 2 (H=512): 16 workers (XCD-pinned, grid 128) ----
  gemm3(x1, GOut{wt2f, l2f_b, pre2f}, GOut{wt2r, l2r_b, pre2r},
        GOut{wt2r, l2r_b, pre2r}, 2, 480, 2048, 512, FLAG_OUTF32, 1);
  lstm_persistent_kernel<512><<<128,256,0,stream>>>(
      pre2f, pre2r, whT2f, whT2r, hb2, x2, flags2, 16, 1024, 512, 0);

  // ---- classifier ----
  gemm3(x2, GOut{wto, bo, outp}, GOut{wto, bo, outp}, GOut{wto, bo, outp}, 1,
        480, 1000, 1024, FLAG_OUTF32, 1);
}

// Round 9
// 999.598 us; speedup vs baseline: 1.4594x; 1.0274x over previous
//
#include <hip/hip_runtime.h>
#include <math.h>

#define DIV_UP(a,b) (((a)+(b)-1)/(b))

typedef _Float16 half_t;
typedef _Float16 half8 __attribute__((ext_vector_type(8)));
typedef float f32x4 __attribute__((ext_vector_type(4)));

#define FLAG_RELU   1
#define FLAG_OUTF32 2
#define FLAG_SPLITK 4
#define FLAG_ATOMIC 8
#define FLAG_BNSUMS 16

#define GLDS16(src, dst) \
  __builtin_amdgcn_global_load_lds((const __attribute__((address_space(1))) void*)(src), \
                                   (__attribute__((address_space(3))) void*)(dst), 16, 0, 0)

__device__ __forceinline__ float fsig_(float x){ return 1.0f/(1.0f+__expf(-x)); }
__device__ __forceinline__ float ftanh_(float x){
  float ax = fabsf(x);
  float e = __expf(-2.0f*ax);
  float t = (1.0f - e)/(1.0f + e);
  return copysignf(t, x);
}

// ------------------------------------------------------------------
// ALL weight transposes (fp32 [K][N] -> fp16 [N][K]) in ONE launch.
// ------------------------------------------------------------------
#define NTP 18
struct TpAll {
  const float* src[NTP];
  half_t* dst[NTP];
  int K[NTP];
  int N[NTP];
  int prefix[NTP+1];
};

__global__ __launch_bounds__(256) void transpose_cvt_all_kernel(TpAll a)
{
  __shared__ float tile[32][33];
  int bid = blockIdx.x;
  int z = 0;
  while (bid >= a.prefix[z+1]) ++z;
  int local = bid - a.prefix[z];
  const float* w = a.src[z];
  half_t* wT = a.dst[z];
  int K = a.K[z], N = a.N[z];
  int tilesX = (N + 31) >> 5;
  int nt = (local % tilesX) * 32;
  int kt = (local / tilesX) * 32;
  int tx = threadIdx.x & 31, ty = threadIdx.x >> 5;
  #pragma unroll
  for (int r = 0; r < 4; ++r) {
    int k = kt + ty + r*8, n = nt + tx;
    tile[ty + r*8][tx] = (k < K && n < N) ? w[(long)k*N + n] : 0.f;
  }
  __syncthreads();
  #pragma unroll
  for (int r = 0; r < 4; ++r) {
    int n = nt + ty + r*8, k = kt + tx;
    if (n < N && k < K) wT[(long)n*K + k] = (half_t)tile[tx][ty + r*8];
  }
}

// ------------------------------------------------------------------
// R9: conv1 FUSED with maxpool1. Block = (n, ho2) pooled output row.
// Stages 4 input rows (2*ho2-1 .. 2*ho2+2, zero-padded) in LDS,
// computes both conv rows + ReLU, pools 2x2 in-register, stores
// (32,32,128,64) fp16 directly. Deletes the 33.5MB conv1 write +
// 83MB pool round trip (ReLU-then-pool order preserved; SAME 2x2/2
// on 64x256 has no boundary windows).
// ------------------------------------------------------------------
__global__ __launch_bounds__(256) void conv1_pool_kernel(
    const float* __restrict__ x, const float* __restrict__ w,
    const float* __restrict__ bias, half_t* __restrict__ out)
{
  __shared__ float xs[4][258*3];
  int nb = blockIdx.x;            // n*32 + ho2
  int n = nb >> 5, ho2 = nb & 31;
  int tid = threadIdx.x;
  int co = tid & 63;
  float wreg[27];
  #pragma unroll
  for (int k = 0; k < 27; ++k) wreg[k] = w[k*64 + co];
  float bco = bias[co];
  for (int i = tid; i < 4*258*3; i += 256) {
    int row = i / (258*3); int rem = i % (258*3);
    int col = rem / 3;     int ci  = rem % 3;
    int ih = ho2*2 - 1 + row; int iw = col - 1;
    float v = 0.f;
    if (ih >= 0 && ih < 64 && iw >= 0 && iw < 256)
      v = x[(((long)n*64 + ih)*256 + iw)*3 + ci];
    xs[row][col*3 + ci] = v;
  }
  __syncthreads();
  int wave = tid >> 6;
  float mprev = 0.f;
  for (int p = 0; p < 64; ++p) {
    int wo = wave*64 + p;
    float acc0 = bco, acc1 = bco;
    #pragma unroll
    for (int kh = 0; kh < 3; ++kh)
      #pragma unroll
      for (int kw = 0; kw < 3; ++kw)
        #pragma unroll
        for (int ci = 0; ci < 3; ++ci) {
          float wv = wreg[(kh*3+kw)*3 + ci];
          acc0 = fmaf(xs[kh]  [(wo+kw)*3 + ci], wv, acc0);
          acc1 = fmaf(xs[kh+1][(wo+kw)*3 + ci], wv, acc1);
        }
    float m = fmaxf(fmaxf(acc0, 0.f), fmaxf(acc1, 0.f));
    if (p & 1) {
      int wo2 = (wave*64 + p) >> 1;
      out[(((long)n*32 + ho2)*128 + wo2)*64 + co] = (half_t)fmaxf(m, mprev);
    } else {
      mprev = m;
    }
  }
}

// ------------------------------------------------------------------
// MFMA implicit-GEMM conv/GEMM. 128x128 tile, BK=64, 4 waves.
// R3: XCD-aware bijective remap. R4: double-buffered K-loop.
// R8: counted vmcnt (kept; >= neutral).
// ------------------------------------------------------------------
struct GOut { const half_t* wT; const float* bias; void* out; };

__global__ __launch_bounds__(256) void mfma_conv_kernel(
    const half_t* __restrict__ x, GOut g0, GOut g1, GOut g2,
    const half_t* __restrict__ zbuf, float* __restrict__ bns,
    int N,int H,int W,int Ci,int Ho,int Wo,int Co,
    int KH,int KW,int padH,int padW,
    int M,int K,int flags,int splitS)
{
  GOut g;
  int ciBeg = 0, ciEnd = Ci;
  if (flags & FLAG_SPLITK) {
    g = g0;
    int span = Ci / splitS;
    ciBeg = blockIdx.z * span;
    ciEnd = ciBeg + span;
  } else {
    g = (blockIdx.z == 0) ? g0 : (blockIdx.z == 1 ? g1 : g2);
  }
  const half_t* __restrict__ wT = g.wT;
  __shared__ half_t As[2][128*64];
  __shared__ half_t Bs[2][128*64];
  int tid = threadIdx.x;

  // ---- XCD-aware bijective remap: slot -> work (m-major, n fastest) ----
  int nbx = gridDim.x, nby = gridDim.y;
  int total = nbx * nby;
  int flat = blockIdx.y * nbx + blockIdx.x;   // dispatch slot within z-slice
  int q = total >> 3, r = total & 7;
  int xcd = flat & 7;                          // hw XCD (round-robin heuristic)
  int j = flat >> 3;                           // j-th slot on that XCD
  int w = xcd * q + (xcd < r ? xcd : r) + j;   // contiguous work band per XCD
  int m0 = (w / nbx) * 128, n0 = (w % nbx) * 128;

  int wave = tid >> 6, lane = tid & 63;
  int l15 = lane & 15, quad = lane >> 4;
  int x7 = lane & 7;
  int wm = (wave & 1) * 64, wn = (wave >> 1) * 64;

  // staging decode: 4 issues, row_i = i*32 + (tid>>3), source chunk swizzled
  int rSub = tid >> 3;
  int colHalf = (((tid & 7) ^ (rSub & 7))) * 8;

  int ho_[4], wo_[4], ni_[4]; bool av_[4];
  #pragma unroll
  for (int i = 0; i < 4; ++i) {
    int m = m0 + i*32 + rSub;
    av_[i] = m < M;
    int mm = av_[i] ? m : 0;
    wo_[i] = mm % Wo; int t2 = mm / Wo;
    ho_[i] = t2 % Ho; ni_[i] = t2 / Ho;
  }
  const half_t* bBase[4];
  #pragma unroll
  for (int i = 0; i < 4; ++i) {
    int n = n0 + i*32 + rSub;
    bBase[i] = (n < Co) ? (wT + (long)n*K + colHalf) : nullptr;
  }

  // fragment LDS chunk offsets per k-sub (conflict-free via XOR swizzle)
  int pch0 = ((quad)     ^ x7) * 8;
  int pch1 = ((4 + quad) ^ x7) * 8;

  f32x4 acc[4][4];
  #pragma unroll
  for (int i = 0; i < 4; ++i)
    #pragma unroll
    for (int j2 = 0; j2 < 4; ++j2)
      acc[i][j2] = (f32x4){0.f, 0.f, 0.f, 0.f};

  // ---- staging state: running (skh, skw, sci) k-tile coordinates ----
  int NT = ((ciEnd - ciBeg) >> 6) * KH * KW;
  int skh = 0, skw = 0, sci = ciBeg;
  long sAOff[4]; bool sAval[4];
  auto recompA = [&]() {
    #pragma unroll
    for (int i = 0; i < 4; ++i) {
      int ih = ho_[i] - padH + skh, iw = wo_[i] - padW + skw;
      bool ok = av_[i] && ih >= 0 && ih < H && iw >= 0 && iw < W;
      sAval[i] = ok;
      sAOff[i] = ok ? ((((long)ni_[i]*H + ih)*W + iw)*(long)Ci + colHalf) : 0;
    }
  };
  recompA();
  auto stage = [&](int b) {
    int kgS = (skh*KW + skw)*Ci + sci;           // global B k-index
    #pragma unroll
    for (int i = 0; i < 4; ++i) {
      const half_t* sa = sAval[i] ? (x + sAOff[i] + sci) : zbuf;
      GLDS16(sa, &As[b][i*2048 + wave*512]);
      const half_t* sb = bBase[i] ? (bBase[i] + kgS) : zbuf;
      GLDS16(sb, &Bs[b][i*2048 + wave*512]);
    }
  };
  auto advance = [&]() {
    sci += 64;
    if (sci == ciEnd) {
      sci = ciBeg; ++skw;
      if (skw == KW) { skw = 0; ++skh; }
      recompA();
    }
  };

  stage(0); advance();             // prologue: buf0 in flight

  for (int kt = 0; kt < NT; ++kt) {
    int p = kt & 1;
    if (kt + 1 < NT) {
      stage(p ^ 1); advance();     // 8 new loads in flight (buf p^1)
      asm volatile("s_waitcnt vmcnt(8)" ::: "memory");  // wait buf p's 8 (oldest)
    } else {
      asm volatile("s_waitcnt vmcnt(0)" ::: "memory");  // last: drain
    }
    __builtin_amdgcn_s_barrier();  // all waves: buf p fully written
    asm volatile("" ::: "memory");
    {
      half8 af[4], bf[4];
      #pragma unroll
      for (int i = 0; i < 4; ++i)
        af[i] = *reinterpret_cast<half8*>(&As[p][(wm + i*16 + l15)*64 + pch0]);
      #pragma unroll
      for (int j2 = 0; j2 < 4; ++j2)
        bf[j2] = *reinterpret_cast<half8*>(&Bs[p][(wn + j2*16 + l15)*64 + pch0]);
      #pragma unroll
      for (int i = 0; i < 4; ++i)
        #pragma unroll
        for (int j2 = 0; j2 < 4; ++j2)
          acc[i][j2] = __builtin_amdgcn_mfma_f32_16x16x32_f16(af[i], bf[j2], acc[i][j2], 0, 0, 0);
    }
    {
      half8 af[4], bf[4];
      #pragma unroll
      for (int i = 0; i < 4; ++i)
        af[i] = *reinterpret_cast<half8*>(&As[p][(wm + i*16 + l15)*64 + pch1]);
      #pragma unroll
      for (int j2 = 0; j2 < 4; ++j2)
        bf[j2] = *reinterpret_cast<half8*>(&Bs[p][(wn + j2*16 + l15)*64 + pch1]);
      #pragma unroll
      for (int i = 0; i < 4; ++i)
        #pragma unroll
        for (int j2 = 0; j2 < 4; ++j2)
          acc[i][j2] = __builtin_amdgcn_mfma_f32_16x16x32_f16(af[i], bf[j2], acc[i][j2], 0, 0, 0);
    }
    asm volatile("" ::: "memory");
    __builtin_amdgcn_s_barrier();  // all waves done reading buf p
  }

  // ---- BN sums from accumulators (f32, pre-relu value incl. bias) ----
  if (flags & FLAG_BNSUMS) {
    float* red = (float*)As;     // [wave][quad][l15][j][2] = 4*4*16*4*2 floats
    #pragma unroll
    for (int j2 = 0; j2 < 4; ++j2) {
      int n = n0 + wn + j2*16 + l15;
      float bv = g.bias[n];
      float s = 0.f, qq = 0.f;
      #pragma unroll
      for (int i = 0; i < 4; ++i)
        #pragma unroll
        for (int rr = 0; rr < 4; ++rr) {
          int m = m0 + wm + i*16 + quad*4 + rr;
          if (m < M) { float v = acc[i][j2][rr] + bv; s += v; qq += v*v; }
        }
      int idx = ((((wave*4 + quad)*16 + l15)*4) + j2)*2;
      red[idx] = s; red[idx+1] = qq;
    }
    __syncthreads();
    if (tid < 128) {
      int hi = tid >> 6;               // which 64-channel half (wn)
      int jj = (tid >> 4) & 3, ll = tid & 15;
      float s = 0.f, qq = 0.f;
      #pragma unroll
      for (int w2 = 0; w2 < 2; ++w2)
        #pragma unroll
        for (int qd = 0; qd < 4; ++qd) {
          int idx = (((((hi*2 + w2)*4 + qd)*16 + ll)*4) + jj)*2;
          s += red[idx]; qq += red[idx+1];
        }
      int n = n0 + tid;                // == n0 + hi*64 + jj*16 + ll
      atomicAdd(&bns[n], s);
      atomicAdd(&bns[Co + n], qq);
    }
  }

  // ---- store ----
  #pragma unroll
  for (int i = 0; i < 4; ++i) {
    #pragma unroll
    for (int rr = 0; rr < 4; ++rr) {
      int m = m0 + wm + i*16 + quad*4 + rr;
      if (m >= M) continue;
      #pragma unroll
      for (int j2 = 0; j2 < 4; ++j2) {
        int n = n0 + wn + j2*16 + l15;
        if (n >= Co) continue;
        if (flags & FLAG_ATOMIC) {
          atomicAdd(&((float*)g.out)[(long)m*Co + n], acc[i][j2][rr]);
        } else {
          float v = acc[i][j2][rr] + g.bias[n];
          if (flags & FLAG_RELU) v = fmaxf(v, 0.f);
          if (flags & FLAG_OUTF32) ((float*)g.out)[(long)m*Co + n] = v;
          else ((half_t*)g.out)[(long)m*Co + n] = (half_t)v;
        }
      }
    }
  }
}

// ------------------------------------------------------------------
// Max pool fp16, NHWC, 8 channels per thread.
// ------------------------------------------------------------------
__global__ __launch_bounds__(256) void maxpool8_kernel(
    const half_t* __restrict__ x, half_t* __restrict__ out,
    int N,int H,int W,int C,int Ho,int Wo,int sH,int sW)
{
  int C8 = C >> 3;
  long idx = (long)blockIdx.x*256 + threadIdx.x;
  long total8 = (long)N*Ho*Wo*C8;
  if (idx >= total8) return;
  int cb = (int)(idx % C8);
  long pix = idx / C8;
  int wo = (int)(pix % Wo); long t2 = pix / Wo;
  int ho = (int)(t2 % Ho); int n = (int)(t2 / Ho);
  int c = cb * 8;
  float m[8];
  #pragma unroll
  for (int e = 0; e < 8; ++e) m[e] = -INFINITY;
  for (int i = 0; i < 2; ++i) {
    int ih = ho*sH + i;
    if (ih >= H) continue;
    for (int j = 0; j < 2; ++j) {
      int iw = wo*sW + j;
      if (iw >= W) continue;
      half8 v = *reinterpret_cast<const half8*>(x + (((long)n*H + ih)*W + iw)*C + c);
      #pragma unroll
      for (int e = 0; e < 8; ++e) m[e] = fmaxf(m[e], (float)v[e]);
    }
  }
  half8 o;
  #pragma unroll
  for (int e = 0; e < 8; ++e) o[e] = (half_t)m[e];
  *reinterpret_cast<half8*>(out + idx*8) = o;
}

// ------------------------------------------------------------------
// BN apply + ReLU (in place), 8 channels/thread.
// ------------------------------------------------------------------
__global__ __launch_bounds__(256) void bn_apply_relu8_kernel(
    half_t* __restrict__ x, const float* __restrict__ sums,
    const float* __restrict__ scale, const float* __restrict__ bias,
    long total8, int C, float invN)
{
  long idx = (long)blockIdx.x*256 + threadIdx.x;
  if (idx >= total8) return;
  int c = (int)((idx*8) % C);
  half8 v = *reinterpret_cast<half8*>(x + idx*8);
  half8 o;
  #pragma unroll
  for (int e = 0; e < 8; ++e) {
    float mean = sums[c+e] * invN;
    float var  = sums[C + c+e] * invN - mean*mean;
    float rstd = rsqrtf(var + 1e-5f);
    float y = ((float)v[e] - mean) * rstd * scale[c+e] + bias[c+e];
    o[e] = (half_t)fmaxf(y, 0.0f);
  }
  *reinterpret_cast<half8*>(x + idx*8) = o;
}

// ------------------------------------------------------------------
// Fused BN+ReLU+maxpool: out (N,Ho,Wo,C) from in (N,H,W,C).
// ------------------------------------------------------------------
__global__ __launch_bounds__(256) void bn_pool8_kernel(
    const half_t* __restrict__ x, half_t* __restrict__ out,
    const float* __restrict__ sums, const float* __restrict__ scale,
    const float* __restrict__ bias,
    int N,int H,int W,int C,int Ho,int Wo,int sH,int sW, float invN)
{
  int C8 = C >> 3;
  long idx = (long)blockIdx.x*256 + threadIdx.x;
  long total8 = (long)N*Ho*Wo*C8;
  if (idx >= total8) return;
  int cb = (int)(idx % C8);
  long pix = idx / C8;
  int wo = (int)(pix % Wo); long t2 = pix / Wo;
  int ho = (int)(t2 % Ho); int n = (int)(t2 / Ho);
  int c = cb * 8;
  float mean[8], rs[8], bb[8];
  #pragma unroll
  for (int e = 0; e < 8; ++e) {
    mean[e] = sums[c+e] * invN;
    float var = sums[C + c+e] * invN - mean[e]*mean[e];
    rs[e] = rsqrtf(var + 1e-5f) * scale[c+e];
    bb[e] = bias[c+e];
  }
  float m[8];
  #pragma unroll
  for (int e = 0; e < 8; ++e) m[e] = -INFINITY;
  for (int i = 0; i < 2; ++i) {
    int ih = ho*sH + i;
    if (ih >= H) continue;
    for (int j = 0; j < 2; ++j) {
      int iw = wo*sW + j;
      if (iw >= W) continue;
      half8 v = *reinterpret_cast<const half8*>(x + (((long)n*H + ih)*W + iw)*C + c);
      #pragma unroll
      for (int e = 0; e < 8; ++e) {
        float y = fmaxf(((float)v[e] - mean[e]) * rs[e] + bb[e], 0.f);
        m[e] = fmaxf(m[e], y);
      }
    }
  }
  half8 o;
  #pragma unroll
  for (int e = 0; e < 8; ++e) o[e] = (half_t)m[e];
  *reinterpret_cast<half8*>(out + idx*8) = o;
}

// ------------------------------------------------------------------
// Bias prefill for the split-K qkv GEMM output (480 x 1536 f32).
// ------------------------------------------------------------------
__global__ __launch_bounds__(256) void bias_fill_kernel(
    float* __restrict__ out, const float* __restrict__ b0,
    const float* __restrict__ b1, const float* __restrict__ b2, int total)
{
  int idx = blockIdx.x*256 + threadIdx.x;
  if (idx >= total) return;
  int n = idx % 1536;
  float v = (n < 512) ? b0[n] : (n < 1024 ? b1[n-512] : b2[n-1024]);
  out[idx] = v;
}

// ------------------------------------------------------------------
// Attention (T=15, D=512), qkv interleaved f32 rows of ld=1536, out fp16.
// ------------------------------------------------------------------
__global__ __launch_bounds__(256) void attention_kernel(
    const float* __restrict__ qkv, half_t* __restrict__ out,
    int T, int D, int ld)
{
  int b = blockIdx.x;
  int tid = threadIdx.x;
  __shared__ float P[15][16];
  if (tid < T*T) {
    int t = tid / T, s = tid % T;
    const float* qp = qkv + ((long)b*T + t)*ld;
    const float* kp = qkv + ((long)b*T + s)*ld + 512;
    float acc = 0.f;
    for (int d = 0; d < D; d += 4) {
      float4 qv = *reinterpret_cast<const float4*>(qp + d);
      float4 kv = *reinterpret_cast<const float4*>(kp + d);
      acc += qv.x*kv.x + qv.y*kv.y + qv.z*kv.z + qv.w*kv.w;
    }
    P[t][s] = acc * (1.0f/32.0f);
  }
  __syncthreads();
  if (tid < T) {
    float mx = -INFINITY;
    for (int s = 0; s < T; ++s) mx = fmaxf(mx, P[tid][s]);
    float sum = 0.f;
    for (int s = 0; s < T; ++s) { float e = expf(P[tid][s] - mx); P[tid][s] = e; sum += e; }
    float inv = 1.0f / sum;
    for (int s = 0; s < T; ++s) P[tid][s] *= inv;
  }
  __syncthreads();
  for (int idx = tid; idx < T*D; idx += 256) {
    int s = idx / D, kk2 = idx % D;
    float acc = 0.f;
    #pragma unroll
    for (int t = 0; t < 15; ++t)
      acc += qkv[((long)b*T + t)*ld + 1024 + kk2] * P[t][s];
    out[((long)b*T + s)*D + kk2] = (half_t)acc;
  }
}

// ------------------------------------------------------------------
// Persistent bidirectional LSTM — R7 version (R4 structure + XCD pin).
// Closed: ~3.5us/step is the agent-scope sync floor (R7 null).
// ------------------------------------------------------------------
#define MAXK 512
#define HSROW (MAXK + 8)

template<int N64, int HLOG>
__device__ __forceinline__ void stage_h(
    const unsigned long long* __restrict__ src, half_t (*hs)[HSROW], int tid)
{
  unsigned long long tmp[N64];
  #pragma unroll
  for (int u = 0; u < N64; ++u)
    tmp[u] = __hip_atomic_load(src + tid + u*256, __ATOMIC_RELAXED, __HIP_MEMORY_SCOPE_AGENT);
  #pragma unroll
  for (int u = 0; u < N64; ++u) {
    int idx = tid + u*256;
    int row = idx >> (HLOG - 2);
    int col = (idx & ((1 << (HLOG - 2)) - 1)) * 4;
    *reinterpret_cast<unsigned long long*>(&hs[row][col]) = tmp[u];
  }
}

template<int H>
__global__ __launch_bounds__(256, 1) void lstm_persistent_kernel(
    const float* __restrict__ preF, const float* __restrict__ preR,
    const half_t* __restrict__ whTF, const half_t* __restrict__ whTR,
    half_t* __restrict__ hbuf, half_t* __restrict__ y,
    int* __restrict__ flags, int nblk,
    int ystride, int yoffF, int yoffR)
{
  if (blockIdx.x & 7) return;      // XCD-pin: keep slot%8==0 -> one XCD
  int wid = blockIdx.x >> 3;       // worker id 0..nblk-1

  constexpr int KI = H / 32;      // k-chunks of 32
  __shared__ half_t hs[32][HSROW];
  __shared__ float gates[32][133]; // [batch][gate*32 + hcol]
  int tid = threadIdx.x;
  int jb0 = wid * 32;              // 32 H-columns per worker
  int lane = tid & 63, wave = tid >> 6;   // wave == gate index
  int l15 = lane & 15, quad = lane >> 4;
  int bb = tid >> 3;               // batch row for elementwise
  int jj0 = (tid & 7) * 4;         // 4 H-cols per thread
  constexpr int H4 = 4 * H;

  float cst[4] = {0.f, 0.f, 0.f, 0.f};
  half8 wreg[2][KI];               // B fragments: [col frag][k chunk]

  auto loadw = [&](const half_t* __restrict__ whT) {
    #pragma unroll
    for (int f = 0; f < 2; ++f) {
      const half_t* wp = whT + (long)(wave*H + jb0 + f*16 + l15)*H + quad*8;
      #pragma unroll
      for (int i = 0; i < KI; ++i)
        wreg[f][i] = *reinterpret_cast<const half8*>(wp + i*32);
    }
  };

  auto loadpv = [&](int s, float (&pv)[16]) {
    const float* pr = (s < 15) ? preF : preR;
    int t = (s < 15) ? s : 29 - s;
    const float* pp = pr + (long)(bb*15 + t)*H4 + jb0 + jj0;
    #pragma unroll
    for (int g = 0; g < 4; ++g) {
      f32x4 v = *reinterpret_cast<const f32x4*>(pp + g*H);
      pv[g*4+0] = v[0]; pv[g*4+1] = v[1]; pv[g*4+2] = v[2]; pv[g*4+3] = v[3];
    }
  };

  loadw(whTF);
  float pv[16];
  loadpv(0, pv);

  for (int s = 0; s < 30; ++s) {
    if (s == 15) loadw(whTR);      // reverse direction: carry (cst) continues
    int t = (s < 15) ? s : 29 - s;
    int yoff = (s < 15) ? yoffF : yoffR;

    const unsigned long long* hsrc =
        (const unsigned long long*)(hbuf + (long)(s & 1) * 32 * H);
    if constexpr (H == 512) stage_h<16, 9>(hsrc, hs, tid);
    else                    stage_h<8, 8>(hsrc, hs, tid);
    __syncthreads();

    f32x4 acc00 = {0.f,0.f,0.f,0.f}, acc10 = {0.f,0.f,0.f,0.f};
    f32x4 acc01 = {0.f,0.f,0.f,0.f}, acc11 = {0.f,0.f,0.f,0.f};
    #pragma unroll
    for (int i = 0; i < KI; ++i) {
      half8 a0 = *reinterpret_cast<half8*>(&hs[l15][i*32 + quad*8]);
      half8 a1 = *reinterpret_cast<half8*>(&hs[16 + l15][i*32 + quad*8]);
      acc00 = __builtin_amdgcn_mfma_f32_16x16x32_f16(a0, wreg[0][i], acc00, 0, 0, 0);
      acc10 = __builtin_amdgcn_mfma_f32_16x16x32_f16(a1, wreg[0][i], acc10, 0, 0, 0);
      acc01 = __builtin_amdgcn_mfma_f32_16x16x32_f16(a0, wreg[1][i], acc01, 0, 0, 0);
      acc11 = __builtin_amdgcn_mfma_f32_16x16x32_f16(a1, wreg[1][i], acc11, 0, 0, 0);
    }
    #pragma unroll
    for (int r = 0; r < 4; ++r) {
      gates[quad*4 + r][wave*32 + l15]           = acc00[r];
      gates[16 + quad*4 + r][wave*32 + l15]      = acc10[r];
      gates[quad*4 + r][wave*32 + 16 + l15]      = acc01[r];
      gates[16 + quad*4 + r][wave*32 + 16 + l15] = acc11[r];
    }
    __syncthreads();

    unsigned long long hpack;
    {
      half_t hn[4];
      #pragma unroll
      for (int p = 0; p < 4; ++p) {
        int j = jj0 + p;
        float gi = pv[p]      + gates[bb][j];
        float gf = pv[4 + p]  + gates[bb][32 + j];
        float gg = pv[8 + p]  + gates[bb][64 + j];
        float go = pv[12 + p] + gates[bb][96 + j];
        gi = fsig_(gi); gf = fsig_(gf); gg = ftanh_(gg); go = fsig_(go);
        float cn = gf * cst[p] + gi * gg;
        cst[p] = cn;
        hn[p] = (half_t)(go * ftanh_(cn));
      }
      hpack = *reinterpret_cast<unsigned long long*>(hn);
      half_t* hdst = hbuf + (long)((s + 1) & 1) * 32 * H;
      __hip_atomic_store((unsigned long long*)(hdst + (long)bb*H + jb0 + jj0), hpack,
                         __ATOMIC_RELAXED, __HIP_MEMORY_SCOPE_AGENT);
    }

    if (s < 29) {
      __syncthreads();             // drains vmcnt -> h stores visible
      if (tid == 0)
        __hip_atomic_store(&flags[wid], s + 1,
                           __ATOMIC_RELAXED, __HIP_MEMORY_SCOPE_AGENT);
      *reinterpret_cast<unsigned long long*>(
          &y[(long)(bb*15 + t)*ystride + yoff + jb0 + jj0]) = hpack;
      loadpv(s + 1, pv);           // prefetch next pv under the spin-wait
      if (tid < 64) {
        int target = s + 1;
        for (;;) {
          int vv = (tid < nblk)
            ? __hip_atomic_load(&flags[tid], __ATOMIC_RELAXED, __HIP_MEMORY_SCOPE_AGENT)
            : target;
          if (__all(vv >= target)) break;
        }
      }
      __syncthreads();
    } else {
      *reinterpret_cast<unsigned long long*>(
          &y[(long)(bb*15 + t)*ystride + yoff + jb0 + jj0]) = hpack;
    }
  }
}

// ------------------------------------------------------------------
// Host orchestration
// ------------------------------------------------------------------
extern "C" void kernel_launch(void* const* d_in, const int* in_sizes, int n_in,
                              void* d_out, int out_size, void* d_ws, size_t ws_size,
                              hipStream_t stream)
{
  const float* x       = (const float*)d_in[0];
  const float* c1w     = (const float*)d_in[1];  const float* c1b = (const float*)d_in[2];
  const float* c2w     = (const float*)d_in[3];  const float* c2b = (const float*)d_in[4];
  const float* c3w     = (const float*)d_in[5];  const float* c3b = (const float*)d_in[6];
  const float* bn1s    = (const float*)d_in[7];  const float* bn1b = (const float*)d_in[8];
  const float* c4w     = (const float*)d_in[9];  const float* c4b = (const float*)d_in[10];
  const float* bn2s    = (const float*)d_in[11]; const float* bn2b = (const float*)d_in[12];
  const float* c5w     = (const float*)d_in[13]; const float* c5b = (const float*)d_in[14];
  const float* bn3s    = (const float*)d_in[15]; const float* bn3b = (const float*)d_in[16];
  const float* c6w     = (const float*)d_in[17]; const float* c6b = (const float*)d_in[18];
  const float* bn4s    = (const float*)d_in[19]; const float* bn4b = (const float*)d_in[20];
  const float* c7w     = (const float*)d_in[21]; const float* c7b = (const float*)d_in[22];
  const float* bn5s    = (const float*)d_in[23]; const float* bn5b = (const float*)d_in[24];
  const float* wq      = (const float*)d_in[25]; const float* bq = (const float*)d_in[26];
  const float* wk      = (const float*)d_in[27]; const float* bk = (const float*)d_in[28];
  const float* wv      = (const float*)d_in[29]; const float* bv = (const float*)d_in[30];
  const float* l1f_wx  = (const float*)d_in[31]; const float* l1f_wh = (const float*)d_in[32]; const float* l1f_b = (const float*)d_in[33];
  const float* l1r_wx  = (const float*)d_in[34]; const float* l1r_wh = (const float*)d_in[35]; const float* l1r_b = (const float*)d_in[36];
  const float* l2f_wx  = (const float*)d_in[37]; const float* l2f_wh = (const float*)d_in[38]; const float* l2f_b = (const float*)d_in[39];
  const float* l2r_wx  = (const float*)d_in[40]; const float* l2r_wh = (const float*)d_in[41]; const float* l2r_b = (const float*)d_in[42];
  const float* wo      = (const float*)d_in[43]; const float* bo = (const float*)d_in[44];
  float* outp = (float*)d_out;

  char* base = (char*)d_ws;
  half_t* actA = (half_t*)base;
  half_t* actB = (half_t*)(base + 67108864);
  half_t* wtA  = (half_t*)(base + 100663296);
  float*  f32a = (float*)(base + 143687680);
  half_t* h16a = (half_t*)(base + 158736384);

  half_t* wt2  = wtA;
  half_t* wt3  = wtA + 73728;
  half_t* wt4  = wtA + 368640;
  half_t* wt5  = wtA + 958464;
  half_t* wt6  = wtA + 2138112;
  half_t* wt7  = wtA + 4497408;
  half_t* wtq  = wtA + 5545984;        // wtq|wtk|wtv contiguous -> [1536][7680]
  half_t* wtk  = wtA + 9478144;
  half_t* wtv  = wtA + 13410304;
  half_t* wt1f = wtA + 17342464;
  half_t* wt1r = wtA + 17866752;
  half_t* wt2f = wtA + 18391040;
  half_t* wt2r = wtA + 19439616;
  half_t* wto  = wtA + 20488192;

  float* qkvbuf = f32a;                // 480 x 1536 f32
  float* pre1f = f32a + 737280;
  float* pre1r = f32a + 1228800;
  float* pre2f = f32a + 1720320;
  float* pre2r = f32a + 2703360;

  half_t* ao  = h16a;
  half_t* x1  = h16a + 245760;
  half_t* x2  = h16a + 491520;
  half_t* hb1 = h16a + 983040;              // 2 x 32 x 256 fp16
  half_t* hb2 = hb1 + 16384;                // 2 x 32 x 512 fp16
  int*    flags1 = (int*)(hb2 + 32768);     // 512 ints
  int*    flags2 = flags1 + 512;
  half_t* zbuf   = (half_t*)(flags2 + 512); // 32 halves
  float*  bnz    = (float*)(zbuf + 32);     // 5 x 2048 floats

  // transposed fp16 LSTM recurrent weights [4H][H] (appended past bnz)
  half_t* whT1f = (half_t*)(base + 160849920);   // 1024x256 = 512KB
  half_t* whT1r = (half_t*)(base + 161374208);
  half_t* whT2f = (half_t*)(base + 161898496);   // 2048x512 = 2MB
  half_t* whT2r = (half_t*)(base + 163995648);   // end 166,092,800

  auto convm = [&](const half_t* in, const half_t* wt, const float* b, void* out,
                   int N,int H,int W,int Ci,int Ho,int Wo,int Co,
                   int KH,int KW,int pH,int pW,int flags, float* bns){
    int M = N*Ho*Wo, K = KH*KW*Ci;
    dim3 grid(DIV_UP(Co,128), DIV_UP(M,128), 1);
    GOut g{wt, b, out};
    mfma_conv_kernel<<<grid,256,0,stream>>>(in,g,g,g,zbuf,bns,N,H,W,Ci,Ho,Wo,Co,
                                            KH,KW,pH,pW,M,K,flags,1);
  };
  auto gemm3 = [&](const half_t* A, GOut g0, GOut g1, GOut g2, int nz,
                   int M, int Nn, int K, int flags, int splitS){
    dim3 grid(DIV_UP(Nn,128), DIV_UP(M,128), nz);
    mfma_conv_kernel<<<grid,256,0,stream>>>(A,g0,g1,g2,zbuf,bnz,M,1,1,K,1,1,Nn,
                                            1,1,0,0,M,K,flags,splitS);
  };
  auto pool = [&](const half_t* in, half_t* out, int N,int H,int W,int C,
                  int Ho,int Wo,int sH,int sW){
    long total8 = (long)N*Ho*Wo*(C/8);
    maxpool8_kernel<<<(int)DIV_UP(total8,256),256,0,stream>>>(in,out,N,H,W,C,Ho,Wo,sH,sW);
  };
  auto bnApply = [&](half_t* buf, long nPix, int C, const float* s, const float* b,
                     float* sums){
    long total8 = nPix * C / 8;
    bn_apply_relu8_kernel<<<(int)DIV_UP(total8,256),256,0,stream>>>(buf, sums, s, b, total8, C, 1.0f/(float)nPix);
  };
  auto bnPool = [&](const half_t* in, half_t* out, int N,int H,int W,int C,
                    int Ho,int Wo,int sH,int sW, long nPix,
                    const float* s, const float* b, float* sums){
    long total8 = (long)N*Ho*Wo*(C/8);
    bn_pool8_kernel<<<(int)DIV_UP(total8,256),256,0,stream>>>(
        in,out,sums,s,b,N,H,W,C,Ho,Wo,sH,sW,1.0f/(float)nPix);
  };

  // one zero-fill: hb1/hb2, flags, zbuf, 5 bn-sum buffers
  hipMemsetAsync(hb1, 0, 143424, stream);

  // ---- ALL weight transposes in one launch (incl. LSTM Wh -> fp16 [4H][H]) ----
  {
    TpAll tp;
    const float* srcs[NTP] = {c2w,c3w,c4w,c5w,c6w,c7w,wq,wk,wv,l1f_wx,l1r_wx,l2f_wx,l2r_wx,wo,
                              l1f_wh,l1r_wh,l2f_wh,l2r_wh};
    half_t* dsts[NTP] = {wt2,wt3,wt4,wt5,wt6,wt7,wtq,wtk,wtv,wt1f,wt1r,wt2f,wt2r,wto,
                         whT1f,whT1r,whT2f,whT2r};
    int Ks[NTP] = {576,1152,2304,2304,4608,2048,7680,7680,7680,512,512,512,512,1024,
                   256,256,512,512};
    int Ns[NTP] = {128,256,256,512,512,512,512,512,512,1024,1024,2048,2048,1000,
                   1024,1024,2048,2048};
    int acc = 0;
    for (int i = 0; i < NTP; ++i) {
      tp.src[i] = srcs[i]; tp.dst[i] = dsts[i]; tp.K[i] = Ks[i]; tp.N[i] = Ns[i];
      tp.prefix[i] = acc;
      acc += DIV_UP(Ks[i],32) * DIV_UP(Ns[i],32);
    }
    tp.prefix[NTP] = acc;
    transpose_cvt_all_kernel<<<acc,256,0,stream>>>(tp);
  }

  // ---- conv stack (activations fp16) ----
  conv1_pool_kernel<<<1024,256,0,stream>>>(x, c1w, c1b, actB);  // fused conv1+pool1
  convm(actB, wt2, c2b, actA, 32,32,128,64,  32,128,128, 3,3,1,1, FLAG_RELU, bnz);
  pool(actA, actB, 32,32,128,128, 16,64, 2,2);
  convm(actB, wt3, c3b, actA, 32,16,64,128,  16,64,256,  3,3,1,1, FLAG_BNSUMS, bnz);
  bnApply(actA, 32768, 256, bn1s, bn1b, bnz);
  convm(actA, wt4, c4b, actB, 32,16,64,256,  16,64,256,  3,3,1,1, FLAG_BNSUMS, bnz + 2048);
  bnPool(actB, actA, 32,16,64,256, 16,32, 1,2, 32768, bn2s, bn2b, bnz + 2048);
  convm(actA, wt5, c5b, actB, 32,16,32,256,  16,32,512,  3,3,1,1, FLAG_BNSUMS, bnz + 4096);
  bnApply(actB, 16384, 512, bn3s, bn3b, bnz + 4096);
  convm(actB, wt6, c6b, actA, 32,16,32,512,  16,32,512,  3,3,1,1, FLAG_BNSUMS, bnz + 6144);
  bnPool(actA, actB, 32,16,32,512, 16,16, 1,2, 16384, bn4s, bn4b, bnz + 6144);
  convm(actB, wt7, c7b, actA, 32,16,16,512,  15,15,512,  2,2,0,0, FLAG_BNSUMS, bnz + 8192);
  bnApply(actA, 7200, 512, bn5s, bn5b, bnz + 8192);

  // ---- attention: single qkv GEMM (N=1536), split-K x4, atomic epilogue ----
  bias_fill_kernel<<<DIV_UP(480*1536,256),256,0,stream>>>(qkvbuf, bq, bk, bv, 480*1536);
  gemm3(actA, GOut{wtq, nullptr, qkvbuf}, GOut{wtq, nullptr, qkvbuf},
        GOut{wtq, nullptr, qkvbuf}, 4, 480, 1536, 7680, FLAG_SPLITK|FLAG_ATOMIC, 4);
  attention_kernel<<<32,256,0,stream>>>(qkvbuf, ao, 15, 512, 1536);

  // ---- LSTM stack 1 (H=256): 8 workers (XCD-pinned, grid 64) ----
  gemm3(ao, GOut{wt1f, l1f_b, pre1f}, GOut{wt1r, l1r_b, pre1r},
        GOut{wt1r, l1r_b, pre1r}, 2, 480, 1024, 512, FLAG_OUTF32, 1);
  lstm_persistent_kernel<256><<<64,256,0,stream>>>(
      pre1f, pre1r, whT1f, whT1r, hb1, x1, flags1, 8, 512, 0, 256);

  // ---- LSTM stack 2 (H=512): 16 workers (XCD-pinned, grid 128) ----
  gemm3(x1, GOut{wt2f, l2f_b, pre2f}, GOut{wt2r, l2r_b, pre2r},
        GOut{wt2r, l2r_b, pre2r}, 2, 480, 2048, 512, FLAG_OUTF32, 1);
  lstm_persistent_kernel<512><<<128,256,0,stream>>>(
      pre2f, pre2r, whT2f, whT2r, hb2, x2, flags2, 16, 1024, 512, 0);

  // ---- classifier ----
  gemm3(x2, GOut{wto, bo, outp}, GOut{wto, bo, outp}, GOut{wto, bo, outp}, 1,
        480, 1000, 1024, FLAG_OUTF32, 1);
}

// Round 10
// 989.924 us; speedup vs baseline: 1.4736x; 1.0098x over previous
//
#include <hip/hip_runtime.h>
#include <math.h>

#define DIV_UP(a,b) (((a)+(b)-1)/(b))

typedef _Float16 half_t;
typedef _Float16 half8 __attribute__((ext_vector_type(8)));
typedef float f32x4 __attribute__((ext_vector_type(4)));

#define FLAG_RELU   1
#define FLAG_OUTF32 2
#define FLAG_SPLITK 4
#define FLAG_BNSUMS 16

#define GLDS16(src, dst) \
  __builtin_amdgcn_global_load_lds((const __attribute__((address_space(1))) void*)(src), \
                                   (__attribute__((address_space(3))) void*)(dst), 16, 0, 0)

__device__ __forceinline__ float fsig_(float x){ return 1.0f/(1.0f+__expf(-x)); }
__device__ __forceinline__ float ftanh_(float x){
  float ax = fabsf(x);
  float e = __expf(-2.0f*ax);
  float t = (1.0f - e)/(1.0f + e);
  return copysignf(t, x);
}

// ------------------------------------------------------------------
// ALL weight transposes (fp32 [K][N] -> fp16 [N][K]) in ONE launch.
// ------------------------------------------------------------------
#define NTP 18
struct TpAll {
  const float* src[NTP];
  half_t* dst[NTP];
  int K[NTP];
  int N[NTP];
  int prefix[NTP+1];
};

__global__ __launch_bounds__(256) void transpose_cvt_all_kernel(TpAll a)
{
  __shared__ float tile[32][33];
  int bid = blockIdx.x;
  int z = 0;
  while (bid >= a.prefix[z+1]) ++z;
  int local = bid - a.prefix[z];
  const float* w = a.src[z];
  half_t* wT = a.dst[z];
  int K = a.K[z], N = a.N[z];
  int tilesX = (N + 31) >> 5;
  int nt = (local % tilesX) * 32;
  int kt = (local / tilesX) * 32;
  int tx = threadIdx.x & 31, ty = threadIdx.x >> 5;
  #pragma unroll
  for (int r = 0; r < 4; ++r) {
    int k = kt + ty + r*8, n = nt + tx;
    tile[ty + r*8][tx] = (k < K && n < N) ? w[(long)k*N + n] : 0.f;
  }
  __syncthreads();
  #pragma unroll
  for (int r = 0; r < 4; ++r) {
    int n = nt + ty + r*8, k = kt + tx;
    if (n < N && k < K) wT[(long)n*K + k] = (half_t)tile[tx][ty + r*8];
  }
}

// ------------------------------------------------------------------
// conv1 FUSED with maxpool1 (R9).
// ------------------------------------------------------------------
__global__ __launch_bounds__(256) void conv1_pool_kernel(
    const float* __restrict__ x, const float* __restrict__ w,
    const float* __restrict__ bias, half_t* __restrict__ out)
{
  __shared__ float xs[4][258*3];
  int nb = blockIdx.x;            // n*32 + ho2
  int n = nb >> 5, ho2 = nb & 31;
  int tid = threadIdx.x;
  int co = tid & 63;
  float wreg[27];
  #pragma unroll
  for (int k = 0; k < 27; ++k) wreg[k] = w[k*64 + co];
  float bco = bias[co];
  for (int i = tid; i < 4*258*3; i += 256) {
    int row = i / (258*3); int rem = i % (258*3);
    int col = rem / 3;     int ci  = rem % 3;
    int ih = ho2*2 - 1 + row; int iw = col - 1;
    float v = 0.f;
    if (ih >= 0 && ih < 64 && iw >= 0 && iw < 256)
      v = x[(((long)n*64 + ih)*256 + iw)*3 + ci];
    xs[row][col*3 + ci] = v;
  }
  __syncthreads();
  int wave = tid >> 6;
  float mprev = 0.f;
  for (int p = 0; p < 64; ++p) {
    int wo = wave*64 + p;
    float acc0 = bco, acc1 = bco;
    #pragma unroll
    for (int kh = 0; kh < 3; ++kh)
      #pragma unroll
      for (int kw = 0; kw < 3; ++kw)
        #pragma unroll
        for (int ci = 0; ci < 3; ++ci) {
          float wv = wreg[(kh*3+kw)*3 + ci];
          acc0 = fmaf(xs[kh]  [(wo+kw)*3 + ci], wv, acc0);
          acc1 = fmaf(xs[kh+1][(wo+kw)*3 + ci], wv, acc1);
        }
    float m = fmaxf(fmaxf(acc0, 0.f), fmaxf(acc1, 0.f));
    if (p & 1) {
      int wo2 = (wave*64 + p) >> 1;
      out[(((long)n*32 + ho2)*128 + wo2)*64 + co] = (half_t)fmaxf(m, mprev);
    } else {
      mprev = m;
    }
  }
}

// ------------------------------------------------------------------
// MFMA implicit-GEMM conv/GEMM. 128x128 tile, BK=64, 4 waves.
// R3: XCD-aware bijective remap. R4: double-buffered K-loop.
// R8: counted vmcnt. R10: FLAG_SPLITK now stores per-slice PARTIALS
// (plain f32 stores at z*M*Co offset) instead of 2.95M atomicAdds;
// the reduce+bias moved into attention_kernel phase 0.
// ------------------------------------------------------------------
struct GOut { const half_t* wT; const float* bias; void* out; };

__global__ __launch_bounds__(256) void mfma_conv_kernel(
    const half_t* __restrict__ x, GOut g0, GOut g1, GOut g2,
    const half_t* __restrict__ zbuf, float* __restrict__ bns,
    int N,int H,int W,int Ci,int Ho,int Wo,int Co,
    int KH,int KW,int padH,int padW,
    int M,int K,int flags,int splitS)
{
  GOut g;
  int ciBeg = 0, ciEnd = Ci;
  if (flags & FLAG_SPLITK) {
    g = g0;
    int span = Ci / splitS;
    ciBeg = blockIdx.z * span;
    ciEnd = ciBeg + span;
  } else {
    g = (blockIdx.z == 0) ? g0 : (blockIdx.z == 1 ? g1 : g2);
  }
  const half_t* __restrict__ wT = g.wT;
  __shared__ half_t As[2][128*64];
  __shared__ half_t Bs[2][128*64];
  int tid = threadIdx.x;

  // ---- XCD-aware bijective remap: slot -> work (m-major, n fastest) ----
  int nbx = gridDim.x, nby = gridDim.y;
  int total = nbx * nby;
  int flat = blockIdx.y * nbx + blockIdx.x;   // dispatch slot within z-slice
  int q = total >> 3, r = total & 7;
  int xcd = flat & 7;                          // hw XCD (round-robin heuristic)
  int j = flat >> 3;                           // j-th slot on that XCD
  int w = xcd * q + (xcd < r ? xcd : r) + j;   // contiguous work band per XCD
  int m0 = (w / nbx) * 128, n0 = (w % nbx) * 128;

  int wave = tid >> 6, lane = tid & 63;
  int l15 = lane & 15, quad = lane >> 4;
  int x7 = lane & 7;
  int wm = (wave & 1) * 64, wn = (wave >> 1) * 64;

  // staging decode: 4 issues, row_i = i*32 + (tid>>3), source chunk swizzled
  int rSub = tid >> 3;
  int colHalf = (((tid & 7) ^ (rSub & 7))) * 8;

  int ho_[4], wo_[4], ni_[4]; bool av_[4];
  #pragma unroll
  for (int i = 0; i < 4; ++i) {
    int m = m0 + i*32 + rSub;
    av_[i] = m < M;
    int mm = av_[i] ? m : 0;
    wo_[i] = mm % Wo; int t2 = mm / Wo;
    ho_[i] = t2 % Ho; ni_[i] = t2 / Ho;
  }
  const half_t* bBase[4];
  #pragma unroll
  for (int i = 0; i < 4; ++i) {
    int n = n0 + i*32 + rSub;
    bBase[i] = (n < Co) ? (wT + (long)n*K + colHalf) : nullptr;
  }

  // fragment LDS chunk offsets per k-sub (conflict-free via XOR swizzle)
  int pch0 = ((quad)     ^ x7) * 8;
  int pch1 = ((4 + quad) ^ x7) * 8;

  f32x4 acc[4][4];
  #pragma unroll
  for (int i = 0; i < 4; ++i)
    #pragma unroll
    for (int j2 = 0; j2 < 4; ++j2)
      acc[i][j2] = (f32x4){0.f, 0.f, 0.f, 0.f};

  // ---- staging state: running (skh, skw, sci) k-tile coordinates ----
  int NT = ((ciEnd - ciBeg) >> 6) * KH * KW;
  int skh = 0, skw = 0, sci = ciBeg;
  long sAOff[4]; bool sAval[4];
  auto recompA = [&]() {
    #pragma unroll
    for (int i = 0; i < 4; ++i) {
      int ih = ho_[i] - padH + skh, iw = wo_[i] - padW + skw;
      bool ok = av_[i] && ih >= 0 && ih < H && iw >= 0 && iw < W;
      sAval[i] = ok;
      sAOff[i] = ok ? ((((long)ni_[i]*H + ih)*W + iw)*(long)Ci + colHalf) : 0;
    }
  };
  recompA();
  auto stage = [&](int b) {
    int kgS = (skh*KW + skw)*Ci + sci;           // global B k-index
    #pragma unroll
    for (int i = 0; i < 4; ++i) {
      const half_t* sa = sAval[i] ? (x + sAOff[i] + sci) : zbuf;
      GLDS16(sa, &As[b][i*2048 + wave*512]);
      const half_t* sb = bBase[i] ? (bBase[i] + kgS) : zbuf;
      GLDS16(sb, &Bs[b][i*2048 + wave*512]);
    }
  };
  auto advance = [&]() {
    sci += 64;
    if (sci == ciEnd) {
      sci = ciBeg; ++skw;
      if (skw == KW) { skw = 0; ++skh; }
      recompA();
    }
  };

  stage(0); advance();             // prologue: buf0 in flight

  for (int kt = 0; kt < NT; ++kt) {
    int p = kt & 1;
    if (kt + 1 < NT) {
      stage(p ^ 1); advance();     // 8 new loads in flight (buf p^1)
      asm volatile("s_waitcnt vmcnt(8)" ::: "memory");  // wait buf p's 8 (oldest)
    } else {
      asm volatile("s_waitcnt vmcnt(0)" ::: "memory");  // last: drain
    }
    __builtin_amdgcn_s_barrier();  // all waves: buf p fully written
    asm volatile("" ::: "memory");
    {
      half8 af[4], bf[4];
      #pragma unroll
      for (int i = 0; i < 4; ++i)
        af[i] = *reinterpret_cast<half8*>(&As[p][(wm + i*16 + l15)*64 + pch0]);
      #pragma unroll
      for (int j2 = 0; j2 < 4; ++j2)
        bf[j2] = *reinterpret_cast<half8*>(&Bs[p][(wn + j2*16 + l15)*64 + pch0]);
      #pragma unroll
      for (int i = 0; i < 4; ++i)
        #pragma unroll
        for (int j2 = 0; j2 < 4; ++j2)
          acc[i][j2] = __builtin_amdgcn_mfma_f32_16x16x32_f16(af[i], bf[j2], acc[i][j2], 0, 0, 0);
    }
    {
      half8 af[4], bf[4];
      #pragma unroll
      for (int i = 0; i < 4; ++i)
        af[i] = *reinterpret_cast<half8*>(&As[p][(wm + i*16 + l15)*64 + pch1]);
      #pragma unroll
      for (int j2 = 0; j2 < 4; ++j2)
        bf[j2] = *reinterpret_cast<half8*>(&Bs[p][(wn + j2*16 + l15)*64 + pch1]);
      #pragma unroll
      for (int i = 0; i < 4; ++i)
        #pragma unroll
        for (int j2 = 0; j2 < 4; ++j2)
          acc[i][j2] = __builtin_amdgcn_mfma_f32_16x16x32_f16(af[i], bf[j2], acc[i][j2], 0, 0, 0);
    }
    asm volatile("" ::: "memory");
    __builtin_amdgcn_s_barrier();  // all waves done reading buf p
  }

  // ---- BN sums from accumulators (f32, pre-relu value incl. bias) ----
  if (flags & FLAG_BNSUMS) {
    float* red = (float*)As;     // [wave][quad][l15][j][2] = 4*4*16*4*2 floats
    #pragma unroll
    for (int j2 = 0; j2 < 4; ++j2) {
      int n = n0 + wn + j2*16 + l15;
      float bv = g.bias[n];
      float s = 0.f, qq = 0.f;
      #pragma unroll
      for (int i = 0; i < 4; ++i)
        #pragma unroll
        for (int rr = 0; rr < 4; ++rr) {
          int m = m0 + wm + i*16 + quad*4 + rr;
          if (m < M) { float v = acc[i][j2][rr] + bv; s += v; qq += v*v; }
        }
      int idx = ((((wave*4 + quad)*16 + l15)*4) + j2)*2;
      red[idx] = s; red[idx+1] = qq;
    }
    __syncthreads();
    if (tid < 128) {
      int hi = tid >> 6;               // which 64-channel half (wn)
      int jj = (tid >> 4) & 3, ll = tid & 15;
      float s = 0.f, qq = 0.f;
      #pragma unroll
      for (int w2 = 0; w2 < 2; ++w2)
        #pragma unroll
        for (int qd = 0; qd < 4; ++qd) {
          int idx = (((((hi*2 + w2)*4 + qd)*16 + ll)*4) + jj)*2;
          s += red[idx]; qq += red[idx+1];
        }
      int n = n0 + tid;                // == n0 + hi*64 + jj*16 + ll
      atomicAdd(&bns[n], s);
      atomicAdd(&bns[Co + n], qq);
    }
  }

  // ---- store ----
  #pragma unroll
  for (int i = 0; i < 4; ++i) {
    #pragma unroll
    for (int rr = 0; rr < 4; ++rr) {
      int m = m0 + wm + i*16 + quad*4 + rr;
      if (m >= M) continue;
      #pragma unroll
      for (int j2 = 0; j2 < 4; ++j2) {
        int n = n0 + wn + j2*16 + l15;
        if (n >= Co) continue;
        if (flags & FLAG_SPLITK) {
          // per-slice partial, no bias (reduced in attention phase 0)
          ((float*)g.out)[((long)blockIdx.z*M + m)*Co + n] = acc[i][j2][rr];
        } else {
          float v = acc[i][j2][rr] + g.bias[n];
          if (flags & FLAG_RELU) v = fmaxf(v, 0.f);
          if (flags & FLAG_OUTF32) ((float*)g.out)[(long)m*Co + n] = v;
          else ((half_t*)g.out)[(long)m*Co + n] = (half_t)v;
        }
      }
    }
  }
}

// ------------------------------------------------------------------
// Max pool fp16, NHWC, 8 channels per thread.
// ------------------------------------------------------------------
__global__ __launch_bounds__(256) void maxpool8_kernel(
    const half_t* __restrict__ x, half_t* __restrict__ out,
    int N,int H,int W,int C,int Ho,int Wo,int sH,int sW)
{
  int C8 = C >> 3;
  long idx = (long)blockIdx.x*256 + threadIdx.x;
  long total8 = (long)N*Ho*Wo*C8;
  if (idx >= total8) return;
  int cb = (int)(idx % C8);
  long pix = idx / C8;
  int wo = (int)(pix % Wo); long t2 = pix / Wo;
  int ho = (int)(t2 % Ho); int n = (int)(t2 / Ho);
  int c = cb * 8;
  float m[8];
  #pragma unroll
  for (int e = 0; e < 8; ++e) m[e] = -INFINITY;
  for (int i = 0; i < 2; ++i) {
    int ih = ho*sH + i;
    if (ih >= H) continue;
    for (int j = 0; j < 2; ++j) {
      int iw = wo*sW + j;
      if (iw >= W) continue;
      half8 v = *reinterpret_cast<const half8*>(x + (((long)n*H + ih)*W + iw)*C + c);
      #pragma unroll
      for (int e = 0; e < 8; ++e) m[e] = fmaxf(m[e], (float)v[e]);
    }
  }
  half8 o;
  #pragma unroll
  for (int e = 0; e < 8; ++e) o[e] = (half_t)m[e];
  *reinterpret_cast<half8*>(out + idx*8) = o;
}

// ------------------------------------------------------------------
// BN apply + ReLU (in place), 8 channels/thread.
// ------------------------------------------------------------------
__global__ __launch_bounds__(256) void bn_apply_relu8_kernel(
    half_t* __restrict__ x, const float* __restrict__ sums,
    const float* __restrict__ scale, const float* __restrict__ bias,
    long total8, int C, float invN)
{
  long idx = (long)blockIdx.x*256 + threadIdx.x;
  if (idx >= total8) return;
  int c = (int)((idx*8) % C);
  half8 v = *reinterpret_cast<half8*>(x + idx*8);
  half8 o;
  #pragma unroll
  for (int e = 0; e < 8; ++e) {
    float mean = sums[c+e] * invN;
    float var  = sums[C + c+e] * invN - mean*mean;
    float rstd = rsqrtf(var + 1e-5f);
    float y = ((float)v[e] - mean) * rstd * scale[c+e] + bias[c+e];
    o[e] = (half_t)fmaxf(y, 0.0f);
  }
  *reinterpret_cast<half8*>(x + idx*8) = o;
}

// ------------------------------------------------------------------
// Fused BN+ReLU+maxpool: out (N,Ho,Wo,C) from in (N,H,W,C).
// ------------------------------------------------------------------
__global__ __launch_bounds__(256) void bn_pool8_kernel(
    const half_t* __restrict__ x, half_t* __restrict__ out,
    const float* __restrict__ sums, const float* __restrict__ scale,
    const float* __restrict__ bias,
    int N,int H,int W,int C,int Ho,int Wo,int sH,int sW, float invN)
{
  int C8 = C >> 3;
  long idx = (long)blockIdx.x*256 + threadIdx.x;
  long total8 = (long)N*Ho*Wo*C8;
  if (idx >= total8) return;
  int cb = (int)(idx % C8);
  long pix = idx / C8;
  int wo = (int)(pix % Wo); long t2 = pix / Wo;
  int ho = (int)(t2 % Ho); int n = (int)(t2 / Ho);
  int c = cb * 8;
  float mean[8], rs[8], bb[8];
  #pragma unroll
  for (int e = 0; e < 8; ++e) {
    mean[e] = sums[c+e] * invN;
    float var = sums[C + c+e] * invN - mean[e]*mean[e];
    rs[e] = rsqrtf(var + 1e-5f) * scale[c+e];
    bb[e] = bias[c+e];
  }
  float m[8];
  #pragma unroll
  for (int e = 0; e < 8; ++e) m[e] = -INFINITY;
  for (int i = 0; i < 2; ++i) {
    int ih = ho*sH + i;
    if (ih >= H) continue;
    for (int j = 0; j < 2; ++j) {
      int iw = wo*sW + j;
      if (iw >= W) continue;
      half8 v = *reinterpret_cast<const half8*>(x + (((long)n*H + ih)*W + iw)*C + c);
      #pragma unroll
      for (int e = 0; e < 8; ++e) {
        float y = fmaxf(((float)v[e] - mean[e]) * rs[e] + bb[e], 0.f);
        m[e] = fmaxf(m[e], y);
      }
    }
  }
  half8 o;
  #pragma unroll
  for (int e = 0; e < 8; ++e) o[e] = (half_t)m[e];
  *reinterpret_cast<half8*>(out + idx*8) = o;
}

// ------------------------------------------------------------------
// Attention (T=15, D=512). R10: phase 0 reduces the 4 split-K qkv
// partials + bias into qkvbuf (replaces bias_fill + atomics), then
// the original QK^T/softmax/PV body runs on qkvbuf.
// ------------------------------------------------------------------
__global__ __launch_bounds__(256) void attention_kernel(
    const float* __restrict__ qkvp, const float* __restrict__ bq,
    const float* __restrict__ bk, const float* __restrict__ bv,
    float* __restrict__ qkv, half_t* __restrict__ out,
    int T, int D, int ld)
{
  int b = blockIdx.x;
  int tid = threadIdx.x;
  __shared__ float P[15][16];

  // ---- phase 0: reduce 4 partials + bias -> qkv rows for this batch ----
  {
    const long pstr = (long)480 * 1536;
    for (int i = tid; i < T*384; i += 256) {       // float4 granularity
      int t = i / 384, n4 = (i % 384) * 4;
      long off = ((long)b*T + t)*1536 + n4;
      f32x4 v = *reinterpret_cast<const f32x4*>(qkvp + off);
      v += *reinterpret_cast<const f32x4*>(qkvp + off + pstr);
      v += *reinterpret_cast<const f32x4*>(qkvp + off + 2*pstr);
      v += *reinterpret_cast<const f32x4*>(qkvp + off + 3*pstr);
      const float* bp = (n4 < 512) ? (bq + n4) : (n4 < 1024 ? bk + n4 - 512 : bv + n4 - 1024);
      v += *reinterpret_cast<const f32x4*>(bp);
      *reinterpret_cast<f32x4*>(qkv + off) = v;
    }
    __syncthreads();
  }

  if (tid < T*T) {
    int t = tid / T, s = tid % T;
    const float* qp = qkv + ((long)b*T + t)*ld;
    const float* kp = qkv + ((long)b*T + s)*ld + 512;
    float acc = 0.f;
    for (int d = 0; d < D; d += 4) {
      float4 qv = *reinterpret_cast<const float4*>(qp + d);
      float4 kv = *reinterpret_cast<const float4*>(kp + d);
      acc += qv.x*kv.x + qv.y*kv.y + qv.z*kv.z + qv.w*kv.w;
    }
    P[t][s] = acc * (1.0f/32.0f);
  }
  __syncthreads();
  if (tid < T) {
    float mx = -INFINITY;
    for (int s = 0; s < T; ++s) mx = fmaxf(mx, P[tid][s]);
    float sum = 0.f;
    for (int s = 0; s < T; ++s) { float e = expf(P[tid][s] - mx); P[tid][s] = e; sum += e; }
    float inv = 1.0f / sum;
    for (int s = 0; s < T; ++s) P[tid][s] *= inv;
  }
  __syncthreads();
  for (int idx = tid; idx < T*D; idx += 256) {
    int s = idx / D, kk2 = idx % D;
    float acc = 0.f;
    #pragma unroll
    for (int t = 0; t < 15; ++t)
      acc += qkv[((long)b*T + t)*ld + 1024 + kk2] * P[t][s];
    out[((long)b*T + s)*D + kk2] = (half_t)acc;
  }
}

// ------------------------------------------------------------------
// Persistent bidirectional LSTM — R7 version (R4 structure + XCD pin).
// Closed: ~3.5us/step is the agent-scope sync floor (R7 null).
// ------------------------------------------------------------------
#define MAXK 512
#define HSROW (MAXK + 8)

template<int N64, int HLOG>
__device__ __forceinline__ void stage_h(
    const unsigned long long* __restrict__ src, half_t (*hs)[HSROW], int tid)
{
  unsigned long long tmp[N64];
  #pragma unroll
  for (int u = 0; u < N64; ++u)
    tmp[u] = __hip_atomic_load(src + tid + u*256, __ATOMIC_RELAXED, __HIP_MEMORY_SCOPE_AGENT);
  #pragma unroll
  for (int u = 0; u < N64; ++u) {
    int idx = tid + u*256;
    int row = idx >> (HLOG - 2);
    int col = (idx & ((1 << (HLOG - 2)) - 1)) * 4;
    *reinterpret_cast<unsigned long long*>(&hs[row][col]) = tmp[u];
  }
}

template<int H>
__global__ __launch_bounds__(256, 1) void lstm_persistent_kernel(
    const float* __restrict__ preF, const float* __restrict__ preR,
    const half_t* __restrict__ whTF, const half_t* __restrict__ whTR,
    half_t* __restrict__ hbuf, half_t* __restrict__ y,
    int* __restrict__ flags, int nblk,
    int ystride, int yoffF, int yoffR)
{
  if (blockIdx.x & 7) return;      // XCD-pin: keep slot%8==0 -> one XCD
  int wid = blockIdx.x >> 3;       // worker id 0..nblk-1

  constexpr int KI = H / 32;      // k-chunks of 32
  __shared__ half_t hs[32][HSROW];
  __shared__ float gates[32][133]; // [batch][gate*32 + hcol]
  int tid = threadIdx.x;
  int jb0 = wid * 32;              // 32 H-columns per worker
  int lane = tid & 63, wave = tid >> 6;   // wave == gate index
  int l15 = lane & 15, quad = lane >> 4;
  int bb = tid >> 3;               // batch row for elementwise
  int jj0 = (tid & 7) * 4;         // 4 H-cols per thread
  constexpr int H4 = 4 * H;

  float cst[4] = {0.f, 0.f, 0.f, 0.f};
  half8 wreg[2][KI];               // B fragments: [col frag][k chunk]

  auto loadw = [&](const half_t* __restrict__ whT) {
    #pragma unroll
    for (int f = 0; f < 2; ++f) {
      const half_t* wp = whT + (long)(wave*H + jb0 + f*16 + l15)*H + quad*8;
      #pragma unroll
      for (int i = 0; i < KI; ++i)
        wreg[f][i] = *reinterpret_cast<const half8*>(wp + i*32);
    }
  };

  auto loadpv = [&](int s, float (&pv)[16]) {
    const float* pr = (s < 15) ? preF : preR;
    int t = (s < 15) ? s : 29 - s;
    const float* pp = pr + (long)(bb*15 + t)*H4 + jb0 + jj0;
    #pragma unroll
    for (int g = 0; g < 4; ++g) {
      f32x4 v = *reinterpret_cast<const f32x4*>(pp + g*H);
      pv[g*4+0] = v[0]; pv[g*4+1] = v[1]; pv[g*4+2] = v[2]; pv[g*4+3] = v[3];
    }
  };

  loadw(whTF);
  float pv[16];
  loadpv(0, pv);

  for (int s = 0; s < 30; ++s) {
    if (s == 15) loadw(whTR);      // reverse direction: carry (cst) continues
    int t = (s < 15) ? s : 29 - s;
    int yoff = (s < 15) ? yoffF : yoffR;

    const unsigned long long* hsrc =
        (const unsigned long long*)(hbuf + (long)(s & 1) * 32 * H);
    if constexpr (H == 512) stage_h<16, 9>(hsrc, hs, tid);
    else                    stage_h<8, 8>(hsrc, hs, tid);
    __syncthreads();

    f32x4 acc00 = {0.f,0.f,0.f,0.f}, acc10 = {0.f,0.f,0.f,0.f};
    f32x4 acc01 = {0.f,0.f,0.f,0.f}, acc11 = {0.f,0.f,0.f,0.f};
    #pragma unroll
    for (int i = 0; i < KI; ++i) {
      half8 a0 = *reinterpret_cast<half8*>(&hs[l15][i*32 + quad*8]);
      half8 a1 = *reinterpret_cast<half8*>(&hs[16 + l15][i*32 + quad*8]);
      acc00 = __builtin_amdgcn_mfma_f32_16x16x32_f16(a0, wreg[0][i], acc00, 0, 0, 0);
      acc10 = __builtin_amdgcn_mfma_f32_16x16x32_f16(a1, wreg[0][i], acc10, 0, 0, 0);
      acc01 = __builtin_amdgcn_mfma_f32_16x16x32_f16(a0, wreg[1][i], acc01, 0, 0, 0);
      acc11 = __builtin_amdgcn_mfma_f32_16x16x32_f16(a1, wreg[1][i], acc11, 0, 0, 0);
    }
    #pragma unroll
    for (int r = 0; r < 4; ++r) {
      gates[quad*4 + r][wave*32 + l15]           = acc00[r];
      gates[16 + quad*4 + r][wave*32 + l15]      = acc10[r];
      gates[quad*4 + r][wave*32 + 16 + l15]      = acc01[r];
      gates[16 + quad*4 + r][wave*32 + 16 + l15] = acc11[r];
    }
    __syncthreads();

    unsigned long long hpack;
    {
      half_t hn[4];
      #pragma unroll
      for (int p = 0; p < 4; ++p) {
        int j = jj0 + p;
        float gi = pv[p]      + gates[bb][j];
        float gf = pv[4 + p]  + gates[bb][32 + j];
        float gg = pv[8 + p]  + gates[bb][64 + j];
        float go = pv[12 + p] + gates[bb][96 + j];
        gi = fsig_(gi); gf = fsig_(gf); gg = ftanh_(gg); go = fsig_(go);
        float cn = gf * cst[p] + gi * gg;
        cst[p] = cn;
        hn[p] = (half_t)(go * ftanh_(cn));
      }
      hpack = *reinterpret_cast<unsigned long long*>(hn);
      half_t* hdst = hbuf + (long)((s + 1) & 1) * 32 * H;
      __hip_atomic_store((unsigned long long*)(hdst + (long)bb*H + jb0 + jj0), hpack,
                         __ATOMIC_RELAXED, __HIP_MEMORY_SCOPE_AGENT);
    }

    if (s < 29) {
      __syncthreads();             // drains vmcnt -> h stores visible
      if (tid == 0)
        __hip_atomic_store(&flags[wid], s + 1,
                           __ATOMIC_RELAXED, __HIP_MEMORY_SCOPE_AGENT);
      *reinterpret_cast<unsigned long long*>(
          &y[(long)(bb*15 + t)*ystride + yoff + jb0 + jj0]) = hpack;
      loadpv(s + 1, pv);           // prefetch next pv under the spin-wait
      if (tid < 64) {
        int target = s + 1;
        for (;;) {
          int vv = (tid < nblk)
            ? __hip_atomic_load(&flags[tid], __ATOMIC_RELAXED, __HIP_MEMORY_SCOPE_AGENT)
            : target;
          if (__all(vv >= target)) break;
        }
      }
      __syncthreads();
    } else {
      *reinterpret_cast<unsigned long long*>(
          &y[(long)(bb*15 + t)*ystride + yoff + jb0 + jj0]) = hpack;
    }
  }
}

// ------------------------------------------------------------------
// Host orchestration
// ------------------------------------------------------------------
extern "C" void kernel_launch(void* const* d_in, const int* in_sizes, int n_in,
                              void* d_out, int out_size, void* d_ws, size_t ws_size,
                              hipStream_t stream)
{
  const float* x       = (const float*)d_in[0];
  const float* c1w     = (const float*)d_in[1];  const float* c1b = (const float*)d_in[2];
  const float* c2w     = (const float*)d_in[3];  const float* c2b = (const float*)d_in[4];
  const float* c3w     = (const float*)d_in[5];  const float* c3b = (const float*)d_in[6];
  const float* bn1s    = (const float*)d_in[7];  const float* bn1b = (const float*)d_in[8];
  const float* c4w     = (const float*)d_in[9];  const float* c4b = (const float*)d_in[10];
  const float* bn2s    = (const float*)d_in[11]; const float* bn2b = (const float*)d_in[12];
  const float* c5w     = (const float*)d_in[13]; const float* c5b = (const float*)d_in[14];
  const float* bn3s    = (const float*)d_in[15]; const float* bn3b = (const float*)d_in[16];
  const float* c6w     = (const float*)d_in[17]; const float* c6b = (const float*)d_in[18];
  const float* bn4s    = (const float*)d_in[19]; const float* bn4b = (const float*)d_in[20];
  const float* c7w     = (const float*)d_in[21]; const float* c7b = (const float*)d_in[22];
  const float* bn5s    = (const float*)d_in[23]; const float* bn5b = (const float*)d_in[24];
  const float* wq      = (const float*)d_in[25]; const float* bq = (const float*)d_in[26];
  const float* wk      = (const float*)d_in[27]; const float* bk = (const float*)d_in[28];
  const float* wv      = (const float*)d_in[29]; const float* bv = (const float*)d_in[30];
  const float* l1f_wx  = (const float*)d_in[31]; const float* l1f_wh = (const float*)d_in[32]; const float* l1f_b = (const float*)d_in[33];
  const float* l1r_wx  = (const float*)d_in[34]; const float* l1r_wh = (const float*)d_in[35]; const float* l1r_b = (const float*)d_in[36];
  const float* l2f_wx  = (const float*)d_in[37]; const float* l2f_wh = (const float*)d_in[38]; const float* l2f_b = (const float*)d_in[39];
  const float* l2r_wx  = (const float*)d_in[40]; const float* l2r_wh = (const float*)d_in[41]; const float* l2r_b = (const float*)d_in[42];
  const float* wo      = (const float*)d_in[43]; const float* bo = (const float*)d_in[44];
  float* outp = (float*)d_out;

  char* base = (char*)d_ws;
  half_t* actA = (half_t*)base;
  half_t* actB = (half_t*)(base + 67108864);
  half_t* wtA  = (half_t*)(base + 100663296);
  float*  f32a = (float*)(base + 143687680);
  half_t* h16a = (half_t*)(base + 158736384);

  half_t* wt2  = wtA;
  half_t* wt3  = wtA + 73728;
  half_t* wt4  = wtA + 368640;
  half_t* wt5  = wtA + 958464;
  half_t* wt6  = wtA + 2138112;
  half_t* wt7  = wtA + 4497408;
  half_t* wtq  = wtA + 5545984;        // wtq|wtk|wtv contiguous -> [1536][7680]
  half_t* wtk  = wtA + 9478144;
  half_t* wtv  = wtA + 13410304;
  half_t* wt1f = wtA + 17342464;
  half_t* wt1r = wtA + 17866752;
  half_t* wt2f = wtA + 18391040;
  half_t* wt2r = wtA + 19439616;
  half_t* wto  = wtA + 20488192;

  float* qkvbuf = f32a;                // 480 x 1536 f32
  float* pre1f = f32a + 737280;
  float* pre1r = f32a + 1228800;
  float* pre2f = f32a + 1720320;
  float* pre2r = f32a + 2703360;

  // qkv split-K partials: 4 x 480x1536 f32 in the (free at that point)
  // actB region — conv7 consumed actB; nothing reads it afterwards.
  float* qkvp = (float*)actB;

  half_t* ao  = h16a;
  half_t* x1  = h16a + 245760;
  half_t* x2  = h16a + 491520;
  half_t* hb1 = h16a + 983040;              // 2 x 32 x 256 fp16
  half_t* hb2 = hb1 + 16384;                // 2 x 32 x 512 fp16
  int*    flags1 = (int*)(hb2 + 32768);     // 512 ints
  int*    flags2 = flags1 + 512;
  half_t* zbuf   = (half_t*)(flags2 + 512); // 32 halves
  float*  bnz    = (float*)(zbuf + 32);     // 5 x 2048 floats

  // transposed fp16 LSTM recurrent weights [4H][H] (appended past bnz)
  half_t* whT1f = (half_t*)(base + 160849920);   // 1024x256 = 512KB
  half_t* whT1r = (half_t*)(base + 161374208);
  half_t* whT2f = (half_t*)(base + 161898496);   // 2048x512 = 2MB
  half_t* whT2r = (half_t*)(base + 163995648);   // end 166,092,800

  auto convm = [&](const half_t* in, const half_t* wt, const float* b, void* out,
                   int N,int H,int W,int Ci,int Ho,int Wo,int Co,
                   int KH,int KW,int pH,int pW,int flags, float* bns){
    int M = N*Ho*Wo, K = KH*KW*Ci;
    dim3 grid(DIV_UP(Co,128), DIV_UP(M,128), 1);
    GOut g{wt, b, out};
    mfma_conv_kernel<<<grid,256,0,stream>>>(in,g,g,g,zbuf,bns,N,H,W,Ci,Ho,Wo,Co,
                                            KH,KW,pH,pW,M,K,flags,1);
  };
  auto gemm3 = [&](const half_t* A, GOut g0, GOut g1, GOut g2, int nz,
                   int M, int Nn, int K, int flags, int splitS){
    dim3 grid(DIV_UP(Nn,128), DIV_UP(M,128), nz);
    mfma_conv_kernel<<<grid,256,0,stream>>>(A,g0,g1,g2,zbuf,bnz,M,1,1,K,1,1,Nn,
                                            1,1,0,0,M,K,flags,splitS);
  };
  auto pool = [&](const half_t* in, half_t* out, int N,int H,int W,int C,
                  int Ho,int Wo,int sH,int sW){
    long total8 = (long)N*Ho*Wo*(C/8);
    maxpool8_kernel<<<(int)DIV_UP(total8,256),256,0,stream>>>(in,out,N,H,W,C,Ho,Wo,sH,sW);
  };
  auto bnApply = [&](half_t* buf, long nPix, int C, const float* s, const float* b,
                     float* sums){
    long total8 = nPix * C / 8;
    bn_apply_relu8_kernel<<<(int)DIV_UP(total8,256),256,0,stream>>>(buf, sums, s, b, total8, C, 1.0f/(float)nPix);
  };
  auto bnPool = [&](const half_t* in, half_t* out, int N,int H,int W,int C,
                    int Ho,int Wo,int sH,int sW, long nPix,
                    const float* s, const float* b, float* sums){
    long total8 = (long)N*Ho*Wo*(C/8);
    bn_pool8_kernel<<<(int)DIV_UP(total8,256),256,0,stream>>>(
        in,out,sums,s,b,N,H,W,C,Ho,Wo,sH,sW,1.0f/(float)nPix);
  };

  // one zero-fill: hb1/hb2, flags, zbuf, 5 bn-sum buffers
  hipMemsetAsync(hb1, 0, 143424, stream);

  // ---- ALL weight transposes in one launch (incl. LSTM Wh -> fp16 [4H][H]) ----
  {
    TpAll tp;
    const float* srcs[NTP] = {c2w,c3w,c4w,c5w,c6w,c7w,wq,wk,wv,l1f_wx,l1r_wx,l2f_wx,l2r_wx,wo,
                              l1f_wh,l1r_wh,l2f_wh,l2r_wh};
    half_t* dsts[NTP] = {wt2,wt3,wt4,wt5,wt6,wt7,wtq,wtk,wtv,wt1f,wt1r,wt2f,wt2r,wto,
                         whT1f,whT1r,whT2f,whT2r};
    int Ks[NTP] = {576,1152,2304,2304,4608,2048,7680,7680,7680,512,512,512,512,1024,
                   256,256,512,512};
    int Ns[NTP] = {128,256,256,512,512,512,512,512,512,1024,1024,2048,2048,1000,
                   1024,1024,2048,2048};
    int acc = 0;
    for (int i = 0; i < NTP; ++i) {
      tp.src[i] = srcs[i]; tp.dst[i] = dsts[i]; tp.K[i] = Ks[i]; tp.N[i] = Ns[i];
      tp.prefix[i] = acc;
      acc += DIV_UP(Ks[i],32) * DIV_UP(Ns[i],32);
    }
    tp.prefix[NTP] = acc;
    transpose_cvt_all_kernel<<<acc,256,0,stream>>>(tp);
  }

  // ---- conv stack (activations fp16) ----
  conv1_pool_kernel<<<1024,256,0,stream>>>(x, c1w, c1b, actB);  // fused conv1+pool1
  convm(actB, wt2, c2b, actA, 32,32,128,64,  32,128,128, 3,3,1,1, FLAG_RELU, bnz);
  pool(actA, actB, 32,32,128,128, 16,64, 2,2);
  convm(actB, wt3, c3b, actA, 32,16,64,128,  16,64,256,  3,3,1,1, FLAG_BNSUMS, bnz);
  bnApply(actA, 32768, 256, bn1s, bn1b, bnz);
  convm(actA, wt4, c4b, actB, 32,16,64,256,  16,64,256,  3,3,1,1, FLAG_BNSUMS, bnz + 2048);
  bnPool(actB, actA, 32,16,64,256, 16,32, 1,2, 32768, bn2s, bn2b, bnz + 2048);
  convm(actA, wt5, c5b, actB, 32,16,32,256,  16,32,512,  3,3,1,1, FLAG_BNSUMS, bnz + 4096);
  bnApply(actB, 16384, 512, bn3s, bn3b, bnz + 4096);
  convm(actB, wt6, c6b, actA, 32,16,32,512,  16,32,512,  3,3,1,1, FLAG_BNSUMS, bnz + 6144);
  bnPool(actA, actB, 32,16,32,512, 16,16, 1,2, 16384, bn4s, bn4b, bnz + 6144);
  convm(actB, wt7, c7b, actA, 32,16,16,512,  15,15,512,  2,2,0,0, FLAG_BNSUMS, bnz + 8192);
  bnApply(actA, 7200, 512, bn5s, bn5b, bnz + 8192);

  // ---- attention: qkv GEMM (N=1536) split-K x4 -> partials (plain
  // stores, no atomics); reduce+bias fused into attention phase 0 ----
  gemm3(actA, GOut{wtq, nullptr, qkvp}, GOut{wtq, nullptr, qkvp},
        GOut{wtq, nullptr, qkvp}, 4, 480, 1536, 7680, FLAG_SPLITK, 4);
  attention_kernel<<<32,256,0,stream>>>(qkvp, bq, bk, bv, qkvbuf, ao, 15, 512, 1536);

  // ---- LSTM stack 1 (H=256): 8 workers (XCD-pinned, grid 64) ----
  gemm3(ao, GOut{wt1f, l1f_b, pre1f}, GOut{wt1r, l1r_b, pre1r},
        GOut{wt1r, l1r_b, pre1r}, 2, 480, 1024, 512, FLAG_OUTF32, 1);
  lstm_persistent_kernel<256><<<64,256,0,stream>>>(
      pre1f, pre1r, whT1f, whT1r, hb1, x1, flags1, 8, 512, 0, 256);

  // ---- LSTM stack 2 (H=512): 16 workers (XCD-pinned, grid 128) ----
  gemm3(x1, GOut{wt2f, l2f_b, pre2f}, GOut{wt2r, l2r_b, pre2r},
        GOut{wt2r, l2r_b, pre2r}, 2, 480, 2048, 512, FLAG_OUTF32, 1);
  lstm_persistent_kernel<512><<<128,256,0,stream>>>(
      pre2f, pre2r, whT2f, whT2r, hb2, x2, flags2, 16, 1024, 512, 0);

  // ---- classifier ----
  gemm3(x2, GOut{wto, bo, outp}, GOut{wto, bo, outp}, GOut{wto, bo, outp}, 1,
        480, 1000, 1024, FLAG_OUTF32, 1);
}